// Round 1
// baseline (1522.873 us; speedup 1.0000x reference)
//
#include <hip/hip_runtime.h>
#include <stdint.h>

// ---------------- types / helpers ----------------
typedef __attribute__((ext_vector_type(8))) short bf16x8;
typedef __attribute__((ext_vector_type(4))) float f32x4;

__device__ __forceinline__ float bf2f(unsigned short u) {
  unsigned int x = ((unsigned int)u) << 16;
  return __builtin_bit_cast(float, x);
}
__device__ __forceinline__ unsigned short f2bf(float f) {
  unsigned int x = __builtin_bit_cast(unsigned int, f);
  unsigned int r = x + 0x7FFFu + ((x >> 16) & 1u);
  return (unsigned short)(r >> 16);
}
__device__ __forceinline__ float silu(float v) { return v / (1.f + expf(-v)); }

#define LSEQ 4096
#define DMODEL 256
#define NIN 1284
#define NINP 1408   // padded to 11*128

// ---------------- weight prep (cast to bf16, pad) ----------------
__global__ void k_prep_w(const float* __restrict__ w_in, const float* __restrict__ w_out,
                         unsigned short* __restrict__ wpad, unsigned short* __restrict__ woutbf) {
  int idx = blockIdx.x * 256 + threadIdx.x;
  const int tot1 = NINP * DMODEL;           // 360448
  if (idx < tot1) {
    int n = idx / DMODEL, k = idx % DMODEL;
    float v = (n < NIN) ? w_in[n * DMODEL + k] : 0.f;
    wpad[idx] = f2bf(v);
  } else {
    int j = idx - tot1;                      // 256*512 = 131072
    woutbf[j] = f2bf(w_out[j]);
  }
}

// ---------------- transpose x (B,C,L) -> u[m][k] bf16 ----------------
__global__ __launch_bounds__(256) void k_transpose_x(const float* __restrict__ x,
                                                     unsigned short* __restrict__ ubf) {
  __shared__ float t[64][65];
  int bid = blockIdx.x;                // 8 * 64 * 4
  int b = bid >> 8;
  int r = bid & 255;
  int lt = r >> 2, kt = r & 3;
  int l0 = lt * 64, k0 = kt * 64;
  int tid = threadIdx.x;
  int j = tid & 63, i0 = tid >> 6;
  for (int rr = 0; rr < 16; rr++) {
    int ki = i0 + rr * 4;
    t[ki][j] = x[(size_t)(b * DMODEL + k0 + ki) * LSEQ + l0 + j];
  }
  __syncthreads();
  for (int rr = 0; rr < 16; rr++) {
    int li = i0 + rr * 4;
    ubf[(size_t)(b * LSEQ + l0 + li) * DMODEL + k0 + j] = f2bf(t[j][li]);
  }
}

// ---------------- m97-style bf16 MFMA GEMM, 128x128 tile, BK=64 ----------------
// C[m][n] = sum_k A[m][k] * B[n][k]   (both row-major, bf16)
// EPI=0: in_proj epilogue (split zx bf16 / dt f32). EPI=1: plain f32 store ld=256.
template <int KDIM, int LDA, int LDB, int EPI>
__global__ __launch_bounds__(256) void k_gemm(const unsigned short* __restrict__ A,
                                              const unsigned short* __restrict__ B,
                                              float* __restrict__ outF,
                                              unsigned short* __restrict__ outBF,
                                              float* __restrict__ dtb, int tilesM) {
  __shared__ __align__(16) short As[128 * 64];
  __shared__ __align__(16) short Bs[128 * 64];
  int bid = blockIdx.x;
  int tm = bid % tilesM, tn = bid / tilesM;
  int m0 = tm * 128, n0 = tn * 128;
  int tid = threadIdx.x;
  int w = tid >> 6, lane = tid & 63;
  int wr = w >> 1, wc = w & 1;
  f32x4 acc[4][4];
  for (int i = 0; i < 4; i++)
    for (int j = 0; j < 4; j++) { acc[i][j][0] = 0.f; acc[i][j][1] = 0.f; acc[i][j][2] = 0.f; acc[i][j][3] = 0.f; }

  for (int kt = 0; kt < KDIM / 64; kt++) {
    int k0 = kt * 64;
    for (int i = 0; i < 4; i++) {
      int rowblk = w * 32 + i * 8;               // 8 rows per 1KB issue
      int row = rowblk + (lane >> 3);
      int kc = (lane & 7) * 8;
      const unsigned short* ga = A + (size_t)(m0 + row) * LDA + k0 + kc;
      __builtin_amdgcn_global_load_lds((const __attribute__((address_space(1))) unsigned int*)ga,
                                       (__attribute__((address_space(3))) unsigned int*)&As[rowblk * 64],
                                       16, 0, 0);
      const unsigned short* gb = B + (size_t)(n0 + row) * LDB + k0 + kc;
      __builtin_amdgcn_global_load_lds((const __attribute__((address_space(1))) unsigned int*)gb,
                                       (__attribute__((address_space(3))) unsigned int*)&Bs[rowblk * 64],
                                       16, 0, 0);
    }
    __syncthreads();
    for (int kk = 0; kk < 64; kk += 32) {
      bf16x8 af[4], bfr[4];
      for (int mi = 0; mi < 4; mi++)
        af[mi] = *(const bf16x8*)&As[(wr * 64 + mi * 16 + (lane & 15)) * 64 + kk + (lane >> 4) * 8];
      for (int ni = 0; ni < 4; ni++)
        bfr[ni] = *(const bf16x8*)&Bs[(wc * 64 + ni * 16 + (lane & 15)) * 64 + kk + (lane >> 4) * 8];
      for (int mi = 0; mi < 4; mi++)
        for (int ni = 0; ni < 4; ni++)
          acc[mi][ni] = __builtin_amdgcn_mfma_f32_16x16x32_bf16(af[mi], bfr[ni], acc[mi][ni], 0, 0, 0);
    }
    __syncthreads();
  }
  int fq = lane >> 4, fr = lane & 15;
  for (int mi = 0; mi < 4; mi++)
    for (int ni = 0; ni < 4; ni++)
      for (int j = 0; j < 4; j++) {
        int m = m0 + wr * 64 + mi * 16 + fq * 4 + j;
        int c = n0 + wc * 64 + ni * 16 + fr;
        float v = acc[mi][ni][j];
        if constexpr (EPI == 0) {
          if (c < 1280) outBF[(size_t)m * 1280 + c] = f2bf(v);
          else if (c < 1284) dtb[m * 4 + (c - 1280)] = v;
        } else {
          outF[(size_t)m * 256 + c] = v;
        }
      }
}

// ---------------- depthwise causal conv (4 taps) + SiLU ----------------
__global__ __launch_bounds__(256) void k_conv(const unsigned short* __restrict__ zx,
                                              const float* __restrict__ conv_w,
                                              const float* __restrict__ conv_b,
                                              unsigned short* __restrict__ xs,
                                              unsigned short* __restrict__ bc) {
  __shared__ __align__(16) unsigned short xt[35 * 512];
  int bid = blockIdx.x;
  int b = bid >> 7;
  int t0 = (bid & 127) * 32;
  int tid = threadIdx.x;
  for (int id = tid; id < 35 * 64; id += 256) {
    int r = id >> 6, ch = id & 63;
    int t = t0 - 3 + r;
    float4 v;
    if (t < 0) v = make_float4(0.f, 0.f, 0.f, 0.f);
    else v = *(const float4*)&zx[(size_t)(b * LSEQ + t) * 1280 + 768 + ch * 8];
    *(float4*)&xt[r * 512 + ch * 8] = v;
  }
  __syncthreads();
  int c0 = tid, c1 = tid + 256;
  float w0[4], w1[4];
  for (int k = 0; k < 4; k++) { w0[k] = conv_w[c0 * 4 + k]; w1[k] = conv_w[c1 * 4 + k]; }
  float bb0 = conv_b[c0], bb1 = conv_b[c1];
  for (int tl = 0; tl < 32; tl++) {
    float a0 = bb0, a1 = bb1;
    for (int k = 0; k < 4; k++) {
      a0 += bf2f(xt[(tl + k) * 512 + c0]) * w0[k];
      a1 += bf2f(xt[(tl + k) * 512 + c1]) * w1[k];
    }
    a0 = silu(a0); a1 = silu(a1);
    size_t row = (size_t)(b * LSEQ + t0 + tl);
    xs[row * 256 + c0] = f2bf(a0);            // channels 0..255 -> xs
    bc[row * 256 + (c1 - 256)] = f2bf(a1);    // 256..383 -> Bm(0..127), 384..511 -> Cm(128..255)
  }
}

// ---------------- selective scan: wave per (b,h,p), lane = n ----------------
__global__ __launch_bounds__(256) void k_scan(const unsigned short* __restrict__ xs,
                                              const unsigned short* __restrict__ bc,
                                              const float* __restrict__ dtb,
                                              const float* __restrict__ dt_bias,
                                              const float* __restrict__ A_log,
                                              const float* __restrict__ Dp,
                                              unsigned short* __restrict__ y) {
  __shared__ __align__(16) unsigned short bcl[32 * 256];
  __shared__ float xsl[32][4];
  __shared__ float dtl[32], dal[32];
  int bid = blockIdx.x;               // 8*4*16 = 512
  int b = bid >> 6;
  int h = (bid >> 4) & 3;
  int pg = bid & 15;
  int tid = threadIdx.x, w = tid >> 6, lane = tid & 63;
  int p = pg * 4 + w;
  float Ah = -expf(A_log[h]);
  float Dh = Dp[h];
  float bias = dt_bias[h];
  float h0 = 0.f, h1 = 0.f;
  for (int t0 = 0; t0 < LSEQ; t0 += 32) {
    for (int id = tid; id < 32 * 32; id += 256) {
      int r = id >> 5, ch = id & 31;
      *(float4*)&bcl[r * 256 + ch * 8] =
          *(const float4*)&bc[(size_t)(b * LSEQ + t0 + r) * 256 + ch * 8];
    }
    if (tid < 128) {
      int r = tid >> 2, pp = tid & 3;
      xsl[r][pp] = bf2f(xs[(size_t)(b * LSEQ + t0 + r) * 256 + h * 64 + pg * 4 + pp]);
    } else if (tid < 160) {
      int r = tid - 128;
      float v = dtb[(size_t)(b * LSEQ + t0 + r) * 4 + h] + bias;
      float dt = (v > 20.f) ? v : log1pf(expf(v));
      dtl[r] = dt;
      dal[r] = expf(dt * Ah);
    }
    __syncthreads();
    for (int tl = 0; tl < 32; tl++) {
      float dtv = dtl[tl], dav = dal[tl], xv = xsl[tl][w];
      float bn  = bf2f(bcl[tl * 256 + lane]);
      float bn2 = bf2f(bcl[tl * 256 + 64 + lane]);
      float cn  = bf2f(bcl[tl * 256 + 128 + lane]);
      float cn2 = bf2f(bcl[tl * 256 + 192 + lane]);
      float coef = dtv * xv;
      h0 = h0 * dav + coef * bn;
      h1 = h1 * dav + coef * bn2;
      float part = h0 * cn + h1 * cn2;
      for (int off = 32; off; off >>= 1) part += __shfl_xor(part, off, 64);
      if (lane == 0)
        y[(size_t)(b * LSEQ + t0 + tl) * 256 + h * 64 + p] = f2bf(part + Dh * xv);
    }
    __syncthreads();
  }
}

// ---------------- gate + RMSNorm + concat -> ycat bf16 [m][512] ----------------
__global__ __launch_bounds__(256) void k_ycat(const unsigned short* __restrict__ y,
                                              const unsigned short* __restrict__ zx,
                                              const float* __restrict__ norm_w,
                                              unsigned short* __restrict__ ycat) {
  int bid = blockIdx.x;
  int tid = threadIdx.x, w = tid >> 6, lane = tid & 63;
  size_t m = (size_t)bid * 4 + w;
  int j0 = lane * 4;
  ushort4 yv = *(const ushort4*)&y[m * 256 + j0];
  ushort4 zv = *(const ushort4*)&zx[m * 1280 + 512 + j0];
  unsigned short ya[4] = {yv.x, yv.y, yv.z, yv.w};
  unsigned short za[4] = {zv.x, zv.y, zv.z, zv.w};
  float g[4]; float ssum = 0.f;
  for (int i = 0; i < 4; i++) {
    float gg = bf2f(ya[i]) * silu(bf2f(za[i]));
    g[i] = gg; ssum += gg * gg;
  }
  for (int off = 32; off; off >>= 1) ssum += __shfl_xor(ssum, off, 64);
  float inv = rsqrtf(ssum * (1.f / 256.f) + 1e-5f);
  ushort4 z0v = *(const ushort4*)&zx[m * 1280 + j0];
  ushort4 x0v = *(const ushort4*)&zx[m * 1280 + 256 + j0];
  unsigned short z0a[4] = {z0v.x, z0v.y, z0v.z, z0v.w};
  unsigned short x0a[4] = {x0v.x, x0v.y, x0v.z, x0v.w};
  ushort4 o1, o2;
  unsigned short* o1a = (unsigned short*)&o1;
  unsigned short* o2a = (unsigned short*)&o2;
  for (int i = 0; i < 4; i++) {
    o1a[i] = f2bf(silu(bf2f(z0a[i])) * bf2f(x0a[i]));
    o2a[i] = f2bf(g[i] * norm_w[j0 + i] * inv);
  }
  *(ushort4*)&ycat[m * 512 + j0] = o1;
  *(ushort4*)&ycat[m * 512 + 256 + j0] = o2;
}

// ---------------- SE: mean over L ----------------
__global__ void k_zero(float* __restrict__ p) { p[blockIdx.x * 256 + threadIdx.x] = 0.f; }

__global__ __launch_bounds__(256) void k_semean(const float* __restrict__ res, float* __restrict__ smean) {
  int bid = blockIdx.x;
  int b = bid >> 5, ch = bid & 31;
  int c = threadIdx.x;
  float acc = 0.f;
  for (int r = 0; r < 128; r++)
    acc += res[(size_t)(b * LSEQ + ch * 128 + r) * 256 + c];
  atomicAdd(&smean[b * 256 + c], acc);
}

__global__ __launch_bounds__(512) void k_sefc(const float* __restrict__ smean,
                                              const float* __restrict__ w1, const float* __restrict__ b1,
                                              const float* __restrict__ w2, const float* __restrict__ b2,
                                              float* __restrict__ s2) {
  __shared__ float s1[512];
  int tid = threadIdx.x;
  int b = tid >> 6, j = tid & 63;
  float acc = b1[j];
  for (int k = 0; k < 256; k++) acc += smean[b * 256 + k] * (1.f / 4096.f) * w1[j * 256 + k];
  s1[b * 64 + j] = fmaxf(acc, 0.f);
  __syncthreads();
  for (int idx = tid; idx < 2048; idx += 512) {
    int bb = idx >> 8, c = idx & 255;
    float a2 = b2[c];
    for (int k = 0; k < 64; k++) a2 += s1[bb * 64 + k] * w2[c * 64 + k];
    s2[idx] = 1.f / (1.f + expf(-a2));
  }
}

// ---------------- final: transpose res[m][c] -> out[b][c][l] * SE scale ----------------
__global__ __launch_bounds__(256) void k_final(const float* __restrict__ res,
                                               const float* __restrict__ s2,
                                               float* __restrict__ out) {
  __shared__ float t[64][65];
  int bid = blockIdx.x;                 // 8 * 4 * 64
  int b = bid >> 8;
  int r = bid & 255;
  int ct = r >> 6, lt = r & 63;
  int c0 = ct * 64, l0 = lt * 64;
  int tid = threadIdx.x, j = tid & 63, i0 = tid >> 6;
  for (int rr = 0; rr < 16; rr++) {
    int i = i0 + rr * 4;                // l-row within tile
    t[i][j] = res[(size_t)(b * LSEQ + l0 + i) * 256 + c0 + j];
  }
  __syncthreads();
  for (int rr = 0; rr < 16; rr++) {
    int ci = i0 + rr * 4;
    float s = s2[b * 256 + c0 + ci];
    out[(size_t)(b * 256 + c0 + ci) * LSEQ + l0 + j] = t[j][ci] * s;
  }
}

// ---------------- launch ----------------
extern "C" void kernel_launch(void* const* d_in, const int* in_sizes, int n_in,
                              void* d_out, int out_size, void* d_ws, size_t ws_size,
                              hipStream_t stream) {
  const float* x         = (const float*)d_in[0];
  const float* in_proj_w = (const float*)d_in[1];
  const float* conv_w    = (const float*)d_in[2];
  const float* conv_b    = (const float*)d_in[3];
  const float* dt_bias   = (const float*)d_in[4];
  const float* A_log     = (const float*)d_in[5];
  const float* Dp        = (const float*)d_in[6];
  const float* norm_w    = (const float*)d_in[7];
  const float* out_projw = (const float*)d_in[8];
  const float* se_w1     = (const float*)d_in[9];
  const float* se_b1     = (const float*)d_in[10];
  const float* se_w2     = (const float*)d_in[11];
  const float* se_b2     = (const float*)d_in[12];
  float* out = (float*)d_out;
  char* ws = (char*)d_ws;

  // workspace layout (bytes); res aliases [ubf|xs] which are dead by GEMM2
  const size_t OFF_UBF   = 0;              // 16,777,216 bf16 u[m][k]
  const size_t OFF_XS    = 16777216;       // 16,777,216 bf16 xs[m][256]
  const size_t OFF_RES   = 0;              // 33,554,432 f32 res[m][256] (alias)
  const size_t OFF_BC    = 33554432;       // 16,777,216 bf16 [Bm|Cm][m][256]
  const size_t OFF_ZX    = 50331648;       // 83,886,080 bf16 zx[m][1280]
  const size_t OFF_DT    = 134217728;      //    524,288 f32 dt[m][4]
  const size_t OFF_Y     = 134742016;      // 16,777,216 bf16 y[m][256]
  const size_t OFF_YCAT  = 151519232;      // 33,554,432 bf16 ycat[m][512]
  const size_t OFF_WPAD  = 185073664;      //    720,896 bf16 [1408][256]
  const size_t OFF_WOUT  = 185794560;      //    262,144 bf16 [256][512]
  const size_t OFF_SMEAN = 186056704;      //      8,192 f32
  const size_t OFF_S2    = 186064896;      //      8,192 f32  (total ~186.1 MB)

  unsigned short* ubf   = (unsigned short*)(ws + OFF_UBF);
  unsigned short* xsb   = (unsigned short*)(ws + OFF_XS);
  float*          res   = (float*)(ws + OFF_RES);
  unsigned short* bcb   = (unsigned short*)(ws + OFF_BC);
  unsigned short* zx    = (unsigned short*)(ws + OFF_ZX);
  float*          dtb   = (float*)(ws + OFF_DT);
  unsigned short* ybuf  = (unsigned short*)(ws + OFF_Y);
  unsigned short* ycat  = (unsigned short*)(ws + OFF_YCAT);
  unsigned short* wpad  = (unsigned short*)(ws + OFF_WPAD);
  unsigned short* woutb = (unsigned short*)(ws + OFF_WOUT);
  float*          smean = (float*)(ws + OFF_SMEAN);
  float*          s2    = (float*)(ws + OFF_S2);

  k_prep_w<<<1920, 256, 0, stream>>>(in_proj_w, out_projw, wpad, woutb);
  k_transpose_x<<<2048, 256, 0, stream>>>(x, ubf);
  k_gemm<256, 256, 256, 0><<<256 * 11, 256, 0, stream>>>(ubf, wpad, nullptr, zx, dtb, 256);
  k_conv<<<1024, 256, 0, stream>>>(zx, conv_w, conv_b, xsb, bcb);
  k_scan<<<512, 256, 0, stream>>>(xsb, bcb, dtb, dt_bias, A_log, Dp, ybuf);
  k_ycat<<<8192, 256, 0, stream>>>(ybuf, zx, norm_w, ycat);
  k_gemm<512, 512, 512, 1><<<256 * 2, 256, 0, stream>>>(ycat, woutb, res, nullptr, nullptr, 256);
  k_zero<<<8, 256, 0, stream>>>(smean);
  k_semean<<<256, 256, 0, stream>>>(res, smean);
  k_sefc<<<1, 512, 0, stream>>>(smean, se_w1, se_b1, se_w2, se_b2, s2);
  k_final<<<2048, 256, 0, stream>>>(res, s2, out);
}

// Round 2
// 431.035 us; speedup vs baseline: 3.5331x; 3.5331x over previous
//
#include <hip/hip_runtime.h>
#include <stdint.h>

// ---------------- types / helpers ----------------
typedef __attribute__((ext_vector_type(8))) short bf16x8;
typedef __attribute__((ext_vector_type(4))) float f32x4;

__device__ __forceinline__ float bf2f(unsigned short u) {
  unsigned int x = ((unsigned int)u) << 16;
  return __builtin_bit_cast(float, x);
}
__device__ __forceinline__ unsigned short f2bf(float f) {
  unsigned int x = __builtin_bit_cast(unsigned int, f);
  unsigned int r = x + 0x7FFFu + ((x >> 16) & 1u);
  return (unsigned short)(r >> 16);
}
__device__ __forceinline__ float silu(float v) { return v / (1.f + expf(-v)); }
__device__ __forceinline__ f32x4 fz4() { f32x4 z; z[0]=0.f; z[1]=0.f; z[2]=0.f; z[3]=0.f; return z; }

#define LSEQ 4096
#define DMODEL 256
#define NIN 1284
#define NINP 1408   // padded to 11*128

// ---------------- weight prep (cast to bf16, pad) ----------------
__global__ void k_prep_w(const float* __restrict__ w_in, const float* __restrict__ w_out,
                         unsigned short* __restrict__ wpad, unsigned short* __restrict__ woutbf) {
  int idx = blockIdx.x * 256 + threadIdx.x;
  const int tot1 = NINP * DMODEL;           // 360448
  if (idx < tot1) {
    int n = idx / DMODEL, k = idx % DMODEL;
    float v = (n < NIN) ? w_in[n * DMODEL + k] : 0.f;
    wpad[idx] = f2bf(v);
  } else {
    int j = idx - tot1;                      // 256*512 = 131072
    woutbf[j] = f2bf(w_out[j]);
  }
}

// ---------------- transpose x (B,C,L) -> u[m][k] bf16 ----------------
__global__ __launch_bounds__(256) void k_transpose_x(const float* __restrict__ x,
                                                     unsigned short* __restrict__ ubf) {
  __shared__ float t[64][65];
  int bid = blockIdx.x;                // 8 * 64 * 4
  int b = bid >> 8;
  int r = bid & 255;
  int lt = r >> 2, kt = r & 3;
  int l0 = lt * 64, k0 = kt * 64;
  int tid = threadIdx.x;
  int j = tid & 63, i0 = tid >> 6;
  for (int rr = 0; rr < 16; rr++) {
    int ki = i0 + rr * 4;
    t[ki][j] = x[(size_t)(b * DMODEL + k0 + ki) * LSEQ + l0 + j];
  }
  __syncthreads();
  for (int rr = 0; rr < 16; rr++) {
    int li = i0 + rr * 4;
    ubf[(size_t)(b * LSEQ + l0 + li) * DMODEL + k0 + j] = f2bf(t[j][li]);
  }
}

// ---------------- m97-style bf16 MFMA GEMM, 128x128 tile, BK=64 ----------------
// C[m][n] = sum_k A[m][k] * B[n][k]
// EPI=0: combined zx[m][1280] + dt.  EPI=1: f32 res[m][256].  EPI=2: split zxa/xbc + dt.
template <int KDIM, int LDA, int LDB, int EPI>
__global__ __launch_bounds__(256) void k_gemm(const unsigned short* __restrict__ A,
                                              const unsigned short* __restrict__ B,
                                              float* __restrict__ outF,
                                              unsigned short* __restrict__ outBF,
                                              unsigned short* __restrict__ outBF2,
                                              float* __restrict__ dtb, int tilesM) {
  __shared__ __align__(16) short As[128 * 64];
  __shared__ __align__(16) short Bs[128 * 64];
  int bid = blockIdx.x;
  int tm = bid % tilesM, tn = bid / tilesM;
  int m0 = tm * 128, n0 = tn * 128;
  int tid = threadIdx.x;
  int w = tid >> 6, lane = tid & 63;
  int wr = w >> 1, wc = w & 1;
  f32x4 acc[4][4];
  for (int i = 0; i < 4; i++)
    for (int j = 0; j < 4; j++) acc[i][j] = fz4();

  for (int kt = 0; kt < KDIM / 64; kt++) {
    int k0 = kt * 64;
    for (int i = 0; i < 4; i++) {
      int rowblk = w * 32 + i * 8;
      int row = rowblk + (lane >> 3);
      int kc = (lane & 7) * 8;
      const unsigned short* ga = A + (size_t)(m0 + row) * LDA + k0 + kc;
      __builtin_amdgcn_global_load_lds((const __attribute__((address_space(1))) unsigned int*)ga,
                                       (__attribute__((address_space(3))) unsigned int*)&As[rowblk * 64],
                                       16, 0, 0);
      const unsigned short* gb = B + (size_t)(n0 + row) * LDB + k0 + kc;
      __builtin_amdgcn_global_load_lds((const __attribute__((address_space(1))) unsigned int*)gb,
                                       (__attribute__((address_space(3))) unsigned int*)&Bs[rowblk * 64],
                                       16, 0, 0);
    }
    __syncthreads();
    for (int kk = 0; kk < 64; kk += 32) {
      bf16x8 af[4], bfr[4];
      for (int mi = 0; mi < 4; mi++)
        af[mi] = *(const bf16x8*)&As[(wr * 64 + mi * 16 + (lane & 15)) * 64 + kk + (lane >> 4) * 8];
      for (int ni = 0; ni < 4; ni++)
        bfr[ni] = *(const bf16x8*)&Bs[(wc * 64 + ni * 16 + (lane & 15)) * 64 + kk + (lane >> 4) * 8];
      for (int mi = 0; mi < 4; mi++)
        for (int ni = 0; ni < 4; ni++)
          acc[mi][ni] = __builtin_amdgcn_mfma_f32_16x16x32_bf16(af[mi], bfr[ni], acc[mi][ni], 0, 0, 0);
    }
    __syncthreads();
  }
  int fq = lane >> 4, fr = lane & 15;
  for (int mi = 0; mi < 4; mi++)
    for (int ni = 0; ni < 4; ni++)
      for (int j = 0; j < 4; j++) {
        int m = m0 + wr * 64 + mi * 16 + fq * 4 + j;
        int c = n0 + wc * 64 + ni * 16 + fr;
        float v = acc[mi][ni][j];
        if constexpr (EPI == 0) {
          if (c < 1280) outBF[(size_t)m * 1280 + c] = f2bf(v);
          else if (c < 1284) dtb[m * 4 + (c - 1280)] = v;
        } else if constexpr (EPI == 1) {
          outF[(size_t)m * 256 + c] = v;
        } else {
          if (c < 768) outBF[(size_t)m * 768 + c] = f2bf(v);
          else if (c < 1280) outBF2[(size_t)m * 512 + (c - 768)] = f2bf(v);
          else if (c < 1284) dtb[m * 4 + (c - 1280)] = v;
        }
      }
}

// ---------------- depthwise causal conv (4 taps) + SiLU ----------------
// src points at xBC channel 0 of row 0; row stride = `stride` bf16 elements.
__global__ __launch_bounds__(256) void k_conv(const unsigned short* __restrict__ src, int stride,
                                              const float* __restrict__ conv_w,
                                              const float* __restrict__ conv_b,
                                              unsigned short* __restrict__ xs,
                                              unsigned short* __restrict__ bc) {
  __shared__ __align__(16) unsigned short xt[35 * 512];
  int bid = blockIdx.x;
  int b = bid >> 7;
  int t0 = (bid & 127) * 32;
  int tid = threadIdx.x;
  for (int id = tid; id < 35 * 64; id += 256) {
    int r = id >> 6, ch = id & 63;
    int t = t0 - 3 + r;
    float4 v;
    if (t < 0) v = make_float4(0.f, 0.f, 0.f, 0.f);
    else v = *(const float4*)&src[(size_t)(b * LSEQ + t) * stride + ch * 8];
    *(float4*)&xt[r * 512 + ch * 8] = v;
  }
  __syncthreads();
  int c0 = tid, c1 = tid + 256;
  float w0[4], w1[4];
  for (int k = 0; k < 4; k++) { w0[k] = conv_w[c0 * 4 + k]; w1[k] = conv_w[c1 * 4 + k]; }
  float bb0 = conv_b[c0], bb1 = conv_b[c1];
  for (int tl = 0; tl < 32; tl++) {
    float a0 = bb0, a1 = bb1;
    for (int k = 0; k < 4; k++) {
      a0 += bf2f(xt[(tl + k) * 512 + c0]) * w0[k];
      a1 += bf2f(xt[(tl + k) * 512 + c1]) * w1[k];
    }
    a0 = silu(a0); a1 = silu(a1);
    size_t row = (size_t)(b * LSEQ + t0 + tl);
    xs[row * 256 + c0] = f2bf(a0);
    bc[row * 256 + (c1 - 256)] = f2bf(a1);
  }
}

// ---------------- OLD sequential scan (ws fallback) ----------------
__global__ __launch_bounds__(256) void k_scan(const unsigned short* __restrict__ xs,
                                              const unsigned short* __restrict__ bc,
                                              const float* __restrict__ dtb,
                                              const float* __restrict__ dt_bias,
                                              const float* __restrict__ A_log,
                                              const float* __restrict__ Dp,
                                              unsigned short* __restrict__ y) {
  __shared__ __align__(16) unsigned short bcl[32 * 256];
  __shared__ float xsl[32][4];
  __shared__ float dtl[32], dal[32];
  int bid = blockIdx.x;
  int b = bid >> 6;
  int h = (bid >> 4) & 3;
  int pg = bid & 15;
  int tid = threadIdx.x, w = tid >> 6, lane = tid & 63;
  int p = pg * 4 + w;
  float Ah = -expf(A_log[h]);
  float Dh = Dp[h];
  float bias = dt_bias[h];
  float h0 = 0.f, h1 = 0.f;
  for (int t0 = 0; t0 < LSEQ; t0 += 32) {
    for (int id = tid; id < 32 * 32; id += 256) {
      int r = id >> 5, ch = id & 31;
      *(float4*)&bcl[r * 256 + ch * 8] =
          *(const float4*)&bc[(size_t)(b * LSEQ + t0 + r) * 256 + ch * 8];
    }
    if (tid < 128) {
      int r = tid >> 2, pp = tid & 3;
      xsl[r][pp] = bf2f(xs[(size_t)(b * LSEQ + t0 + r) * 256 + h * 64 + pg * 4 + pp]);
    } else if (tid < 160) {
      int r = tid - 128;
      float v = dtb[(size_t)(b * LSEQ + t0 + r) * 4 + h] + bias;
      float dt = (v > 20.f) ? v : log1pf(expf(v));
      dtl[r] = dt;
      dal[r] = expf(dt * Ah);
    }
    __syncthreads();
    for (int tl = 0; tl < 32; tl++) {
      float dtv = dtl[tl], dav = dal[tl], xv = xsl[tl][w];
      float bn  = bf2f(bcl[tl * 256 + lane]);
      float bn2 = bf2f(bcl[tl * 256 + 64 + lane]);
      float cn  = bf2f(bcl[tl * 256 + 128 + lane]);
      float cn2 = bf2f(bcl[tl * 256 + 192 + lane]);
      float coef = dtv * xv;
      h0 = h0 * dav + coef * bn;
      h1 = h1 * dav + coef * bn2;
      float part = h0 * cn + h1 * cn2;
      for (int off = 32; off; off >>= 1) part += __shfl_xor(part, off, 64);
      if (lane == 0)
        y[(size_t)(b * LSEQ + t0 + tl) * 256 + h * 64 + p] = f2bf(part + Dh * xv);
    }
    __syncthreads();
  }
}

// ---------------- dt precompute: softplus + within-chunk cumsum of dt*A ----------------
__global__ __launch_bounds__(64) void k_dtpre(const float* __restrict__ dtraw,
                                              const float* __restrict__ dt_bias,
                                              const float* __restrict__ A_log,
                                              float* __restrict__ dts, float* __restrict__ cums) {
  int bid = blockIdx.x;               // bh*64 + c
  int bh = bid >> 6, c = bid & 63;
  int b = bh >> 2, h = bh & 3;
  int lane = threadIdx.x;
  int t = c * 64 + lane;
  float v = dtraw[(size_t)(b * LSEQ + t) * 4 + h] + dt_bias[h];
  float dt = (v > 20.f) ? v : log1pf(expf(v));
  float Ah = -expf(A_log[h]);
  float s = dt * Ah;
  for (int off = 1; off < 64; off <<= 1) {
    float o = __shfl_up(s, off, 64);
    if (lane >= off) s += o;
  }
  dts[bh * LSEQ + t] = dt;
  cums[bh * LSEQ + t] = s;
}

// ---------------- chunk phase A: G=C·B^T, mask, Y_intra=M·X, ST=X^T·Bsc ----------------
// grid: bh*64 + c (2048 blocks), 256 threads (4 waves)
__global__ __launch_bounds__(256) void k_chunkA(const unsigned short* __restrict__ bc,
                                                const unsigned short* __restrict__ xs,
                                                const float* __restrict__ dts,
                                                const float* __restrict__ cums,
                                                float* __restrict__ ST,
                                                unsigned short* __restrict__ yb) {
  __shared__ __align__(16) unsigned short Cs[64 * 128];
  __shared__ __align__(16) unsigned short Bsm[64 * 128];
  __shared__ __align__(16) unsigned short Bt[128 * 64];
  __shared__ __align__(16) unsigned short Xt[64 * 64];
  __shared__ __align__(16) unsigned short Ms[64 * 64];
  __shared__ float dtl[64], cuml[64];
  int bid = blockIdx.x;
  int bh = bid >> 6, c = bid & 63;
  int b = bh >> 2, h = bh & 3;
  int m0 = b * LSEQ + c * 64;
  int tid = threadIdx.x, w = tid >> 6, lane = tid & 63;

  if (tid < 64) {
    dtl[tid] = dts[bh * LSEQ + c * 64 + tid];
    cuml[tid] = cums[bh * LSEQ + c * 64 + tid];
  }
  __syncthreads();
  float cumQ = cuml[63];

  // stage Cs/Bs row-major swizzled; Bt transposed+scaled; 64 rows x 16 granules
  for (int it = 0; it < 4; it++) {
    int idx = it * 256 + tid;
    int row = idx >> 4, g = idx & 15;
    int sg = g ^ (row & 7);
    uint4 vC = *(const uint4*)&bc[(size_t)(m0 + row) * 256 + 128 + g * 8];
    *(uint4*)((char*)Cs + row * 256 + sg * 16) = vC;
    uint4 vB = *(const uint4*)&bc[(size_t)(m0 + row) * 256 + g * 8];
    *(uint4*)((char*)Bsm + row * 256 + sg * 16) = vB;
    float sc = dtl[row] * expf(cumQ - cuml[row]);
    const unsigned short* pv = (const unsigned short*)&vB;
    for (int e = 0; e < 8; e++) {
      int n = g * 8 + e;
      *(unsigned short*)((char*)Bt + n * 128 + (((row >> 3) ^ (n & 7)) << 4) + ((row & 7) << 1)) =
          f2bf(bf2f(pv[e]) * sc);
    }
  }
  // stage Xt transposed: 64 rows x 8 granules
  for (int it = 0; it < 2; it++) {
    int idx = it * 256 + tid;
    int row = idx >> 3, g = idx & 7;
    uint4 vX = *(const uint4*)&xs[(size_t)(m0 + row) * 256 + h * 64 + g * 8];
    const unsigned short* pv = (const unsigned short*)&vX;
    for (int e = 0; e < 8; e++) {
      int p = g * 8 + e;
      *(unsigned short*)((char*)Xt + p * 128 + (((row >> 3) ^ (p & 7)) << 4) + ((row & 7) << 1)) = pv[e];
    }
  }
  __syncthreads();

  // GEMM1: G = C · B^T  (wave w: t-rows w*16..+15, all 64 s)
  f32x4 acc1[4];
#pragma unroll
  for (int i = 0; i < 4; i++) acc1[i] = fz4();
#pragma unroll
  for (int ks = 0; ks < 4; ks++) {
    int g = ks * 4 + (lane >> 4);
    int rt = w * 16 + (lane & 15);
    bf16x8 a = *(const bf16x8*)((char*)Cs + rt * 256 + ((g ^ (rt & 7)) << 4));
#pragma unroll
    for (int ni = 0; ni < 4; ni++) {
      int rs = ni * 16 + (lane & 15);
      bf16x8 bfr = *(const bf16x8*)((char*)Bsm + rs * 256 + ((g ^ (rs & 7)) << 4));
      acc1[ni] = __builtin_amdgcn_mfma_f32_16x16x32_bf16(a, bfr, acc1[ni], 0, 0, 0);
    }
  }
  // mask + write M (bf16, swizzled)
#pragma unroll
  for (int ni = 0; ni < 4; ni++)
#pragma unroll
    for (int j = 0; j < 4; j++) {
      int t = w * 16 + (lane >> 4) * 4 + j;
      int s = ni * 16 + (lane & 15);
      float v = 0.f;
      if (t >= s) v = acc1[ni][j] * expf(cuml[t] - cuml[s]) * dtl[s];
      *(unsigned short*)((char*)Ms + t * 128 + (((s >> 3) ^ (t & 7)) << 4) + ((s & 7) << 1)) = f2bf(v);
    }
  __syncthreads();

  // GEMM2: Y_intra = M · X   and GEMM3: ST[p][n] = X^T · Bsc
  f32x4 acc2[4], acc3[8];
#pragma unroll
  for (int i = 0; i < 4; i++) acc2[i] = fz4();
#pragma unroll
  for (int i = 0; i < 8; i++) acc3[i] = fz4();
#pragma unroll
  for (int ks = 0; ks < 2; ks++) {
    int g = ks * 2 + (lane >> 5);             // careful: see below
    // k0 = ks*32 + (lane>>4)*8 -> granule = k0>>3 = ks*4 + (lane>>4)
    g = ks * 4 + (lane >> 4);
    bf16x8 xf[4];
#pragma unroll
    for (int ni = 0; ni < 4; ni++) {
      int rp = ni * 16 + (lane & 15);
      xf[ni] = *(const bf16x8*)((char*)Xt + rp * 128 + ((g ^ (rp & 7)) << 4));
    }
    {
      int rt = w * 16 + (lane & 15);
      bf16x8 a = *(const bf16x8*)((char*)Ms + rt * 128 + ((g ^ (rt & 7)) << 4));
#pragma unroll
      for (int ni = 0; ni < 4; ni++)
        acc2[ni] = __builtin_amdgcn_mfma_f32_16x16x32_bf16(a, xf[ni], acc2[ni], 0, 0, 0);
    }
    {
      bf16x8 a3 = xf[w];                       // Xt row w*16+(lane&15)
#pragma unroll
      for (int ni = 0; ni < 8; ni++) {
        int rn = ni * 16 + (lane & 15);
        bf16x8 bfr = *(const bf16x8*)((char*)Bt + rn * 128 + ((g ^ (rn & 7)) << 4));
        acc3[ni] = __builtin_amdgcn_mfma_f32_16x16x32_bf16(a3, bfr, acc3[ni], 0, 0, 0);
      }
    }
  }
  // epilogue
#pragma unroll
  for (int ni = 0; ni < 4; ni++)
#pragma unroll
    for (int j = 0; j < 4; j++) {
      int t = w * 16 + (lane >> 4) * 4 + j;
      int p = ni * 16 + (lane & 15);
      yb[(size_t)(m0 + t) * 256 + h * 64 + p] = f2bf(acc2[ni][j]);
    }
  float* stp = ST + ((size_t)bid << 13);
#pragma unroll
  for (int ni = 0; ni < 8; ni++)
#pragma unroll
    for (int j = 0; j < 4; j++) {
      int p = w * 16 + (lane >> 4) * 4 + j;
      int n = ni * 16 + (lane & 15);
      stp[p * 128 + n] = acc3[ni][j];
    }
}

// ---------------- chunk phase B: sequential state carry ----------------
// grid: bh*8 + pslice (256 blocks), 256 threads
__global__ __launch_bounds__(256) void k_chunkB(const float* __restrict__ ST,
                                                const float* __restrict__ cums,
                                                unsigned short* __restrict__ HT) {
  int bid = blockIdx.x;
  int bh = bid >> 3, psl = bid & 7;
  int p = psl * 8 + (threadIdx.x >> 5);
  int n0 = (threadIdx.x & 31) * 4;
  float H[4] = {0.f, 0.f, 0.f, 0.f};
  for (int c = 0; c < 64; c++) {
    size_t base = (size_t)(bh * 64 + c);
    ushort4 hv;
    unsigned short* ha = (unsigned short*)&hv;
#pragma unroll
    for (int e = 0; e < 4; e++) ha[e] = f2bf(H[e]);
    *(ushort4*)&HT[(base * 64 + p) * 128 + n0] = hv;
    float4 s4 = *(const float4*)&ST[(base << 13) + p * 128 + n0];
    float dec = expf(cums[bh * LSEQ + c * 64 + 63]);
    H[0] = H[0] * dec + s4.x;
    H[1] = H[1] * dec + s4.y;
    H[2] = H[2] * dec + s4.z;
    H[3] = H[3] * dec + s4.w;
  }
}

// ---------------- chunk phase C: Y += exp(cum)·C·Hstart + D·x ----------------
// grid: bh*64 + c (2048 blocks), 256 threads
__global__ __launch_bounds__(256) void k_chunkC(const unsigned short* __restrict__ bc,
                                                const unsigned short* __restrict__ xs,
                                                const unsigned short* __restrict__ HT,
                                                const float* __restrict__ cums,
                                                const float* __restrict__ Dp,
                                                unsigned short* __restrict__ yb) {
  __shared__ __align__(16) unsigned short Cse[64 * 128];
  __shared__ __align__(16) unsigned short Hs[64 * 128];
  int bid = blockIdx.x;
  int bh = bid >> 6, c = bid & 63;
  int b = bh >> 2, h = bh & 3;
  int m0 = b * LSEQ + c * 64;
  int tid = threadIdx.x, w = tid >> 6, lane = tid & 63;
  float Dh = Dp[h];
  for (int it = 0; it < 4; it++) {
    int idx = it * 256 + tid;
    int row = idx >> 4, g = idx & 15;
    int sg = g ^ (row & 7);
    float ex = expf(cums[bh * LSEQ + c * 64 + row]);
    uint4 vC = *(const uint4*)&bc[(size_t)(m0 + row) * 256 + 128 + g * 8];
    const unsigned short* pc = (const unsigned short*)&vC;
    uint4 vo;
    unsigned short* po = (unsigned short*)&vo;
#pragma unroll
    for (int e = 0; e < 8; e++) po[e] = f2bf(bf2f(pc[e]) * ex);
    *(uint4*)((char*)Cse + row * 256 + sg * 16) = vo;
    uint4 vH = *(const uint4*)&HT[((size_t)(bh * 64 + c) * 64 + row) * 128 + g * 8];
    *(uint4*)((char*)Hs + row * 256 + sg * 16) = vH;
  }
  __syncthreads();
  f32x4 acc[4];
#pragma unroll
  for (int i = 0; i < 4; i++) acc[i] = fz4();
#pragma unroll
  for (int ks = 0; ks < 4; ks++) {
    int g = ks * 4 + (lane >> 4);
    int rt = w * 16 + (lane & 15);
    bf16x8 a = *(const bf16x8*)((char*)Cse + rt * 256 + ((g ^ (rt & 7)) << 4));
#pragma unroll
    for (int ni = 0; ni < 4; ni++) {
      int rp = ni * 16 + (lane & 15);
      bf16x8 bfr = *(const bf16x8*)((char*)Hs + rp * 256 + ((g ^ (rp & 7)) << 4));
      acc[ni] = __builtin_amdgcn_mfma_f32_16x16x32_bf16(a, bfr, acc[ni], 0, 0, 0);
    }
  }
#pragma unroll
  for (int ni = 0; ni < 4; ni++)
#pragma unroll
    for (int j = 0; j < 4; j++) {
      int t = w * 16 + (lane >> 4) * 4 + j;
      int p = ni * 16 + (lane & 15);
      size_t off = (size_t)(m0 + t) * 256 + h * 64 + p;
      float v = acc[ni][j] + bf2f(yb[off]) + Dh * bf2f(xs[off]);
      yb[off] = f2bf(v);
    }
}

// ---------------- gate + RMSNorm + concat -> ycat bf16 [m][512] ----------------
__global__ __launch_bounds__(256) void k_ycat(const unsigned short* __restrict__ y,
                                              const unsigned short* __restrict__ zsrc, int zstride,
                                              const float* __restrict__ norm_w,
                                              unsigned short* __restrict__ ycat) {
  int bid = blockIdx.x;
  int tid = threadIdx.x, w = tid >> 6, lane = tid & 63;
  size_t m = (size_t)bid * 4 + w;
  int j0 = lane * 4;
  ushort4 yv = *(const ushort4*)&y[m * 256 + j0];
  ushort4 zv = *(const ushort4*)&zsrc[m * zstride + 512 + j0];
  unsigned short ya[4] = {yv.x, yv.y, yv.z, yv.w};
  unsigned short za[4] = {zv.x, zv.y, zv.z, zv.w};
  float g[4]; float ssum = 0.f;
  for (int i = 0; i < 4; i++) {
    float gg = bf2f(ya[i]) * silu(bf2f(za[i]));
    g[i] = gg; ssum += gg * gg;
  }
  for (int off = 32; off; off >>= 1) ssum += __shfl_xor(ssum, off, 64);
  float inv = rsqrtf(ssum * (1.f / 256.f) + 1e-5f);
  ushort4 z0v = *(const ushort4*)&zsrc[m * zstride + j0];
  ushort4 x0v = *(const ushort4*)&zsrc[m * zstride + 256 + j0];
  unsigned short z0a[4] = {z0v.x, z0v.y, z0v.z, z0v.w};
  unsigned short x0a[4] = {x0v.x, x0v.y, x0v.z, x0v.w};
  ushort4 o1, o2;
  unsigned short* o1a = (unsigned short*)&o1;
  unsigned short* o2a = (unsigned short*)&o2;
  for (int i = 0; i < 4; i++) {
    o1a[i] = f2bf(silu(bf2f(z0a[i])) * bf2f(x0a[i]));
    o2a[i] = f2bf(g[i] * norm_w[j0 + i] * inv);
  }
  *(ushort4*)&ycat[m * 512 + j0] = o1;
  *(ushort4*)&ycat[m * 512 + 256 + j0] = o2;
}

// ---------------- SE ----------------
__global__ void k_zero(float* __restrict__ p) { p[blockIdx.x * 256 + threadIdx.x] = 0.f; }

__global__ __launch_bounds__(256) void k_semean(const float* __restrict__ res, float* __restrict__ smean) {
  int bid = blockIdx.x;
  int b = bid >> 5, ch = bid & 31;
  int c = threadIdx.x;
  float acc = 0.f;
  for (int r = 0; r < 128; r++)
    acc += res[(size_t)(b * LSEQ + ch * 128 + r) * 256 + c];
  atomicAdd(&smean[b * 256 + c], acc);
}

__global__ __launch_bounds__(512) void k_sefc(const float* __restrict__ smean,
                                              const float* __restrict__ w1, const float* __restrict__ b1,
                                              const float* __restrict__ w2, const float* __restrict__ b2,
                                              float* __restrict__ s2) {
  __shared__ float s1[512];
  int tid = threadIdx.x;
  int b = tid >> 6, j = tid & 63;
  float acc = b1[j];
  for (int k = 0; k < 256; k++) acc += smean[b * 256 + k] * (1.f / 4096.f) * w1[j * 256 + k];
  s1[b * 64 + j] = fmaxf(acc, 0.f);
  __syncthreads();
  for (int idx = tid; idx < 2048; idx += 512) {
    int bb = idx >> 8, c = idx & 255;
    float a2 = b2[c];
    for (int k = 0; k < 64; k++) a2 += s1[bb * 64 + k] * w2[c * 64 + k];
    s2[idx] = 1.f / (1.f + expf(-a2));
  }
}

// ---------------- final: transpose + SE scale ----------------
__global__ __launch_bounds__(256) void k_final(const float* __restrict__ res,
                                               const float* __restrict__ s2,
                                               float* __restrict__ out) {
  __shared__ float t[64][65];
  int bid = blockIdx.x;
  int b = bid >> 8;
  int r = bid & 255;
  int ct = r >> 6, lt = r & 63;
  int c0 = ct * 64, l0 = lt * 64;
  int tid = threadIdx.x, j = tid & 63, i0 = tid >> 6;
  for (int rr = 0; rr < 16; rr++) {
    int i = i0 + rr * 4;
    t[i][j] = res[(size_t)(b * LSEQ + l0 + i) * 256 + c0 + j];
  }
  __syncthreads();
  for (int rr = 0; rr < 16; rr++) {
    int ci = i0 + rr * 4;
    float s = s2[b * 256 + c0 + ci];
    out[(size_t)(b * 256 + c0 + ci) * LSEQ + l0 + j] = t[j][ci] * s;
  }
}

// ---------------- launch ----------------
extern "C" void kernel_launch(void* const* d_in, const int* in_sizes, int n_in,
                              void* d_out, int out_size, void* d_ws, size_t ws_size,
                              hipStream_t stream) {
  const float* x         = (const float*)d_in[0];
  const float* in_proj_w = (const float*)d_in[1];
  const float* conv_w    = (const float*)d_in[2];
  const float* conv_b    = (const float*)d_in[3];
  const float* dt_bias   = (const float*)d_in[4];
  const float* A_log     = (const float*)d_in[5];
  const float* Dp        = (const float*)d_in[6];
  const float* norm_w    = (const float*)d_in[7];
  const float* out_projw = (const float*)d_in[8];
  const float* se_w1     = (const float*)d_in[9];
  const float* se_b1     = (const float*)d_in[10];
  const float* se_w2     = (const float*)d_in[11];
  const float* se_b2     = (const float*)d_in[12];
  float* out = (float*)d_out;
  char* ws = (char*)d_ws;

  const size_t NEED_CHUNKED = 220676096;

  if (ws_size >= NEED_CHUNKED) {
    // ---- chunked-SSD path ----
    // layout (bytes):
    unsigned short* ubf   = (unsigned short*)(ws + 0);          // 16.7MB, dead after gemm1
    unsigned short* xbc   = (unsigned short*)(ws + 16777216);   // 33.5MB [m][512], dead after conv
    unsigned short* ycat  = (unsigned short*)(ws + 50331648);   // 33.5MB, written at k_ycat
    float*          ST    = (float*)(ws + 0);                   // 67MB alias over [0,67M) (dead zone)
    float*          res   = (float*)(ws + 0);                   // 33.5MB alias, written at gemm2
    unsigned short* zxa   = (unsigned short*)(ws + 83886080);   // 50.3MB [m][768]
    unsigned short* xsb   = (unsigned short*)(ws + 134217728);  // 16.7MB
    unsigned short* bcb   = (unsigned short*)(ws + 150994944);  // 16.7MB
    unsigned short* HT    = (unsigned short*)(ws + 167772160);  // 33.5MB
    unsigned short* ybuf  = (unsigned short*)(ws + 201326592);  // 16.7MB
    unsigned short* wpad  = (unsigned short*)(ws + 218103808);
    unsigned short* woutb = (unsigned short*)(ws + 218824704);
    float*          dtraw = (float*)(ws + 219086848);
    float*          dts   = (float*)(ws + 219611136);
    float*          cums  = (float*)(ws + 220135424);
    float*          smean = (float*)(ws + 220659712);
    float*          s2    = (float*)(ws + 220667904);

    k_prep_w<<<1920, 256, 0, stream>>>(in_proj_w, out_projw, wpad, woutb);
    k_transpose_x<<<2048, 256, 0, stream>>>(x, ubf);
    k_gemm<256, 256, 256, 2><<<256 * 11, 256, 0, stream>>>(ubf, wpad, nullptr, zxa, xbc, dtraw, 256);
    k_conv<<<1024, 256, 0, stream>>>(xbc, 512, conv_w, conv_b, xsb, bcb);
    k_dtpre<<<2048, 64, 0, stream>>>(dtraw, dt_bias, A_log, dts, cums);
    k_chunkA<<<2048, 256, 0, stream>>>(bcb, xsb, dts, cums, ST, ybuf);
    k_chunkB<<<256, 256, 0, stream>>>(ST, cums, HT);
    k_chunkC<<<2048, 256, 0, stream>>>(bcb, xsb, HT, cums, Dp, ybuf);
    k_ycat<<<8192, 256, 0, stream>>>(ybuf, zxa, 768, norm_w, ycat);
    k_gemm<512, 512, 512, 1><<<256 * 2, 256, 0, stream>>>(ycat, woutb, res, nullptr, nullptr, nullptr, 256);
    k_zero<<<8, 256, 0, stream>>>(smean);
    k_semean<<<256, 256, 0, stream>>>(res, smean);
    k_sefc<<<1, 512, 0, stream>>>(smean, se_w1, se_b1, se_w2, se_b2, s2);
    k_final<<<2048, 256, 0, stream>>>(res, s2, out);
  } else {
    // ---- fallback: proven round-1 sequential-scan path (<=186.1MB) ----
    unsigned short* ubf   = (unsigned short*)(ws + 0);
    unsigned short* xsb   = (unsigned short*)(ws + 16777216);
    float*          res   = (float*)(ws + 0);
    unsigned short* bcb   = (unsigned short*)(ws + 33554432);
    unsigned short* zx    = (unsigned short*)(ws + 50331648);
    float*          dtb   = (float*)(ws + 134217728);
    unsigned short* ybuf  = (unsigned short*)(ws + 134742016);
    unsigned short* ycat  = (unsigned short*)(ws + 151519232);
    unsigned short* wpad  = (unsigned short*)(ws + 185073664);
    unsigned short* woutb = (unsigned short*)(ws + 185794560);
    float*          smean = (float*)(ws + 186056704);
    float*          s2    = (float*)(ws + 186064896);

    k_prep_w<<<1920, 256, 0, stream>>>(in_proj_w, out_projw, wpad, woutb);
    k_transpose_x<<<2048, 256, 0, stream>>>(x, ubf);
    k_gemm<256, 256, 256, 0><<<256 * 11, 256, 0, stream>>>(ubf, wpad, nullptr, zx, nullptr, dtb, 256);
    k_conv<<<1024, 256, 0, stream>>>(zx + 768, 1280, conv_w, conv_b, xsb, bcb);
    k_scan<<<512, 256, 0, stream>>>(xsb, bcb, dtb, dt_bias, A_log, Dp, ybuf);
    k_ycat<<<8192, 256, 0, stream>>>(ybuf, zx, 1280, norm_w, ycat);
    k_gemm<512, 512, 512, 1><<<256 * 2, 256, 0, stream>>>(ycat, woutb, res, nullptr, nullptr, nullptr, 256);
    k_zero<<<8, 256, 0, stream>>>(smean);
    k_semean<<<256, 256, 0, stream>>>(res, smean);
    k_sefc<<<1, 512, 0, stream>>>(smean, se_w1, se_b1, se_w2, se_b2, s2);
    k_final<<<2048, 256, 0, stream>>>(res, s2, out);
  }
}

// Round 3
// 252.208 us; speedup vs baseline: 6.0382x; 1.7090x over previous
//
#include <hip/hip_runtime.h>
#include <stdint.h>

// ---------------- types / helpers ----------------
typedef __attribute__((ext_vector_type(8))) short bf16x8;
typedef __attribute__((ext_vector_type(4))) float f32x4;

__device__ __forceinline__ float bf2f(unsigned short u) {
  unsigned int x = ((unsigned int)u) << 16;
  return __builtin_bit_cast(float, x);
}
__device__ __forceinline__ unsigned short f2bf(float f) {
  unsigned int x = __builtin_bit_cast(unsigned int, f);
  unsigned int r = x + 0x7FFFu + ((x >> 16) & 1u);
  return (unsigned short)(r >> 16);
}
__device__ __forceinline__ float silu(float v) { return v / (1.f + expf(-v)); }
__device__ __forceinline__ f32x4 fz4() { f32x4 z; z[0]=0.f; z[1]=0.f; z[2]=0.f; z[3]=0.f; return z; }

#define LSEQ 4096
#define DMODEL 256
#define NIN 1284
#define NINP 1408   // padded to 11*128

// ---------------- weight prep (cast to bf16, pad) ----------------
__global__ void k_prep_w(const float* __restrict__ w_in, const float* __restrict__ w_out,
                         unsigned short* __restrict__ wpad, unsigned short* __restrict__ woutbf) {
  int idx = blockIdx.x * 256 + threadIdx.x;
  const int tot1 = NINP * DMODEL;           // 360448
  if (idx < tot1) {
    int n = idx / DMODEL, k = idx % DMODEL;
    float v = (n < NIN) ? w_in[n * DMODEL + k] : 0.f;
    wpad[idx] = f2bf(v);
  } else {
    int j = idx - tot1;                      // 256*512 = 131072
    woutbf[j] = f2bf(w_out[j]);
  }
}

// ---------------- transpose x (B,C,L) -> u[m][k] bf16 ----------------
__global__ __launch_bounds__(256) void k_transpose_x(const float* __restrict__ x,
                                                     unsigned short* __restrict__ ubf) {
  __shared__ float t[64][65];
  int bid = blockIdx.x;                // 8 * 64 * 4
  int b = bid >> 8;
  int r = bid & 255;
  int lt = r >> 2, kt = r & 3;
  int l0 = lt * 64, k0 = kt * 64;
  int tid = threadIdx.x;
  int j = tid & 63, i0 = tid >> 6;
  for (int rr = 0; rr < 16; rr++) {
    int ki = i0 + rr * 4;
    t[ki][j] = x[(size_t)(b * DMODEL + k0 + ki) * LSEQ + l0 + j];
  }
  __syncthreads();
  for (int rr = 0; rr < 16; rr++) {
    int li = i0 + rr * 4;
    ubf[(size_t)(b * LSEQ + l0 + li) * DMODEL + k0 + j] = f2bf(t[j][li]);
  }
}

// ---------------- m97-style bf16 MFMA GEMM, 128x128 tile, BK=64 ----------------
// C[m][n] = sum_k A[m][k] * B[n][k]
// EPI=0: combined zx[m][1280] + dt.  EPI=1: f32 res[m][256].  EPI=2: split zxa/xbc + dt.
// Coalesced LDS-staged epilogues; tn-fastest + XCD-chunk block swizzle.
template <int KDIM, int LDA, int LDB, int EPI>
__global__ __launch_bounds__(256) void k_gemm(const unsigned short* __restrict__ A,
                                              const unsigned short* __restrict__ B,
                                              float* __restrict__ outF,
                                              unsigned short* __restrict__ outBF,
                                              unsigned short* __restrict__ outBF2,
                                              float* __restrict__ dtb, int tilesN) {
  __shared__ __align__(16) short lds[17408];     // 34816 B: As(8192)+Bs(8192) / C-staging
  short* As = lds;
  short* Bs = lds + 8192;
  int nwg = gridDim.x;
  int orig = blockIdx.x;
  int wgid = (nwg & 7) ? orig : ((orig & 7) * (nwg >> 3) + (orig >> 3));
  int tn = wgid % tilesN, tm = wgid / tilesN;
  int m0 = tm * 128, n0 = tn * 128;
  int tid = threadIdx.x;
  int w = tid >> 6, lane = tid & 63;
  int wr = w >> 1, wc = w & 1;
  f32x4 acc[4][4];
  for (int i = 0; i < 4; i++)
    for (int j = 0; j < 4; j++) acc[i][j] = fz4();

  for (int kt = 0; kt < KDIM / 64; kt++) {
    int k0 = kt * 64;
    for (int i = 0; i < 4; i++) {
      int rowblk = w * 32 + i * 8;
      int row = rowblk + (lane >> 3);
      int kc = (lane & 7) * 8;
      const unsigned short* ga = A + (size_t)(m0 + row) * LDA + k0 + kc;
      __builtin_amdgcn_global_load_lds((const __attribute__((address_space(1))) unsigned int*)ga,
                                       (__attribute__((address_space(3))) unsigned int*)&As[rowblk * 64],
                                       16, 0, 0);
      const unsigned short* gb = B + (size_t)(n0 + row) * LDB + k0 + kc;
      __builtin_amdgcn_global_load_lds((const __attribute__((address_space(1))) unsigned int*)gb,
                                       (__attribute__((address_space(3))) unsigned int*)&Bs[rowblk * 64],
                                       16, 0, 0);
    }
    __syncthreads();
    for (int kk = 0; kk < 64; kk += 32) {
      bf16x8 af[4], bfr[4];
      for (int mi = 0; mi < 4; mi++)
        af[mi] = *(const bf16x8*)&As[(wr * 64 + mi * 16 + (lane & 15)) * 64 + kk + (lane >> 4) * 8];
      for (int ni = 0; ni < 4; ni++)
        bfr[ni] = *(const bf16x8*)&Bs[(wc * 64 + ni * 16 + (lane & 15)) * 64 + kk + (lane >> 4) * 8];
      for (int mi = 0; mi < 4; mi++)
        for (int ni = 0; ni < 4; ni++)
          acc[mi][ni] = __builtin_amdgcn_mfma_f32_16x16x32_bf16(af[mi], bfr[ni], acc[mi][ni], 0, 0, 0);
    }
    __syncthreads();
  }

  int fq = lane >> 4, fr = lane & 15;
  if constexpr (EPI == 1) {
    // f32 output: two 128x64 passes staged in LDS (stride 68 f32 = 272 B)
    float* Cf = (float*)lds;
    for (int ph = 0; ph < 2; ph++) {
      if (ph) __syncthreads();
      if (wc == ph) {
        for (int mi = 0; mi < 4; mi++)
          for (int ni = 0; ni < 4; ni++)
            for (int j = 0; j < 4; j++)
              Cf[(wr * 64 + mi * 16 + fq * 4 + j) * 68 + ni * 16 + fr] = acc[mi][ni][j];
      }
      __syncthreads();
      int rr = tid >> 4, cc = (tid & 15) * 4;
      for (int it = 0; it < 8; it++) {
        int r = it * 16 + rr;
        float4 v = *(const float4*)&Cf[r * 68 + cc];
        *(float4*)&outF[(size_t)(m0 + r) * 256 + n0 + ph * 64 + cc] = v;
      }
    }
  } else {
    bool dttile = (n0 >= 1280);
    if (dttile) {
      // only columns 1280..1283 are live (dt, f32)
      if (wc == 0 && fr < 4) {
        for (int mi = 0; mi < 4; mi++)
          for (int j = 0; j < 4; j++) {
            int m = m0 + wr * 64 + mi * 16 + fq * 4 + j;
            dtb[m * 4 + fr] = acc[mi][0][j];
          }
      }
    } else {
      // bf16 tile staged in LDS (stride 136 shorts = 272 B), then 16B/lane stores
      short* Ct = lds;
      for (int mi = 0; mi < 4; mi++)
        for (int ni = 0; ni < 4; ni++)
          for (int j = 0; j < 4; j++)
            Ct[(wr * 64 + mi * 16 + fq * 4 + j) * 136 + wc * 64 + ni * 16 + fr] =
                (short)f2bf(acc[mi][ni][j]);
      __syncthreads();
      int rr = tid >> 4, cc = (tid & 15) * 8;
      for (int it = 0; it < 8; it++) {
        int r = it * 16 + rr;
        uint4 v = *(const uint4*)&Ct[r * 136 + cc];
        if constexpr (EPI == 0) {
          *(uint4*)&outBF[(size_t)(m0 + r) * 1280 + n0 + cc] = v;
        } else {
          if (n0 < 768) *(uint4*)&outBF[(size_t)(m0 + r) * 768 + n0 + cc] = v;
          else *(uint4*)&outBF2[(size_t)(m0 + r) * 512 + (n0 - 768) + cc] = v;
        }
      }
    }
  }
}

// ---------------- depthwise causal conv (4 taps) + SiLU ----------------
__global__ __launch_bounds__(256) void k_conv(const unsigned short* __restrict__ src, int stride,
                                              const float* __restrict__ conv_w,
                                              const float* __restrict__ conv_b,
                                              unsigned short* __restrict__ xs,
                                              unsigned short* __restrict__ bc) {
  __shared__ __align__(16) unsigned short xt[35 * 512];
  int bid = blockIdx.x;
  int b = bid >> 7;
  int t0 = (bid & 127) * 32;
  int tid = threadIdx.x;
  for (int id = tid; id < 35 * 64; id += 256) {
    int r = id >> 6, ch = id & 63;
    int t = t0 - 3 + r;
    float4 v;
    if (t < 0) v = make_float4(0.f, 0.f, 0.f, 0.f);
    else v = *(const float4*)&src[(size_t)(b * LSEQ + t) * stride + ch * 8];
    *(float4*)&xt[r * 512 + ch * 8] = v;
  }
  __syncthreads();
  int c0 = tid, c1 = tid + 256;
  float w0[4], w1[4];
  for (int k = 0; k < 4; k++) { w0[k] = conv_w[c0 * 4 + k]; w1[k] = conv_w[c1 * 4 + k]; }
  float bb0 = conv_b[c0], bb1 = conv_b[c1];
  for (int tl = 0; tl < 32; tl++) {
    float a0 = bb0, a1 = bb1;
    for (int k = 0; k < 4; k++) {
      a0 += bf2f(xt[(tl + k) * 512 + c0]) * w0[k];
      a1 += bf2f(xt[(tl + k) * 512 + c1]) * w1[k];
    }
    a0 = silu(a0); a1 = silu(a1);
    size_t row = (size_t)(b * LSEQ + t0 + tl);
    xs[row * 256 + c0] = f2bf(a0);
    bc[row * 256 + (c1 - 256)] = f2bf(a1);
  }
}

// ---------------- OLD sequential scan (ws fallback) ----------------
__global__ __launch_bounds__(256) void k_scan(const unsigned short* __restrict__ xs,
                                              const unsigned short* __restrict__ bc,
                                              const float* __restrict__ dtb,
                                              const float* __restrict__ dt_bias,
                                              const float* __restrict__ A_log,
                                              const float* __restrict__ Dp,
                                              unsigned short* __restrict__ y) {
  __shared__ __align__(16) unsigned short bcl[32 * 256];
  __shared__ float xsl[32][4];
  __shared__ float dtl[32], dal[32];
  int bid = blockIdx.x;
  int b = bid >> 6;
  int h = (bid >> 4) & 3;
  int pg = bid & 15;
  int tid = threadIdx.x, w = tid >> 6, lane = tid & 63;
  int p = pg * 4 + w;
  float Ah = -expf(A_log[h]);
  float Dh = Dp[h];
  float bias = dt_bias[h];
  float h0 = 0.f, h1 = 0.f;
  for (int t0 = 0; t0 < LSEQ; t0 += 32) {
    for (int id = tid; id < 32 * 32; id += 256) {
      int r = id >> 5, ch = id & 31;
      *(float4*)&bcl[r * 256 + ch * 8] =
          *(const float4*)&bc[(size_t)(b * LSEQ + t0 + r) * 256 + ch * 8];
    }
    if (tid < 128) {
      int r = tid >> 2, pp = tid & 3;
      xsl[r][pp] = bf2f(xs[(size_t)(b * LSEQ + t0 + r) * 256 + h * 64 + pg * 4 + pp]);
    } else if (tid < 160) {
      int r = tid - 128;
      float v = dtb[(size_t)(b * LSEQ + t0 + r) * 4 + h] + bias;
      float dt = (v > 20.f) ? v : log1pf(expf(v));
      dtl[r] = dt;
      dal[r] = expf(dt * Ah);
    }
    __syncthreads();
    for (int tl = 0; tl < 32; tl++) {
      float dtv = dtl[tl], dav = dal[tl], xv = xsl[tl][w];
      float bn  = bf2f(bcl[tl * 256 + lane]);
      float bn2 = bf2f(bcl[tl * 256 + 64 + lane]);
      float cn  = bf2f(bcl[tl * 256 + 128 + lane]);
      float cn2 = bf2f(bcl[tl * 256 + 192 + lane]);
      float coef = dtv * xv;
      h0 = h0 * dav + coef * bn;
      h1 = h1 * dav + coef * bn2;
      float part = h0 * cn + h1 * cn2;
      for (int off = 32; off; off >>= 1) part += __shfl_xor(part, off, 64);
      if (lane == 0)
        y[(size_t)(b * LSEQ + t0 + tl) * 256 + h * 64 + p] = f2bf(part + Dh * xv);
    }
    __syncthreads();
  }
}

// ---------------- dt precompute: softplus + within-chunk cumsum of dt*A ----------------
__global__ __launch_bounds__(64) void k_dtpre(const float* __restrict__ dtraw,
                                              const float* __restrict__ dt_bias,
                                              const float* __restrict__ A_log,
                                              float* __restrict__ dts, float* __restrict__ cums) {
  int bid = blockIdx.x;               // bh*64 + c
  int bh = bid >> 6, c = bid & 63;
  int b = bh >> 2, h = bh & 3;
  int lane = threadIdx.x;
  int t = c * 64 + lane;
  float v = dtraw[(size_t)(b * LSEQ + t) * 4 + h] + dt_bias[h];
  float dt = (v > 20.f) ? v : log1pf(expf(v));
  float Ah = -expf(A_log[h]);
  float s = dt * Ah;
  for (int off = 1; off < 64; off <<= 1) {
    float o = __shfl_up(s, off, 64);
    if (lane >= off) s += o;
  }
  dts[bh * LSEQ + t] = dt;
  cums[bh * LSEQ + t] = s;
}

// ---------------- chunk phase A: G=C·B^T, mask, Y_intra=M·X, ST=X^T·Bsc ----------------
// grid: bh*64 + c (2048 blocks), 256 threads (4 waves)
__global__ __launch_bounds__(256) void k_chunkA(const unsigned short* __restrict__ bc,
                                                const unsigned short* __restrict__ xs,
                                                const float* __restrict__ dts,
                                                const float* __restrict__ cums,
                                                float* __restrict__ ST,
                                                unsigned short* __restrict__ yb) {
  __shared__ __align__(16) unsigned short Cs[64 * 128];
  __shared__ __align__(16) unsigned short Bsm[64 * 128];
  __shared__ __align__(16) unsigned short Bt[128 * 64];
  __shared__ __align__(16) unsigned short Xt[64 * 64];
  __shared__ __align__(16) unsigned short Ms[64 * 72];   // M (stride 128B) / y-staging (stride 144B)
  __shared__ float dtl[64], cuml[64];
  int bid = blockIdx.x;
  int bh = bid >> 6, c = bid & 63;
  int b = bh >> 2, h = bh & 3;
  int m0 = b * LSEQ + c * 64;
  int tid = threadIdx.x, w = tid >> 6, lane = tid & 63;

  if (tid < 64) {
    dtl[tid] = dts[bh * LSEQ + c * 64 + tid];
    cuml[tid] = cums[bh * LSEQ + c * 64 + tid];
  }
  __syncthreads();
  float cumQ = cuml[63];

  for (int it = 0; it < 4; it++) {
    int idx = it * 256 + tid;
    int row = idx >> 4, g = idx & 15;
    int sg = g ^ (row & 7);
    uint4 vC = *(const uint4*)&bc[(size_t)(m0 + row) * 256 + 128 + g * 8];
    *(uint4*)((char*)Cs + row * 256 + sg * 16) = vC;
    uint4 vB = *(const uint4*)&bc[(size_t)(m0 + row) * 256 + g * 8];
    *(uint4*)((char*)Bsm + row * 256 + sg * 16) = vB;
    float sc = dtl[row] * expf(cumQ - cuml[row]);
    const unsigned short* pv = (const unsigned short*)&vB;
    for (int e = 0; e < 8; e++) {
      int n = g * 8 + e;
      *(unsigned short*)((char*)Bt + n * 128 + (((row >> 3) ^ (n & 7)) << 4) + ((row & 7) << 1)) =
          f2bf(bf2f(pv[e]) * sc);
    }
  }
  for (int it = 0; it < 2; it++) {
    int idx = it * 256 + tid;
    int row = idx >> 3, g = idx & 7;
    uint4 vX = *(const uint4*)&xs[(size_t)(m0 + row) * 256 + h * 64 + g * 8];
    const unsigned short* pv = (const unsigned short*)&vX;
    for (int e = 0; e < 8; e++) {
      int p = g * 8 + e;
      *(unsigned short*)((char*)Xt + p * 128 + (((row >> 3) ^ (p & 7)) << 4) + ((row & 7) << 1)) = pv[e];
    }
  }
  __syncthreads();

  // GEMM1: G = C · B^T
  f32x4 acc1[4];
#pragma unroll
  for (int i = 0; i < 4; i++) acc1[i] = fz4();
#pragma unroll
  for (int ks = 0; ks < 4; ks++) {
    int g = ks * 4 + (lane >> 4);
    int rt = w * 16 + (lane & 15);
    bf16x8 a = *(const bf16x8*)((char*)Cs + rt * 256 + ((g ^ (rt & 7)) << 4));
#pragma unroll
    for (int ni = 0; ni < 4; ni++) {
      int rs = ni * 16 + (lane & 15);
      bf16x8 bfr = *(const bf16x8*)((char*)Bsm + rs * 256 + ((g ^ (rs & 7)) << 4));
      acc1[ni] = __builtin_amdgcn_mfma_f32_16x16x32_bf16(a, bfr, acc1[ni], 0, 0, 0);
    }
  }
#pragma unroll
  for (int ni = 0; ni < 4; ni++)
#pragma unroll
    for (int j = 0; j < 4; j++) {
      int t = w * 16 + (lane >> 4) * 4 + j;
      int s = ni * 16 + (lane & 15);
      float v = 0.f;
      if (t >= s) v = acc1[ni][j] * expf(cuml[t] - cuml[s]) * dtl[s];
      *(unsigned short*)((char*)Ms + t * 128 + (((s >> 3) ^ (t & 7)) << 4) + ((s & 7) << 1)) = f2bf(v);
    }
  __syncthreads();

  // GEMM2: Y_intra = M · X   and GEMM3: ST[p][n] = X^T · Bsc
  f32x4 acc2[4], acc3[8];
#pragma unroll
  for (int i = 0; i < 4; i++) acc2[i] = fz4();
#pragma unroll
  for (int i = 0; i < 8; i++) acc3[i] = fz4();
#pragma unroll
  for (int ks = 0; ks < 2; ks++) {
    int g = ks * 4 + (lane >> 4);
    bf16x8 xf[4];
#pragma unroll
    for (int ni = 0; ni < 4; ni++) {
      int rp = ni * 16 + (lane & 15);
      xf[ni] = *(const bf16x8*)((char*)Xt + rp * 128 + ((g ^ (rp & 7)) << 4));
    }
    {
      int rt = w * 16 + (lane & 15);
      bf16x8 a = *(const bf16x8*)((char*)Ms + rt * 128 + ((g ^ (rt & 7)) << 4));
#pragma unroll
      for (int ni = 0; ni < 4; ni++)
        acc2[ni] = __builtin_amdgcn_mfma_f32_16x16x32_bf16(a, xf[ni], acc2[ni], 0, 0, 0);
    }
    {
      bf16x8 a3 = xf[w];
#pragma unroll
      for (int ni = 0; ni < 8; ni++) {
        int rn = ni * 16 + (lane & 15);
        bf16x8 bfr = *(const bf16x8*)((char*)Bt + rn * 128 + ((g ^ (rn & 7)) << 4));
        acc3[ni] = __builtin_amdgcn_mfma_f32_16x16x32_bf16(a3, bfr, acc3[ni], 0, 0, 0);
      }
    }
  }
  // ---- epilogue: stage y tile in LDS, coalesced 16B stores ----
  __syncthreads();
#pragma unroll
  for (int ni = 0; ni < 4; ni++)
#pragma unroll
    for (int j = 0; j < 4; j++) {
      int t = w * 16 + (lane >> 4) * 4 + j;
      int p = ni * 16 + (lane & 15);
      Ms[t * 72 + p] = f2bf(acc2[ni][j]);
    }
  float* stp = ST + ((size_t)bid << 13);
#pragma unroll
  for (int ni = 0; ni < 8; ni++)
#pragma unroll
    for (int j = 0; j < 4; j++) {
      int p = w * 16 + (lane >> 4) * 4 + j;
      int n = ni * 16 + (lane & 15);
      stp[p * 128 + n] = acc3[ni][j];
    }
  __syncthreads();
  {
    int rr = tid >> 3, cc = (tid & 7) * 8;
    for (int it = 0; it < 2; it++) {
      int t = it * 32 + rr;
      uint4 v = *(const uint4*)&Ms[t * 72 + cc];
      *(uint4*)&yb[(size_t)(m0 + t) * 256 + h * 64 + cc] = v;
    }
  }
}

// ---------------- chunk phase B: sequential state carry ----------------
__global__ __launch_bounds__(256) void k_chunkB(const float* __restrict__ ST,
                                                const float* __restrict__ cums,
                                                unsigned short* __restrict__ HT) {
  int bid = blockIdx.x;
  int bh = bid >> 3, psl = bid & 7;
  int p = psl * 8 + (threadIdx.x >> 5);
  int n0 = (threadIdx.x & 31) * 4;
  float H[4] = {0.f, 0.f, 0.f, 0.f};
  for (int c = 0; c < 64; c++) {
    size_t base = (size_t)(bh * 64 + c);
    ushort4 hv;
    unsigned short* ha = (unsigned short*)&hv;
#pragma unroll
    for (int e = 0; e < 4; e++) ha[e] = f2bf(H[e]);
    *(ushort4*)&HT[(base * 64 + p) * 128 + n0] = hv;
    float4 s4 = *(const float4*)&ST[(base << 13) + p * 128 + n0];
    float dec = expf(cums[bh * LSEQ + c * 64 + 63]);
    H[0] = H[0] * dec + s4.x;
    H[1] = H[1] * dec + s4.y;
    H[2] = H[2] * dec + s4.z;
    H[3] = H[3] * dec + s4.w;
  }
}

// ---------------- chunk phase C: Y += exp(cum)·C·Hstart + D·x ----------------
__global__ __launch_bounds__(256) void k_chunkC(const unsigned short* __restrict__ bc,
                                                const unsigned short* __restrict__ xs,
                                                const unsigned short* __restrict__ HT,
                                                const float* __restrict__ cums,
                                                const float* __restrict__ Dp,
                                                unsigned short* __restrict__ yb) {
  __shared__ __align__(16) unsigned short Cse[64 * 128];
  __shared__ __align__(16) unsigned short Hs[64 * 128];
  __shared__ __align__(16) unsigned short yst[64 * 72];
  int bid = blockIdx.x;
  int bh = bid >> 6, c = bid & 63;
  int b = bh >> 2, h = bh & 3;
  int m0 = b * LSEQ + c * 64;
  int tid = threadIdx.x, w = tid >> 6, lane = tid & 63;
  float Dh = Dp[h];
  for (int it = 0; it < 4; it++) {
    int idx = it * 256 + tid;
    int row = idx >> 4, g = idx & 15;
    int sg = g ^ (row & 7);
    float ex = expf(cums[bh * LSEQ + c * 64 + row]);
    uint4 vC = *(const uint4*)&bc[(size_t)(m0 + row) * 256 + 128 + g * 8];
    const unsigned short* pc = (const unsigned short*)&vC;
    uint4 vo;
    unsigned short* po = (unsigned short*)&vo;
#pragma unroll
    for (int e = 0; e < 8; e++) po[e] = f2bf(bf2f(pc[e]) * ex);
    *(uint4*)((char*)Cse + row * 256 + sg * 16) = vo;
    uint4 vH = *(const uint4*)&HT[((size_t)(bh * 64 + c) * 64 + row) * 128 + g * 8];
    *(uint4*)((char*)Hs + row * 256 + sg * 16) = vH;
  }
  __syncthreads();
  f32x4 acc[4];
#pragma unroll
  for (int i = 0; i < 4; i++) acc[i] = fz4();
#pragma unroll
  for (int ks = 0; ks < 4; ks++) {
    int g = ks * 4 + (lane >> 4);
    int rt = w * 16 + (lane & 15);
    bf16x8 a = *(const bf16x8*)((char*)Cse + rt * 256 + ((g ^ (rt & 7)) << 4));
#pragma unroll
    for (int ni = 0; ni < 4; ni++) {
      int rp = ni * 16 + (lane & 15);
      bf16x8 bfr = *(const bf16x8*)((char*)Hs + rp * 256 + ((g ^ (rp & 7)) << 4));
      acc[ni] = __builtin_amdgcn_mfma_f32_16x16x32_bf16(a, bfr, acc[ni], 0, 0, 0);
    }
  }
  // stage acc, then coalesced RMW (+= y_intra + D*x)
#pragma unroll
  for (int ni = 0; ni < 4; ni++)
#pragma unroll
    for (int j = 0; j < 4; j++) {
      int t = w * 16 + (lane >> 4) * 4 + j;
      int p = ni * 16 + (lane & 15);
      yst[t * 72 + p] = f2bf(acc[ni][j]);
    }
  __syncthreads();
  {
    int rr = tid >> 3, cc = (tid & 7) * 8;
    for (int it = 0; it < 2; it++) {
      int t = it * 32 + rr;
      size_t off = (size_t)(m0 + t) * 256 + h * 64 + cc;
      uint4 yo = *(const uint4*)&yb[off];
      uint4 xv = *(const uint4*)&xs[off];
      const unsigned short* pyo = (const unsigned short*)&yo;
      const unsigned short* pxv = (const unsigned short*)&xv;
      const unsigned short* pys = &yst[t * 72 + cc];
      uint4 vo;
      unsigned short* po = (unsigned short*)&vo;
#pragma unroll
      for (int e = 0; e < 8; e++)
        po[e] = f2bf(bf2f(pyo[e]) + bf2f(pys[e]) + Dh * bf2f(pxv[e]));
      *(uint4*)&yb[off] = vo;
    }
  }
}

// ---------------- gate + RMSNorm + concat -> ycat bf16 [m][512] ----------------
__global__ __launch_bounds__(256) void k_ycat(const unsigned short* __restrict__ y,
                                              const unsigned short* __restrict__ zsrc, int zstride,
                                              const float* __restrict__ norm_w,
                                              unsigned short* __restrict__ ycat) {
  int bid = blockIdx.x;
  int tid = threadIdx.x, w = tid >> 6, lane = tid & 63;
  size_t m = (size_t)bid * 4 + w;
  int j0 = lane * 4;
  ushort4 yv = *(const ushort4*)&y[m * 256 + j0];
  ushort4 zv = *(const ushort4*)&zsrc[m * zstride + 512 + j0];
  unsigned short ya[4] = {yv.x, yv.y, yv.z, yv.w};
  unsigned short za[4] = {zv.x, zv.y, zv.z, zv.w};
  float g[4]; float ssum = 0.f;
  for (int i = 0; i < 4; i++) {
    float gg = bf2f(ya[i]) * silu(bf2f(za[i]));
    g[i] = gg; ssum += gg * gg;
  }
  for (int off = 32; off; off >>= 1) ssum += __shfl_xor(ssum, off, 64);
  float inv = rsqrtf(ssum * (1.f / 256.f) + 1e-5f);
  ushort4 z0v = *(const ushort4*)&zsrc[m * zstride + j0];
  ushort4 x0v = *(const ushort4*)&zsrc[m * zstride + 256 + j0];
  unsigned short z0a[4] = {z0v.x, z0v.y, z0v.z, z0v.w};
  unsigned short x0a[4] = {x0v.x, x0v.y, x0v.z, x0v.w};
  ushort4 o1, o2;
  unsigned short* o1a = (unsigned short*)&o1;
  unsigned short* o2a = (unsigned short*)&o2;
  for (int i = 0; i < 4; i++) {
    o1a[i] = f2bf(silu(bf2f(z0a[i])) * bf2f(x0a[i]));
    o2a[i] = f2bf(g[i] * norm_w[j0 + i] * inv);
  }
  *(ushort4*)&ycat[m * 512 + j0] = o1;
  *(ushort4*)&ycat[m * 512 + 256 + j0] = o2;
}

// ---------------- SE ----------------
__global__ void k_zero(float* __restrict__ p) { p[blockIdx.x * 256 + threadIdx.x] = 0.f; }

__global__ __launch_bounds__(256) void k_semean(const float* __restrict__ res, float* __restrict__ smean) {
  int bid = blockIdx.x;
  int b = bid >> 5, ch = bid & 31;
  int c = threadIdx.x;
  float acc = 0.f;
  for (int r = 0; r < 128; r++)
    acc += res[(size_t)(b * LSEQ + ch * 128 + r) * 256 + c];
  atomicAdd(&smean[b * 256 + c], acc);
}

__global__ __launch_bounds__(512) void k_sefc(const float* __restrict__ smean,
                                              const float* __restrict__ w1, const float* __restrict__ b1,
                                              const float* __restrict__ w2, const float* __restrict__ b2,
                                              float* __restrict__ s2) {
  __shared__ float s1[512];
  int tid = threadIdx.x;
  int b = tid >> 6, j = tid & 63;
  float acc = b1[j];
  for (int k = 0; k < 256; k++) acc += smean[b * 256 + k] * (1.f / 4096.f) * w1[j * 256 + k];
  s1[b * 64 + j] = fmaxf(acc, 0.f);
  __syncthreads();
  for (int idx = tid; idx < 2048; idx += 512) {
    int bb = idx >> 8, c = idx & 255;
    float a2 = b2[c];
    for (int k = 0; k < 64; k++) a2 += s1[bb * 64 + k] * w2[c * 64 + k];
    s2[idx] = 1.f / (1.f + expf(-a2));
  }
}

// ---------------- final: transpose + SE scale ----------------
__global__ __launch_bounds__(256) void k_final(const float* __restrict__ res,
                                               const float* __restrict__ s2,
                                               float* __restrict__ out) {
  __shared__ float t[64][65];
  int bid = blockIdx.x;
  int b = bid >> 8;
  int r = bid & 255;
  int ct = r >> 6, lt = r & 63;
  int c0 = ct * 64, l0 = lt * 64;
  int tid = threadIdx.x, j = tid & 63, i0 = tid >> 6;
  for (int rr = 0; rr < 16; rr++) {
    int i = i0 + rr * 4;
    t[i][j] = res[(size_t)(b * LSEQ + l0 + i) * 256 + c0 + j];
  }
  __syncthreads();
  for (int rr = 0; rr < 16; rr++) {
    int ci = i0 + rr * 4;
    float s = s2[b * 256 + c0 + ci];
    out[(size_t)(b * 256 + c0 + ci) * LSEQ + l0 + j] = t[j][ci] * s;
  }
}

// ---------------- launch ----------------
extern "C" void kernel_launch(void* const* d_in, const int* in_sizes, int n_in,
                              void* d_out, int out_size, void* d_ws, size_t ws_size,
                              hipStream_t stream) {
  const float* x         = (const float*)d_in[0];
  const float* in_proj_w = (const float*)d_in[1];
  const float* conv_w    = (const float*)d_in[2];
  const float* conv_b    = (const float*)d_in[3];
  const float* dt_bias   = (const float*)d_in[4];
  const float* A_log     = (const float*)d_in[5];
  const float* Dp        = (const float*)d_in[6];
  const float* norm_w    = (const float*)d_in[7];
  const float* out_projw = (const float*)d_in[8];
  const float* se_w1     = (const float*)d_in[9];
  const float* se_b1     = (const float*)d_in[10];
  const float* se_w2     = (const float*)d_in[11];
  const float* se_b2     = (const float*)d_in[12];
  float* out = (float*)d_out;
  char* ws = (char*)d_ws;

  const size_t NEED_CHUNKED = 220676096;

  if (ws_size >= NEED_CHUNKED) {
    unsigned short* ubf   = (unsigned short*)(ws + 0);
    unsigned short* xbc   = (unsigned short*)(ws + 16777216);
    unsigned short* ycat  = (unsigned short*)(ws + 50331648);
    float*          ST    = (float*)(ws + 0);
    float*          res   = (float*)(ws + 0);
    unsigned short* zxa   = (unsigned short*)(ws + 83886080);
    unsigned short* xsb   = (unsigned short*)(ws + 134217728);
    unsigned short* bcb   = (unsigned short*)(ws + 150994944);
    unsigned short* HT    = (unsigned short*)(ws + 167772160);
    unsigned short* ybuf  = (unsigned short*)(ws + 201326592);
    unsigned short* wpad  = (unsigned short*)(ws + 218103808);
    unsigned short* woutb = (unsigned short*)(ws + 218824704);
    float*          dtraw = (float*)(ws + 219086848);
    float*          dts   = (float*)(ws + 219611136);
    float*          cums  = (float*)(ws + 220135424);
    float*          smean = (float*)(ws + 220659712);
    float*          s2    = (float*)(ws + 220667904);

    k_prep_w<<<1920, 256, 0, stream>>>(in_proj_w, out_projw, wpad, woutb);
    k_transpose_x<<<2048, 256, 0, stream>>>(x, ubf);
    k_gemm<256, 256, 256, 2><<<256 * 11, 256, 0, stream>>>(ubf, wpad, nullptr, zxa, xbc, dtraw, 11);
    k_conv<<<1024, 256, 0, stream>>>(xbc, 512, conv_w, conv_b, xsb, bcb);
    k_dtpre<<<2048, 64, 0, stream>>>(dtraw, dt_bias, A_log, dts, cums);
    k_chunkA<<<2048, 256, 0, stream>>>(bcb, xsb, dts, cums, ST, ybuf);
    k_chunkB<<<256, 256, 0, stream>>>(ST, cums, HT);
    k_chunkC<<<2048, 256, 0, stream>>>(bcb, xsb, HT, cums, Dp, ybuf);
    k_ycat<<<8192, 256, 0, stream>>>(ybuf, zxa, 768, norm_w, ycat);
    k_gemm<512, 512, 512, 1><<<256 * 2, 256, 0, stream>>>(ycat, woutb, res, nullptr, nullptr, nullptr, 2);
    k_zero<<<8, 256, 0, stream>>>(smean);
    k_semean<<<256, 256, 0, stream>>>(res, smean);
    k_sefc<<<1, 512, 0, stream>>>(smean, se_w1, se_b1, se_w2, se_b2, s2);
    k_final<<<2048, 256, 0, stream>>>(res, s2, out);
  } else {
    unsigned short* ubf   = (unsigned short*)(ws + 0);
    unsigned short* xsb   = (unsigned short*)(ws + 16777216);
    float*          res   = (float*)(ws + 0);
    unsigned short* bcb   = (unsigned short*)(ws + 33554432);
    unsigned short* zx    = (unsigned short*)(ws + 50331648);
    float*          dtb   = (float*)(ws + 134217728);
    unsigned short* ybuf  = (unsigned short*)(ws + 134742016);
    unsigned short* ycat  = (unsigned short*)(ws + 151519232);
    unsigned short* wpad  = (unsigned short*)(ws + 185073664);
    unsigned short* woutb = (unsigned short*)(ws + 185794560);
    float*          smean = (float*)(ws + 186056704);
    float*          s2    = (float*)(ws + 186064896);

    k_prep_w<<<1920, 256, 0, stream>>>(in_proj_w, out_projw, wpad, woutb);
    k_transpose_x<<<2048, 256, 0, stream>>>(x, ubf);
    k_gemm<256, 256, 256, 0><<<256 * 11, 256, 0, stream>>>(ubf, wpad, nullptr, zx, nullptr, dtb, 11);
    k_conv<<<1024, 256, 0, stream>>>(zx + 768, 1280, conv_w, conv_b, xsb, bcb);
    k_scan<<<512, 256, 0, stream>>>(xsb, bcb, dtb, dt_bias, A_log, Dp, ybuf);
    k_ycat<<<8192, 256, 0, stream>>>(ybuf, zx, 1280, norm_w, ycat);
    k_gemm<512, 512, 512, 1><<<256 * 2, 256, 0, stream>>>(ycat, woutb, res, nullptr, nullptr, nullptr, 2);
    k_zero<<<8, 256, 0, stream>>>(smean);
    k_semean<<<256, 256, 0, stream>>>(res, smean);
    k_sefc<<<1, 512, 0, stream>>>(smean, se_w1, se_b1, se_w2, se_b2, s2);
    k_final<<<2048, 256, 0, stream>>>(res, s2, out);
  }
}

// Round 4
// 236.134 us; speedup vs baseline: 6.4492x; 1.0681x over previous
//
#include <hip/hip_runtime.h>
#include <stdint.h>

// ---------------- types / helpers ----------------
typedef __attribute__((ext_vector_type(8))) short bf16x8;
typedef __attribute__((ext_vector_type(4))) float f32x4;

__device__ __forceinline__ float bf2f(unsigned short u) {
  unsigned int x = ((unsigned int)u) << 16;
  return __builtin_bit_cast(float, x);
}
__device__ __forceinline__ unsigned short f2bf(float f) {
  unsigned int x = __builtin_bit_cast(unsigned int, f);
  unsigned int r = x + 0x7FFFu + ((x >> 16) & 1u);
  return (unsigned short)(r >> 16);
}
__device__ __forceinline__ float silu(float v) { return v / (1.f + __expf(-v)); }
__device__ __forceinline__ f32x4 fz4() { f32x4 z; z[0]=0.f; z[1]=0.f; z[2]=0.f; z[3]=0.f; return z; }

#define LSEQ 4096
#define DMODEL 256
#define NIN 1284
#define NINP 1408   // padded to 11*128

// ---------------- weight prep (cast to bf16, pad, interleave z0/x0 rows) ----------------
// wpad row r: r<512 -> (r odd ? x0_{r/2} (src 256+r/2) : z0_{r/2} (src r/2)); else src=r.
__global__ void k_prep_w(const float* __restrict__ w_in, const float* __restrict__ w_out,
                         unsigned short* __restrict__ wpad, unsigned short* __restrict__ woutbf) {
  int idx = blockIdx.x * 256 + threadIdx.x;
  const int tot1 = NINP * DMODEL;           // 360448
  if (idx < tot1) {
    int n = idx / DMODEL, k = idx % DMODEL;
    int src = (n < 512) ? ((n & 1) ? 256 + (n >> 1) : (n >> 1)) : n;
    float v = (src < NIN) ? w_in[src * DMODEL + k] : 0.f;
    wpad[idx] = f2bf(v);
  } else {
    int j = idx - tot1;                      // 256*512 = 131072
    woutbf[j] = f2bf(w_out[j]);
  }
}

// ---------------- transpose x (B,C,L) -> u[m][k] bf16 ----------------
__global__ __launch_bounds__(256) void k_transpose_x(const float* __restrict__ x,
                                                     unsigned short* __restrict__ ubf) {
  __shared__ float t[64][65];
  int bid = blockIdx.x;                // 8 * 64 * 4
  int b = bid >> 8;
  int r = bid & 255;
  int lt = r >> 2, kt = r & 3;
  int l0 = lt * 64, k0 = kt * 64;
  int tid = threadIdx.x;
  int j = tid & 63, i0 = tid >> 6;
  for (int rr = 0; rr < 16; rr++) {
    int ki = i0 + rr * 4;
    t[ki][j] = x[(size_t)(b * DMODEL + k0 + ki) * LSEQ + l0 + j];
  }
  __syncthreads();
  for (int rr = 0; rr < 16; rr++) {
    int li = i0 + rr * 4;
    ubf[(size_t)(b * LSEQ + l0 + li) * DMODEL + k0 + j] = f2bf(t[j][li]);
  }
}

// ---------------- m97-style bf16 MFMA GEMM, 128x128 tile, BK=64 ----------------
// C[m][n] = sum_k A[m][k] * B[n][k]
// EPI=0 (fallback): combined zx[m][1280] (z0/x0 interleaved in cols 0..511) + dt
// EPI=1: f32 res[m][256]
// EPI=2 (chunked): zc=silu(z0)*x0 -> zcat[m][512] cols 0..255; z -> zbuf[m][256];
//                  xBC -> xbc[m][512] (via outF cast); dt -> dtb
template <int KDIM, int LDA, int LDB, int EPI>
__global__ __launch_bounds__(256) void k_gemm(const unsigned short* __restrict__ A,
                                              const unsigned short* __restrict__ B,
                                              float* __restrict__ outF,
                                              unsigned short* __restrict__ outBF,
                                              unsigned short* __restrict__ outBF2,
                                              float* __restrict__ dtb, int tilesN) {
  __shared__ __align__(16) short lds[17408];     // 34816 B
  short* As = lds;
  short* Bs = lds + 8192;
  int nwg = gridDim.x;
  int orig = blockIdx.x;
  int wgid = (nwg & 7) ? orig : ((orig & 7) * (nwg >> 3) + (orig >> 3));
  int tn = wgid % tilesN, tm = wgid / tilesN;
  int m0 = tm * 128, n0 = tn * 128;
  int tid = threadIdx.x;
  int w = tid >> 6, lane = tid & 63;
  int wr = w >> 1, wc = w & 1;
  f32x4 acc[4][4];
  for (int i = 0; i < 4; i++)
    for (int j = 0; j < 4; j++) acc[i][j] = fz4();

  for (int kt = 0; kt < KDIM / 64; kt++) {
    int k0 = kt * 64;
    for (int i = 0; i < 4; i++) {
      int rowblk = w * 32 + i * 8;
      int row = rowblk + (lane >> 3);
      int kc = (lane & 7) * 8;
      const unsigned short* ga = A + (size_t)(m0 + row) * LDA + k0 + kc;
      __builtin_amdgcn_global_load_lds((const __attribute__((address_space(1))) unsigned int*)ga,
                                       (__attribute__((address_space(3))) unsigned int*)&As[rowblk * 64],
                                       16, 0, 0);
      const unsigned short* gb = B + (size_t)(n0 + row) * LDB + k0 + kc;
      __builtin_amdgcn_global_load_lds((const __attribute__((address_space(1))) unsigned int*)gb,
                                       (__attribute__((address_space(3))) unsigned int*)&Bs[rowblk * 64],
                                       16, 0, 0);
    }
    __syncthreads();
    for (int kk = 0; kk < 64; kk += 32) {
      bf16x8 af[4], bfr[4];
      for (int mi = 0; mi < 4; mi++)
        af[mi] = *(const bf16x8*)&As[(wr * 64 + mi * 16 + (lane & 15)) * 64 + kk + (lane >> 4) * 8];
      for (int ni = 0; ni < 4; ni++)
        bfr[ni] = *(const bf16x8*)&Bs[(wc * 64 + ni * 16 + (lane & 15)) * 64 + kk + (lane >> 4) * 8];
      for (int mi = 0; mi < 4; mi++)
        for (int ni = 0; ni < 4; ni++)
          acc[mi][ni] = __builtin_amdgcn_mfma_f32_16x16x32_bf16(af[mi], bfr[ni], acc[mi][ni], 0, 0, 0);
    }
    __syncthreads();
  }

  int fq = lane >> 4, fr = lane & 15;
  if constexpr (EPI == 1) {
    float* Cf = (float*)lds;
    for (int ph = 0; ph < 2; ph++) {
      if (ph) __syncthreads();
      if (wc == ph) {
        for (int mi = 0; mi < 4; mi++)
          for (int ni = 0; ni < 4; ni++)
            for (int j = 0; j < 4; j++)
              Cf[(wr * 64 + mi * 16 + fq * 4 + j) * 68 + ni * 16 + fr] = acc[mi][ni][j];
      }
      __syncthreads();
      int rr = tid >> 4, cc = (tid & 15) * 4;
      for (int it = 0; it < 8; it++) {
        int r = it * 16 + rr;
        float4 v = *(const float4*)&Cf[r * 68 + cc];
        *(float4*)&outF[(size_t)(m0 + r) * 256 + n0 + ph * 64 + cc] = v;
      }
    }
  } else if constexpr (EPI == 2) {
    unsigned short* xbc = (unsigned short*)outF;
    if (n0 >= 1280) {
      if (wc == 0 && fr < 4) {
        for (int mi = 0; mi < 4; mi++)
          for (int j = 0; j < 4; j++) {
            int m = m0 + wr * 64 + mi * 16 + fq * 4 + j;
            dtb[m * 4 + fr] = acc[mi][0][j];
          }
      }
    } else if (n0 < 512) {
      // zc = silu(z0)*x0 : even fr holds z0, odd fr holds x0 (interleaved rows)
      short* Ct = lds;
      for (int mi = 0; mi < 4; mi++)
        for (int ni = 0; ni < 4; ni++)
          for (int j = 0; j < 4; j++) {
            float v = acc[mi][ni][j];
            float vp = __shfl_xor(v, 1, 64);
            if (!(fr & 1)) {
              float zc = silu(v) * vp;
              Ct[(wr * 64 + mi * 16 + fq * 4 + j) * 72 + wc * 32 + ni * 8 + (fr >> 1)] =
                  (short)f2bf(zc);
            }
          }
      __syncthreads();
      int r = tid >> 1, base = (tid & 1) * 32;
      for (int it = 0; it < 4; it++) {
        int cc = base + it * 8;
        uint4 v = *(const uint4*)&Ct[r * 72 + cc];
        *(uint4*)&outBF[(size_t)(m0 + r) * 512 + (n0 >> 1) + cc] = v;
      }
    } else {
      short* Ct = lds;
      for (int mi = 0; mi < 4; mi++)
        for (int ni = 0; ni < 4; ni++)
          for (int j = 0; j < 4; j++)
            Ct[(wr * 64 + mi * 16 + fq * 4 + j) * 136 + wc * 64 + ni * 16 + fr] =
                (short)f2bf(acc[mi][ni][j]);
      __syncthreads();
      int rr = tid >> 4, cc = (tid & 15) * 8;
      for (int it = 0; it < 8; it++) {
        int r = it * 16 + rr;
        uint4 v = *(const uint4*)&Ct[r * 136 + cc];
        if (n0 < 768) *(uint4*)&outBF2[(size_t)(m0 + r) * 256 + (n0 - 512) + cc] = v;
        else *(uint4*)&xbc[(size_t)(m0 + r) * 512 + (n0 - 768) + cc] = v;
      }
    }
  } else {  // EPI == 0 fallback
    bool dttile = (n0 >= 1280);
    if (dttile) {
      if (wc == 0 && fr < 4) {
        for (int mi = 0; mi < 4; mi++)
          for (int j = 0; j < 4; j++) {
            int m = m0 + wr * 64 + mi * 16 + fq * 4 + j;
            dtb[m * 4 + fr] = acc[mi][0][j];
          }
      }
    } else {
      short* Ct = lds;
      for (int mi = 0; mi < 4; mi++)
        for (int ni = 0; ni < 4; ni++)
          for (int j = 0; j < 4; j++)
            Ct[(wr * 64 + mi * 16 + fq * 4 + j) * 136 + wc * 64 + ni * 16 + fr] =
                (short)f2bf(acc[mi][ni][j]);
      __syncthreads();
      int rr = tid >> 4, cc = (tid & 15) * 8;
      for (int it = 0; it < 8; it++) {
        int r = it * 16 + rr;
        uint4 v = *(const uint4*)&Ct[r * 136 + cc];
        *(uint4*)&outBF[(size_t)(m0 + r) * 1280 + n0 + cc] = v;
      }
    }
  }
}

// ---------------- depthwise causal conv (4 taps) + SiLU; dual-layout outputs ----------------
__global__ __launch_bounds__(256) void k_conv(const unsigned short* __restrict__ src, int stride,
                                              const float* __restrict__ conv_w,
                                              const float* __restrict__ conv_b,
                                              unsigned short* __restrict__ xs,
                                              unsigned short* __restrict__ bc,
                                              unsigned short* __restrict__ xsT,
                                              unsigned short* __restrict__ bT) {
  __shared__ __align__(16) unsigned short xt[35 * 512];
  int bid = blockIdx.x;
  int b = bid >> 7;
  int t0 = (bid & 127) * 32;
  int tid = threadIdx.x;
  for (int id = tid; id < 35 * 64; id += 256) {
    int r = id >> 6, ch = id & 63;
    int t = t0 - 3 + r;
    float4 v;
    if (t < 0) v = make_float4(0.f, 0.f, 0.f, 0.f);
    else v = *(const float4*)&src[(size_t)(b * LSEQ + t) * stride + ch * 8];
    *(float4*)&xt[r * 512 + ch * 8] = v;
  }
  __syncthreads();
  int c0 = tid, c1 = tid + 256;
  float w0[4], w1[4];
  for (int k = 0; k < 4; k++) { w0[k] = conv_w[c0 * 4 + k]; w1[k] = conv_w[c1 * 4 + k]; }
  float bb0 = conv_b[c0], bb1 = conv_b[c1];
  unsigned short xa0[32], xa1[32];
#pragma unroll
  for (int tl = 0; tl < 32; tl++) {
    float a0 = bb0, a1 = bb1;
    for (int k = 0; k < 4; k++) {
      a0 += bf2f(xt[(tl + k) * 512 + c0]) * w0[k];
      a1 += bf2f(xt[(tl + k) * 512 + c1]) * w1[k];
    }
    a0 = silu(a0); a1 = silu(a1);
    unsigned short u0 = f2bf(a0), u1 = f2bf(a1);
    xa0[tl] = u0; xa1[tl] = u1;
    size_t row = (size_t)(b * LSEQ + t0 + tl);
    xs[row * 256 + c0] = u0;
    bc[row * 256 + (c1 - 256)] = u1;
  }
  if (xsT) {
    const uint4* p0 = (const uint4*)xa0;
    for (int k = 0; k < 4; k++)
      *(uint4*)&xsT[((size_t)(b * 256 + c0)) * LSEQ + t0 + k * 8] = p0[k];
    if (c1 < 384) {
      const uint4* p1 = (const uint4*)xa1;
      for (int k = 0; k < 4; k++)
        *(uint4*)&bT[((size_t)(b * 128 + (c1 - 256))) * LSEQ + t0 + k * 8] = p1[k];
    }
  }
}

// ---------------- OLD sequential scan (ws fallback) ----------------
__global__ __launch_bounds__(256) void k_scan(const unsigned short* __restrict__ xs,
                                              const unsigned short* __restrict__ bc,
                                              const float* __restrict__ dtb,
                                              const float* __restrict__ dt_bias,
                                              const float* __restrict__ A_log,
                                              const float* __restrict__ Dp,
                                              unsigned short* __restrict__ y) {
  __shared__ __align__(16) unsigned short bcl[32 * 256];
  __shared__ float xsl[32][4];
  __shared__ float dtl[32], dal[32];
  int bid = blockIdx.x;
  int b = bid >> 6;
  int h = (bid >> 4) & 3;
  int pg = bid & 15;
  int tid = threadIdx.x, w = tid >> 6, lane = tid & 63;
  int p = pg * 4 + w;
  float Ah = -expf(A_log[h]);
  float Dh = Dp[h];
  float bias = dt_bias[h];
  float h0 = 0.f, h1 = 0.f;
  for (int t0 = 0; t0 < LSEQ; t0 += 32) {
    for (int id = tid; id < 32 * 32; id += 256) {
      int r = id >> 5, ch = id & 31;
      *(float4*)&bcl[r * 256 + ch * 8] =
          *(const float4*)&bc[(size_t)(b * LSEQ + t0 + r) * 256 + ch * 8];
    }
    if (tid < 128) {
      int r = tid >> 2, pp = tid & 3;
      xsl[r][pp] = bf2f(xs[(size_t)(b * LSEQ + t0 + r) * 256 + h * 64 + pg * 4 + pp]);
    } else if (tid < 160) {
      int r = tid - 128;
      float v = dtb[(size_t)(b * LSEQ + t0 + r) * 4 + h] + bias;
      float dt = (v > 20.f) ? v : log1pf(expf(v));
      dtl[r] = dt;
      dal[r] = expf(dt * Ah);
    }
    __syncthreads();
    for (int tl = 0; tl < 32; tl++) {
      float dtv = dtl[tl], dav = dal[tl], xv = xsl[tl][w];
      float bn  = bf2f(bcl[tl * 256 + lane]);
      float bn2 = bf2f(bcl[tl * 256 + 64 + lane]);
      float cn  = bf2f(bcl[tl * 256 + 128 + lane]);
      float cn2 = bf2f(bcl[tl * 256 + 192 + lane]);
      float coef = dtv * xv;
      h0 = h0 * dav + coef * bn;
      h1 = h1 * dav + coef * bn2;
      float part = h0 * cn + h1 * cn2;
      for (int off = 32; off; off >>= 1) part += __shfl_xor(part, off, 64);
      if (lane == 0)
        y[(size_t)(b * LSEQ + t0 + tl) * 256 + h * 64 + p] = f2bf(part + Dh * xv);
    }
    __syncthreads();
  }
}

// ---------------- dt precompute ----------------
__global__ __launch_bounds__(64) void k_dtpre(const float* __restrict__ dtraw,
                                              const float* __restrict__ dt_bias,
                                              const float* __restrict__ A_log,
                                              float* __restrict__ dts, float* __restrict__ cums) {
  int bid = blockIdx.x;
  int bh = bid >> 6, c = bid & 63;
  int b = bh >> 2, h = bh & 3;
  int lane = threadIdx.x;
  int t = c * 64 + lane;
  float v = dtraw[(size_t)(b * LSEQ + t) * 4 + h] + dt_bias[h];
  float dt = (v > 20.f) ? v : log1pf(expf(v));
  float Ah = -expf(A_log[h]);
  float s = dt * Ah;
  for (int off = 1; off < 64; off <<= 1) {
    float o = __shfl_up(s, off, 64);
    if (lane >= off) s += o;
  }
  dts[bh * LSEQ + t] = dt;
  cums[bh * LSEQ + t] = s;
}

// ---------------- chunk phase A ----------------
// grid: bh*64 + c (2048 blocks), 256 threads
__global__ __launch_bounds__(256) void k_chunkA(const unsigned short* __restrict__ bc,
                                                const unsigned short* __restrict__ xsT,
                                                const unsigned short* __restrict__ bT,
                                                const float* __restrict__ dts,
                                                const float* __restrict__ cums,
                                                float* __restrict__ ST,
                                                unsigned short* __restrict__ yb) {
  __shared__ __align__(16) unsigned short Bsm[64 * 128];  // token-major B
  __shared__ __align__(16) unsigned short BTs[128 * 64];  // ch-major scaled B
  __shared__ __align__(16) unsigned short XT[64 * 64];    // ch-major X
  __shared__ __align__(16) unsigned short Ms[64 * 72];    // mask / y-staging
  __shared__ float dtl[64], cuml[64], scl[64];
  int bid = blockIdx.x;
  int bh = bid >> 6, c = bid & 63;
  int b = bh >> 2, h = bh & 3;
  int m0 = b * LSEQ + c * 64;
  int tid = threadIdx.x, w = tid >> 6, lane = tid & 63;

  if (tid < 64) {
    dtl[tid] = dts[bh * LSEQ + c * 64 + tid];
    cuml[tid] = cums[bh * LSEQ + c * 64 + tid];
  }
  __syncthreads();
  float cumQ = cuml[63];

  // stage Bsm (token-major, swizzled)
  for (int it = 0; it < 4; it++) {
    int idx = it * 256 + tid, row = idx >> 4, g = idx & 15;
    uint4 v = *(const uint4*)&bc[(size_t)(m0 + row) * 256 + g * 8];
    *(uint4*)((char*)Bsm + row * 256 + ((g ^ (row & 7)) << 4)) = v;
  }
  // stage XT (ch-major)
  for (int it = 0; it < 2; it++) {
    int idx = it * 256 + tid, row = idx >> 3, g = idx & 7;
    uint4 v = *(const uint4*)&xsT[((size_t)(b * 256 + h * 64 + row)) * LSEQ + c * 64 + g * 8];
    *(uint4*)((char*)XT + row * 128 + ((g ^ (row & 7)) << 4)) = v;
  }
  if (tid < 64) scl[tid] = dtl[tid] * __expf(cumQ - cuml[tid]);
  __syncthreads();
  // stage BTs (ch-major, per-s scale)
  for (int it = 0; it < 4; it++) {
    int idx = it * 256 + tid, row = idx >> 3, g = idx & 7;
    uint4 v = *(const uint4*)&bT[((size_t)(b * 128 + row)) * LSEQ + c * 64 + g * 8];
    const unsigned short* pv = (const unsigned short*)&v;
    uint4 o; unsigned short* po = (unsigned short*)&o;
#pragma unroll
    for (int e = 0; e < 8; e++) po[e] = f2bf(bf2f(pv[e]) * scl[g * 8 + e]);
    *(uint4*)((char*)BTs + row * 128 + ((g ^ (row & 7)) << 4)) = o;
  }

  // GEMM1: G = C·B^T, A direct from global
  int rt = w * 16 + (lane & 15);
  const unsigned short* arow = bc + (size_t)(m0 + rt) * 256 + 128;
  f32x4 acc1[4];
#pragma unroll
  for (int i = 0; i < 4; i++) acc1[i] = fz4();
#pragma unroll
  for (int ks = 0; ks < 4; ks++) {
    int g = ks * 4 + (lane >> 4);
    bf16x8 a = *(const bf16x8*)&arow[g * 8];
#pragma unroll
    for (int ni = 0; ni < 4; ni++) {
      int rs = ni * 16 + (lane & 15);
      bf16x8 bfr = *(const bf16x8*)((char*)Bsm + rs * 256 + ((g ^ (rs & 7)) << 4));
      acc1[ni] = __builtin_amdgcn_mfma_f32_16x16x32_bf16(a, bfr, acc1[ni], 0, 0, 0);
    }
  }
  // mask -> Ms (own-wave rows)
#pragma unroll
  for (int ni = 0; ni < 4; ni++)
#pragma unroll
    for (int j = 0; j < 4; j++) {
      int t = w * 16 + (lane >> 4) * 4 + j;
      int s = ni * 16 + (lane & 15);
      float v = 0.f;
      if (t >= s) v = acc1[ni][j] * __expf(cuml[t] - cuml[s]) * dtl[s];
      *(unsigned short*)((char*)Ms + t * 128 + (((s >> 3) ^ (t & 7)) << 4) + ((s & 7) << 1)) = f2bf(v);
    }
  __syncthreads();  // BTs staged everywhere; Ms own-wave

  // GEMM2: Y_intra = M·X ; GEMM3: ST = X^T·Bsc
  f32x4 acc2[4], acc3[8];
#pragma unroll
  for (int i = 0; i < 4; i++) acc2[i] = fz4();
#pragma unroll
  for (int i = 0; i < 8; i++) acc3[i] = fz4();
#pragma unroll
  for (int ks = 0; ks < 2; ks++) {
    int g = ks * 4 + (lane >> 4);
    bf16x8 xf[4];
#pragma unroll
    for (int ni = 0; ni < 4; ni++) {
      int rp = ni * 16 + (lane & 15);
      xf[ni] = *(const bf16x8*)((char*)XT + rp * 128 + ((g ^ (rp & 7)) << 4));
    }
    {
      bf16x8 a = *(const bf16x8*)((char*)Ms + rt * 128 + ((g ^ (rt & 7)) << 4));
#pragma unroll
      for (int ni = 0; ni < 4; ni++)
        acc2[ni] = __builtin_amdgcn_mfma_f32_16x16x32_bf16(a, xf[ni], acc2[ni], 0, 0, 0);
    }
    {
      bf16x8 a3 = xf[w];
#pragma unroll
      for (int ni = 0; ni < 8; ni++) {
        int rn = ni * 16 + (lane & 15);
        bf16x8 bfr = *(const bf16x8*)((char*)BTs + rn * 128 + ((g ^ (rn & 7)) << 4));
        acc3[ni] = __builtin_amdgcn_mfma_f32_16x16x32_bf16(a3, bfr, acc3[ni], 0, 0, 0);
      }
    }
  }
  __syncthreads();  // all waves done reading Ms before reuse
#pragma unroll
  for (int ni = 0; ni < 4; ni++)
#pragma unroll
    for (int j = 0; j < 4; j++) {
      int t = w * 16 + (lane >> 4) * 4 + j;
      int p = ni * 16 + (lane & 15);
      Ms[t * 72 + p] = f2bf(acc2[ni][j]);
    }
  float* stp = ST + ((size_t)bid << 13);
#pragma unroll
  for (int ni = 0; ni < 8; ni++)
#pragma unroll
    for (int j = 0; j < 4; j++) {
      int p = w * 16 + (lane >> 4) * 4 + j;
      int n = ni * 16 + (lane & 15);
      stp[p * 128 + n] = acc3[ni][j];
    }
  __syncthreads();
  {
    int rr = tid >> 3, cc = (tid & 7) * 8;
    for (int it = 0; it < 2; it++) {
      int t = it * 32 + rr;
      uint4 v = *(const uint4*)&Ms[t * 72 + cc];
      *(uint4*)&yb[(size_t)(m0 + t) * 256 + h * 64 + cc] = v;
    }
  }
}

// ---------------- chunk phase B: sequential state carry ----------------
__global__ __launch_bounds__(256) void k_chunkB(const float* __restrict__ ST,
                                                const float* __restrict__ cums,
                                                unsigned short* __restrict__ HT) {
  int bid = blockIdx.x;
  int bh = bid >> 3, psl = bid & 7;
  int p = psl * 8 + (threadIdx.x >> 5);
  int n0 = (threadIdx.x & 31) * 4;
  float H[4] = {0.f, 0.f, 0.f, 0.f};
  for (int c = 0; c < 64; c++) {
    size_t base = (size_t)(bh * 64 + c);
    ushort4 hv;
    unsigned short* ha = (unsigned short*)&hv;
#pragma unroll
    for (int e = 0; e < 4; e++) ha[e] = f2bf(H[e]);
    *(ushort4*)&HT[(base * 64 + p) * 128 + n0] = hv;
    float4 s4 = *(const float4*)&ST[(base << 13) + p * 128 + n0];
    float dec = __expf(cums[bh * LSEQ + c * 64 + 63]);
    H[0] = H[0] * dec + s4.x;
    H[1] = H[1] * dec + s4.y;
    H[2] = H[2] * dec + s4.z;
    H[3] = H[3] * dec + s4.w;
  }
}

// ---------------- chunk phase C: Y += exp(cum)·C·Hstart^T + D·x ----------------
__global__ __launch_bounds__(256) void k_chunkC(const unsigned short* __restrict__ bc,
                                                const unsigned short* __restrict__ xs,
                                                const unsigned short* __restrict__ HT,
                                                const float* __restrict__ cums,
                                                const float* __restrict__ Dp,
                                                unsigned short* __restrict__ yb) {
  __shared__ __align__(16) unsigned short Hs[64 * 128];
  __shared__ __align__(16) unsigned short yst[64 * 72];
  int bid = blockIdx.x;
  int bh = bid >> 6, c = bid & 63;
  int b = bh >> 2, h = bh & 3;
  int m0 = b * LSEQ + c * 64;
  int tid = threadIdx.x, w = tid >> 6, lane = tid & 63;
  float Dh = Dp[h];
  for (int it = 0; it < 4; it++) {
    int idx = it * 256 + tid, row = idx >> 4, g = idx & 15;
    uint4 v = *(const uint4*)&HT[((size_t)(bh * 64 + c) * 64 + row) * 128 + g * 8];
    *(uint4*)((char*)Hs + row * 256 + ((g ^ (row & 7)) << 4)) = v;
  }
  float exq[4];
  {
    int tb = w * 16 + (lane >> 4) * 4;
#pragma unroll
    for (int j = 0; j < 4; j++) exq[j] = __expf(cums[bh * LSEQ + c * 64 + tb + j]);
  }
  __syncthreads();
  int rt = w * 16 + (lane & 15);
  const unsigned short* arow = bc + (size_t)(m0 + rt) * 256 + 128;
  f32x4 acc[4];
#pragma unroll
  for (int i = 0; i < 4; i++) acc[i] = fz4();
#pragma unroll
  for (int ks = 0; ks < 4; ks++) {
    int g = ks * 4 + (lane >> 4);
    bf16x8 a = *(const bf16x8*)&arow[g * 8];
#pragma unroll
    for (int ni = 0; ni < 4; ni++) {
      int rp = ni * 16 + (lane & 15);
      bf16x8 bfr = *(const bf16x8*)((char*)Hs + rp * 256 + ((g ^ (rp & 7)) << 4));
      acc[ni] = __builtin_amdgcn_mfma_f32_16x16x32_bf16(a, bfr, acc[ni], 0, 0, 0);
    }
  }
#pragma unroll
  for (int ni = 0; ni < 4; ni++)
#pragma unroll
    for (int j = 0; j < 4; j++) {
      int t = w * 16 + (lane >> 4) * 4 + j;
      int p = ni * 16 + (lane & 15);
      yst[t * 72 + p] = f2bf(acc[ni][j] * exq[j]);
    }
  __syncthreads();
  {
    int rr = tid >> 3, cc = (tid & 7) * 8;
    for (int it = 0; it < 2; it++) {
      int t = it * 32 + rr;
      size_t off = (size_t)(m0 + t) * 256 + h * 64 + cc;
      uint4 yo = *(const uint4*)&yb[off];
      uint4 xv = *(const uint4*)&xs[off];
      const unsigned short* pyo = (const unsigned short*)&yo;
      const unsigned short* pxv = (const unsigned short*)&xv;
      const unsigned short* pys = &yst[t * 72 + cc];
      uint4 vo;
      unsigned short* po = (unsigned short*)&vo;
#pragma unroll
      for (int e = 0; e < 8; e++)
        po[e] = f2bf(bf2f(pyo[e]) + bf2f(pys[e]) + Dh * bf2f(pxv[e]));
      *(uint4*)&yb[off] = vo;
    }
  }
}

// ---------------- gate + RMSNorm ----------------
// MODE 0 (chunked): z from zbuf[m][256]; write rms part into zcat[m][512] cols 256..511.
// MODE 1 (fallback): zsrc = zx[m][1280] (interleaved z0/x0 in 0..511, z in 512..767); write full ycat.
template <int MODE>
__global__ __launch_bounds__(256) void k_ycat(const unsigned short* __restrict__ y,
                                              const unsigned short* __restrict__ zsrc,
                                              const float* __restrict__ norm_w,
                                              unsigned short* __restrict__ ocat) {
  int bid = blockIdx.x;
  int tid = threadIdx.x, w = tid >> 6, lane = tid & 63;
  size_t m = (size_t)bid * 4 + w;
  int j0 = lane * 4;
  ushort4 yv = *(const ushort4*)&y[m * 256 + j0];
  ushort4 zv;
  if constexpr (MODE == 0) zv = *(const ushort4*)&zsrc[m * 256 + j0];
  else zv = *(const ushort4*)&zsrc[m * 1280 + 512 + j0];
  unsigned short ya[4] = {yv.x, yv.y, yv.z, yv.w};
  unsigned short za[4] = {zv.x, zv.y, zv.z, zv.w};
  float g[4]; float ssum = 0.f;
  for (int i = 0; i < 4; i++) {
    float gg = bf2f(ya[i]) * silu(bf2f(za[i]));
    g[i] = gg; ssum += gg * gg;
  }
  for (int off = 32; off; off >>= 1) ssum += __shfl_xor(ssum, off, 64);
  float inv = rsqrtf(ssum * (1.f / 256.f) + 1e-5f);
  ushort4 o2;
  unsigned short* o2a = (unsigned short*)&o2;
  for (int i = 0; i < 4; i++) o2a[i] = f2bf(g[i] * norm_w[j0 + i] * inv);
  *(ushort4*)&ocat[m * 512 + 256 + j0] = o2;
  if constexpr (MODE == 1) {
    ushort4 p0 = *(const ushort4*)&zsrc[m * 1280 + 2 * j0];
    ushort4 p1 = *(const ushort4*)&zsrc[m * 1280 + 2 * j0 + 4];
    ushort4 o1;
    unsigned short* o1a = (unsigned short*)&o1;
    o1a[0] = f2bf(silu(bf2f(p0.x)) * bf2f(p0.y));
    o1a[1] = f2bf(silu(bf2f(p0.z)) * bf2f(p0.w));
    o1a[2] = f2bf(silu(bf2f(p1.x)) * bf2f(p1.y));
    o1a[3] = f2bf(silu(bf2f(p1.z)) * bf2f(p1.w));
    *(ushort4*)&ocat[m * 512 + j0] = o1;
  }
}

// ---------------- SE ----------------
__global__ void k_zero(float* __restrict__ p) { p[blockIdx.x * 256 + threadIdx.x] = 0.f; }

__global__ __launch_bounds__(256) void k_semean(const float* __restrict__ res, float* __restrict__ smean) {
  int bid = blockIdx.x;
  int b = bid >> 5, ch = bid & 31;
  int c = threadIdx.x;
  float acc = 0.f;
  for (int r = 0; r < 128; r++)
    acc += res[(size_t)(b * LSEQ + ch * 128 + r) * 256 + c];
  atomicAdd(&smean[b * 256 + c], acc);
}

__global__ __launch_bounds__(512) void k_sefc(const float* __restrict__ smean,
                                              const float* __restrict__ w1, const float* __restrict__ b1,
                                              const float* __restrict__ w2, const float* __restrict__ b2,
                                              float* __restrict__ s2) {
  __shared__ float s1[512];
  int tid = threadIdx.x;
  int b = tid >> 6, j = tid & 63;
  float acc = b1[j];
  for (int k = 0; k < 256; k++) acc += smean[b * 256 + k] * (1.f / 4096.f) * w1[j * 256 + k];
  s1[b * 64 + j] = fmaxf(acc, 0.f);
  __syncthreads();
  for (int idx = tid; idx < 2048; idx += 512) {
    int bb = idx >> 8, c = idx & 255;
    float a2 = b2[c];
    for (int k = 0; k < 64; k++) a2 += s1[bb * 64 + k] * w2[c * 64 + k];
    s2[idx] = 1.f / (1.f + expf(-a2));
  }
}

// ---------------- final: transpose + SE scale ----------------
__global__ __launch_bounds__(256) void k_final(const float* __restrict__ res,
                                               const float* __restrict__ s2,
                                               float* __restrict__ out) {
  __shared__ float t[64][65];
  int bid = blockIdx.x;
  int b = bid >> 8;
  int r = bid & 255;
  int ct = r >> 6, lt = r & 63;
  int c0 = ct * 64, l0 = lt * 64;
  int tid = threadIdx.x, j = tid & 63, i0 = tid >> 6;
  for (int rr = 0; rr < 16; rr++) {
    int i = i0 + rr * 4;
    t[i][j] = res[(size_t)(b * LSEQ + l0 + i) * 256 + c0 + j];
  }
  __syncthreads();
  for (int rr = 0; rr < 16; rr++) {
    int ci = i0 + rr * 4;
    float s = s2[b * 256 + c0 + ci];
    out[(size_t)(b * 256 + c0 + ci) * LSEQ + l0 + j] = t[j][ci] * s;
  }
}

// ---------------- launch ----------------
extern "C" void kernel_launch(void* const* d_in, const int* in_sizes, int n_in,
                              void* d_out, int out_size, void* d_ws, size_t ws_size,
                              hipStream_t stream) {
  const float* x         = (const float*)d_in[0];
  const float* in_proj_w = (const float*)d_in[1];
  const float* conv_w    = (const float*)d_in[2];
  const float* conv_b    = (const float*)d_in[3];
  const float* dt_bias   = (const float*)d_in[4];
  const float* A_log     = (const float*)d_in[5];
  const float* Dp        = (const float*)d_in[6];
  const float* norm_w    = (const float*)d_in[7];
  const float* out_projw = (const float*)d_in[8];
  const float* se_w1     = (const float*)d_in[9];
  const float* se_b1     = (const float*)d_in[10];
  const float* se_w2     = (const float*)d_in[11];
  const float* se_b2     = (const float*)d_in[12];
  float* out = (float*)d_out;
  char* ws = (char*)d_ws;

  const size_t NEED_CHUNKED = 220676096;

  if (ws_size >= NEED_CHUNKED) {
    // layout (bytes):
    float*          ST    = (float*)(ws + 0);                   // [0, 67,108,864)
    unsigned short* ubf   = (unsigned short*)(ws + 0);          // pre-gemm1 tenant
    unsigned short* xbc   = (unsigned short*)(ws + 16777216);   // gemm1->conv tenant
    float*          res   = (float*)(ws + 0);                   // post-chunkB tenant
    unsigned short* zcat  = (unsigned short*)(ws + 67108864);   // [67.1M, 100.7M)
    unsigned short* zbuf  = (unsigned short*)(ws + 100663296);  // [100.7M, 117.4M)
    unsigned short* xsb   = (unsigned short*)(ws + 117440512);  // [117.4M, 134.2M)
    unsigned short* bcb   = (unsigned short*)(ws + 134217728);  // [134.2M, 151.0M)
    unsigned short* HT    = (unsigned short*)(ws + 150994944);  // [151.0M, 184.5M)
    unsigned short* xsT   = (unsigned short*)(ws + 150994944);  //   pre-chunkB tenant
    unsigned short* bT    = (unsigned short*)(ws + 167772160);  //   pre-chunkB tenant
    unsigned short* ybuf  = (unsigned short*)(ws + 184549376);  // [184.5M, 201.3M)
    unsigned short* wpad  = (unsigned short*)(ws + 201326592);
    unsigned short* woutb = (unsigned short*)(ws + 202047488);
    float*          dtraw = (float*)(ws + 202309632);
    float*          dts   = (float*)(ws + 202833920);
    float*          cums  = (float*)(ws + 203358208);
    float*          smean = (float*)(ws + 203882496);
    float*          s2    = (float*)(ws + 203890688);

    k_prep_w<<<1920, 256, 0, stream>>>(in_proj_w, out_projw, wpad, woutb);
    k_transpose_x<<<2048, 256, 0, stream>>>(x, ubf);
    k_gemm<256, 256, 256, 2><<<256 * 11, 256, 0, stream>>>(ubf, wpad, (float*)xbc, zcat, zbuf, dtraw, 11);
    k_conv<<<1024, 256, 0, stream>>>(xbc, 512, conv_w, conv_b, xsb, bcb, xsT, bT);
    k_dtpre<<<2048, 64, 0, stream>>>(dtraw, dt_bias, A_log, dts, cums);
    k_chunkA<<<2048, 256, 0, stream>>>(bcb, xsT, bT, dts, cums, ST, ybuf);
    k_chunkB<<<256, 256, 0, stream>>>(ST, cums, HT);
    k_chunkC<<<2048, 256, 0, stream>>>(bcb, xsb, HT, cums, Dp, ybuf);
    k_ycat<0><<<8192, 256, 0, stream>>>(ybuf, zbuf, norm_w, zcat);
    k_gemm<512, 512, 512, 1><<<256 * 2, 256, 0, stream>>>(zcat, woutb, res, nullptr, nullptr, nullptr, 2);
    k_zero<<<8, 256, 0, stream>>>(smean);
    k_semean<<<256, 256, 0, stream>>>(res, smean);
    k_sefc<<<1, 512, 0, stream>>>(smean, se_w1, se_b1, se_w2, se_b2, s2);
    k_final<<<2048, 256, 0, stream>>>(res, s2, out);
  } else {
    // fallback: sequential-scan path (note: wpad rows 0..511 are interleaved; ycat<1> handles)
    unsigned short* ubf   = (unsigned short*)(ws + 0);
    unsigned short* xsb   = (unsigned short*)(ws + 16777216);
    float*          res   = (float*)(ws + 0);
    unsigned short* bcb   = (unsigned short*)(ws + 33554432);
    unsigned short* zx    = (unsigned short*)(ws + 50331648);
    float*          dtb   = (float*)(ws + 134217728);
    unsigned short* ybuf  = (unsigned short*)(ws + 134742016);
    unsigned short* ycat  = (unsigned short*)(ws + 151519232);
    unsigned short* wpad  = (unsigned short*)(ws + 185073664);
    unsigned short* woutb = (unsigned short*)(ws + 185794560);
    float*          smean = (float*)(ws + 186056704);
    float*          s2    = (float*)(ws + 186064896);

    k_prep_w<<<1920, 256, 0, stream>>>(in_proj_w, out_projw, wpad, woutb);
    k_transpose_x<<<2048, 256, 0, stream>>>(x, ubf);
    k_gemm<256, 256, 256, 0><<<256 * 11, 256, 0, stream>>>(ubf, wpad, nullptr, zx, nullptr, dtb, 11);
    k_conv<<<1024, 256, 0, stream>>>(zx + 768, 1280, conv_w, conv_b, xsb, bcb, nullptr, nullptr);
    k_scan<<<512, 256, 0, stream>>>(xsb, bcb, dtb, dt_bias, A_log, Dp, ybuf);
    k_ycat<1><<<8192, 256, 0, stream>>>(ybuf, zx, norm_w, ycat);
    k_gemm<512, 512, 512, 1><<<256 * 2, 256, 0, stream>>>(ycat, woutb, res, nullptr, nullptr, nullptr, 2);
    k_zero<<<8, 256, 0, stream>>>(smean);
    k_semean<<<256, 256, 0, stream>>>(res, smean);
    k_sefc<<<1, 512, 0, stream>>>(smean, se_w1, se_b1, se_w2, se_b2, s2);
    k_final<<<2048, 256, 0, stream>>>(res, s2, out);
  }
}

// Round 5
// 226.318 us; speedup vs baseline: 6.7289x; 1.0434x over previous
//
#include <hip/hip_runtime.h>
#include <stdint.h>

// ---------------- types / helpers ----------------
typedef __attribute__((ext_vector_type(8))) short bf16x8;
typedef __attribute__((ext_vector_type(4))) float f32x4;

__device__ __forceinline__ float bf2f(unsigned short u) {
  unsigned int x = ((unsigned int)u) << 16;
  return __builtin_bit_cast(float, x);
}
__device__ __forceinline__ unsigned short f2bf(float f) {
  unsigned int x = __builtin_bit_cast(unsigned int, f);
  unsigned int r = x + 0x7FFFu + ((x >> 16) & 1u);
  return (unsigned short)(r >> 16);
}
__device__ __forceinline__ float silu(float v) { return v / (1.f + __expf(-v)); }
__device__ __forceinline__ f32x4 fz4() { f32x4 z; z[0]=0.f; z[1]=0.f; z[2]=0.f; z[3]=0.f; return z; }

#define LSEQ 4096
#define DMODEL 256
#define NIN 1284
#define NINP 1408   // padded to 11*128

// ---------------- prep: weight cast/pad/interleave + x transpose ----------------
// blocks [0,1920): wpad/woutbf.  blocks [1920, 1920+2048): transpose x -> ubf.
__global__ __launch_bounds__(256) void k_prep(const float* __restrict__ w_in,
                                              const float* __restrict__ w_out,
                                              unsigned short* __restrict__ wpad,
                                              unsigned short* __restrict__ woutbf,
                                              const float* __restrict__ x,
                                              unsigned short* __restrict__ ubf) {
  int bid = blockIdx.x;
  int tid = threadIdx.x;
  if (bid < 1920) {
    int idx = bid * 256 + tid;
    const int tot1 = NINP * DMODEL;           // 360448
    if (idx < tot1) {
      int n = idx / DMODEL, k = idx % DMODEL;
      int src = (n < 512) ? ((n & 1) ? 256 + (n >> 1) : (n >> 1)) : n;
      float v = (src < NIN) ? w_in[src * DMODEL + k] : 0.f;
      wpad[idx] = f2bf(v);
    } else {
      int j = idx - tot1;                      // 256*512 = 131072
      woutbf[j] = f2bf(w_out[j]);
    }
    return;
  }
  __shared__ float t[64][65];
  int r = (bid - 1920) & 255;
  int b = (bid - 1920) >> 8;
  int lt = r >> 2, kt = r & 3;
  int l0 = lt * 64, k0 = kt * 64;
  int j = tid & 63, i0 = tid >> 6;
  for (int rr = 0; rr < 16; rr++) {
    int ki = i0 + rr * 4;
    t[ki][j] = x[(size_t)(b * DMODEL + k0 + ki) * LSEQ + l0 + j];
  }
  __syncthreads();
  for (int rr = 0; rr < 16; rr++) {
    int li = i0 + rr * 4;
    ubf[(size_t)(b * LSEQ + l0 + li) * DMODEL + k0 + j] = f2bf(t[j][li]);
  }
}

// ---------------- bf16 MFMA GEMM, 128x128 tile, BK=64, T2-swizzled LDS ----------------
// C[m][n] = sum_k A[m][k] * B[n][k]
// EPI=0 (fallback): combined zx[m][1280] (z0/x0 interleaved in cols 0..511) + dt
// EPI=1: f32 res[m][256]
// EPI=2 (chunked): zc=silu(z0)*x0 -> zcat cols 0..255; z -> zbuf; xBC -> xbc; dt -> dtb
template <int KDIM, int LDA, int LDB, int EPI>
__global__ __launch_bounds__(256) void k_gemm(const unsigned short* __restrict__ A,
                                              const unsigned short* __restrict__ B,
                                              float* __restrict__ outF,
                                              unsigned short* __restrict__ outBF,
                                              unsigned short* __restrict__ outBF2,
                                              float* __restrict__ dtb, int tilesN) {
  __shared__ __align__(16) short lds[17408];     // 34816 B
  short* As = lds;
  short* Bs = lds + 8192;
  int nwg = gridDim.x;
  int orig = blockIdx.x;
  int wgid = (nwg & 7) ? orig : ((orig & 7) * (nwg >> 3) + (orig >> 3));
  int tn = wgid % tilesN, tm = wgid / tilesN;
  int m0 = tm * 128, n0 = tn * 128;
  int tid = threadIdx.x;
  int w = tid >> 6, lane = tid & 63;
  int wr = w >> 1, wc = w & 1;
  f32x4 acc[4][4];
  for (int i = 0; i < 4; i++)
    for (int j = 0; j < 4; j++) acc[i][j] = fz4();

  for (int kt = 0; kt < KDIM / 64; kt++) {
    int k0 = kt * 64;
    for (int i = 0; i < 4; i++) {
      int rowblk = w * 32 + i * 8;
      int row = rowblk + (lane >> 3);
      // pre-swizzled source granule: LDS[row][g] holds logical granule g^(row&7)
      int kc = ((lane & 7) ^ (row & 7)) * 8;
      const unsigned short* ga = A + (size_t)(m0 + row) * LDA + k0 + kc;
      __builtin_amdgcn_global_load_lds((const __attribute__((address_space(1))) unsigned int*)ga,
                                       (__attribute__((address_space(3))) unsigned int*)&As[rowblk * 64],
                                       16, 0, 0);
      const unsigned short* gb = B + (size_t)(n0 + row) * LDB + k0 + kc;
      __builtin_amdgcn_global_load_lds((const __attribute__((address_space(1))) unsigned int*)gb,
                                       (__attribute__((address_space(3))) unsigned int*)&Bs[rowblk * 64],
                                       16, 0, 0);
    }
    __syncthreads();
    for (int kk = 0; kk < 64; kk += 32) {
      int gq = (kk >> 3) + (lane >> 4);       // logical granule 0..7
      bf16x8 af[4], bfr[4];
      for (int mi = 0; mi < 4; mi++) {
        int rt = wr * 64 + mi * 16 + (lane & 15);
        af[mi] = *(const bf16x8*)((const char*)As + rt * 128 + ((gq ^ (rt & 7)) << 4));
      }
      for (int ni = 0; ni < 4; ni++) {
        int rs = wc * 64 + ni * 16 + (lane & 15);
        bfr[ni] = *(const bf16x8*)((const char*)Bs + rs * 128 + ((gq ^ (rs & 7)) << 4));
      }
      for (int mi = 0; mi < 4; mi++)
        for (int ni = 0; ni < 4; ni++)
          acc[mi][ni] = __builtin_amdgcn_mfma_f32_16x16x32_bf16(af[mi], bfr[ni], acc[mi][ni], 0, 0, 0);
    }
    __syncthreads();
  }

  int fq = lane >> 4, fr = lane & 15;
  if constexpr (EPI == 1) {
    float* Cf = (float*)lds;
    for (int ph = 0; ph < 2; ph++) {
      if (ph) __syncthreads();
      if (wc == ph) {
        for (int mi = 0; mi < 4; mi++)
          for (int ni = 0; ni < 4; ni++)
            for (int j = 0; j < 4; j++)
              Cf[(wr * 64 + mi * 16 + fq * 4 + j) * 68 + ni * 16 + fr] = acc[mi][ni][j];
      }
      __syncthreads();
      int rr = tid >> 4, cc = (tid & 15) * 4;
      for (int it = 0; it < 8; it++) {
        int r = it * 16 + rr;
        float4 v = *(const float4*)&Cf[r * 68 + cc];
        *(float4*)&outF[(size_t)(m0 + r) * 256 + n0 + ph * 64 + cc] = v;
      }
    }
  } else if constexpr (EPI == 2) {
    unsigned short* xbc = (unsigned short*)outF;
    if (n0 >= 1280) {
      if (wc == 0 && fr < 4) {
        for (int mi = 0; mi < 4; mi++)
          for (int j = 0; j < 4; j++) {
            int m = m0 + wr * 64 + mi * 16 + fq * 4 + j;
            dtb[m * 4 + fr] = acc[mi][0][j];
          }
      }
    } else if (n0 < 512) {
      // zc = silu(z0)*x0 : even fr holds z0, odd fr holds x0 (interleaved rows)
      short* Ct = lds;
      for (int mi = 0; mi < 4; mi++)
        for (int ni = 0; ni < 4; ni++)
          for (int j = 0; j < 4; j++) {
            float v = acc[mi][ni][j];
            float vp = __shfl_xor(v, 1, 64);
            if (!(fr & 1)) {
              float zc = silu(v) * vp;
              Ct[(wr * 64 + mi * 16 + fq * 4 + j) * 72 + wc * 32 + ni * 8 + (fr >> 1)] =
                  (short)f2bf(zc);
            }
          }
      __syncthreads();
      int r = tid >> 1, base = (tid & 1) * 32;
      for (int it = 0; it < 4; it++) {
        int cc = base + it * 8;
        uint4 v = *(const uint4*)&Ct[r * 72 + cc];
        *(uint4*)&outBF[(size_t)(m0 + r) * 512 + (n0 >> 1) + cc] = v;
      }
    } else {
      short* Ct = lds;
      for (int mi = 0; mi < 4; mi++)
        for (int ni = 0; ni < 4; ni++)
          for (int j = 0; j < 4; j++)
            Ct[(wr * 64 + mi * 16 + fq * 4 + j) * 136 + wc * 64 + ni * 16 + fr] =
                (short)f2bf(acc[mi][ni][j]);
      __syncthreads();
      int rr = tid >> 4, cc = (tid & 15) * 8;
      for (int it = 0; it < 8; it++) {
        int r = it * 16 + rr;
        uint4 v = *(const uint4*)&Ct[r * 136 + cc];
        if (n0 < 768) *(uint4*)&outBF2[(size_t)(m0 + r) * 256 + (n0 - 512) + cc] = v;
        else *(uint4*)&xbc[(size_t)(m0 + r) * 512 + (n0 - 768) + cc] = v;
      }
    }
  } else {  // EPI == 0 fallback
    bool dttile = (n0 >= 1280);
    if (dttile) {
      if (wc == 0 && fr < 4) {
        for (int mi = 0; mi < 4; mi++)
          for (int j = 0; j < 4; j++) {
            int m = m0 + wr * 64 + mi * 16 + fq * 4 + j;
            dtb[m * 4 + fr] = acc[mi][0][j];
          }
      }
    } else {
      short* Ct = lds;
      for (int mi = 0; mi < 4; mi++)
        for (int ni = 0; ni < 4; ni++)
          for (int j = 0; j < 4; j++)
            Ct[(wr * 64 + mi * 16 + fq * 4 + j) * 136 + wc * 64 + ni * 16 + fr] =
                (short)f2bf(acc[mi][ni][j]);
      __syncthreads();
      int rr = tid >> 4, cc = (tid & 15) * 8;
      for (int it = 0; it < 8; it++) {
        int r = it * 16 + rr;
        uint4 v = *(const uint4*)&Ct[r * 136 + cc];
        *(uint4*)&outBF[(size_t)(m0 + r) * 1280 + n0 + cc] = v;
      }
    }
  }
}

// ---------------- depthwise causal conv (4 taps) + SiLU; + dtpre tail blocks ----------------
// blocks [0,1024): conv.  blocks [1024, 1536): dt softplus + within-chunk cumsum (chunked path).
__global__ __launch_bounds__(256) void k_conv(const unsigned short* __restrict__ src, int stride,
                                              const float* __restrict__ conv_w,
                                              const float* __restrict__ conv_b,
                                              unsigned short* __restrict__ xs,
                                              unsigned short* __restrict__ bc,
                                              unsigned short* __restrict__ xsT,
                                              unsigned short* __restrict__ bT,
                                              const float* __restrict__ dtraw,
                                              const float* __restrict__ dt_bias,
                                              const float* __restrict__ A_log,
                                              float* __restrict__ dts,
                                              float* __restrict__ cums) {
  __shared__ __align__(16) unsigned short xt[35 * 512];
  int bid = blockIdx.x;
  int tid = threadIdx.x;
  if (bid >= 1024) {
    // dtpre: 512 blocks x 4 waves = 2048 (bh,c) chunks
    int w4 = tid >> 6, lane = tid & 63;
    int gc = (bid - 1024) * 4 + w4;
    int bh = gc >> 6, cc = gc & 63;
    int b2 = bh >> 2, h2 = bh & 3;
    int t = cc * 64 + lane;
    float v = dtraw[(size_t)(b2 * LSEQ + t) * 4 + h2] + dt_bias[h2];
    float dt = (v > 20.f) ? v : log1pf(__expf(v));
    float Ah = -__expf(A_log[h2]);
    float s = dt * Ah;
    for (int off = 1; off < 64; off <<= 1) {
      float o = __shfl_up(s, off, 64);
      if (lane >= off) s += o;
    }
    dts[bh * LSEQ + t] = dt;
    cums[bh * LSEQ + t] = s;
    return;
  }
  int b = bid >> 7;
  int t0 = (bid & 127) * 32;
  for (int id = tid; id < 35 * 64; id += 256) {
    int r = id >> 6, ch = id & 63;
    int t = t0 - 3 + r;
    float4 v;
    if (t < 0) v = make_float4(0.f, 0.f, 0.f, 0.f);
    else v = *(const float4*)&src[(size_t)(b * LSEQ + t) * stride + ch * 8];
    *(float4*)&xt[r * 512 + ch * 8] = v;
  }
  __syncthreads();
  int c0 = tid, c1 = tid + 256;
  float w0[4], w1[4];
  for (int k = 0; k < 4; k++) { w0[k] = conv_w[c0 * 4 + k]; w1[k] = conv_w[c1 * 4 + k]; }
  float bb0 = conv_b[c0], bb1 = conv_b[c1];
  unsigned short xa0[32], xa1[32];
#pragma unroll
  for (int tl = 0; tl < 32; tl++) {
    float a0 = bb0, a1 = bb1;
    for (int k = 0; k < 4; k++) {
      a0 += bf2f(xt[(tl + k) * 512 + c0]) * w0[k];
      a1 += bf2f(xt[(tl + k) * 512 + c1]) * w1[k];
    }
    a0 = silu(a0); a1 = silu(a1);
    unsigned short u0 = f2bf(a0), u1 = f2bf(a1);
    xa0[tl] = u0; xa1[tl] = u1;
    size_t row = (size_t)(b * LSEQ + t0 + tl);
    xs[row * 256 + c0] = u0;
    bc[row * 256 + (c1 - 256)] = u1;
  }
  if (xsT) {
    const uint4* p0 = (const uint4*)xa0;
    for (int k = 0; k < 4; k++)
      *(uint4*)&xsT[((size_t)(b * 256 + c0)) * LSEQ + t0 + k * 8] = p0[k];
    if (c1 < 384) {
      const uint4* p1 = (const uint4*)xa1;
      for (int k = 0; k < 4; k++)
        *(uint4*)&bT[((size_t)(b * 128 + (c1 - 256))) * LSEQ + t0 + k * 8] = p1[k];
    }
  }
}

// ---------------- OLD sequential scan (ws fallback) ----------------
__global__ __launch_bounds__(256) void k_scan(const unsigned short* __restrict__ xs,
                                              const unsigned short* __restrict__ bc,
                                              const float* __restrict__ dtb,
                                              const float* __restrict__ dt_bias,
                                              const float* __restrict__ A_log,
                                              const float* __restrict__ Dp,
                                              unsigned short* __restrict__ y) {
  __shared__ __align__(16) unsigned short bcl[32 * 256];
  __shared__ float xsl[32][4];
  __shared__ float dtl[32], dal[32];
  int bid = blockIdx.x;
  int b = bid >> 6;
  int h = (bid >> 4) & 3;
  int pg = bid & 15;
  int tid = threadIdx.x, w = tid >> 6, lane = tid & 63;
  int p = pg * 4 + w;
  float Ah = -expf(A_log[h]);
  float Dh = Dp[h];
  float bias = dt_bias[h];
  float h0 = 0.f, h1 = 0.f;
  for (int t0 = 0; t0 < LSEQ; t0 += 32) {
    for (int id = tid; id < 32 * 32; id += 256) {
      int r = id >> 5, ch = id & 31;
      *(float4*)&bcl[r * 256 + ch * 8] =
          *(const float4*)&bc[(size_t)(b * LSEQ + t0 + r) * 256 + ch * 8];
    }
    if (tid < 128) {
      int r = tid >> 2, pp = tid & 3;
      xsl[r][pp] = bf2f(xs[(size_t)(b * LSEQ + t0 + r) * 256 + h * 64 + pg * 4 + pp]);
    } else if (tid < 160) {
      int r = tid - 128;
      float v = dtb[(size_t)(b * LSEQ + t0 + r) * 4 + h] + bias;
      float dt = (v > 20.f) ? v : log1pf(expf(v));
      dtl[r] = dt;
      dal[r] = expf(dt * Ah);
    }
    __syncthreads();
    for (int tl = 0; tl < 32; tl++) {
      float dtv = dtl[tl], dav = dal[tl], xv = xsl[tl][w];
      float bn  = bf2f(bcl[tl * 256 + lane]);
      float bn2 = bf2f(bcl[tl * 256 + 64 + lane]);
      float cn  = bf2f(bcl[tl * 256 + 128 + lane]);
      float cn2 = bf2f(bcl[tl * 256 + 192 + lane]);
      float coef = dtv * xv;
      h0 = h0 * dav + coef * bn;
      h1 = h1 * dav + coef * bn2;
      float part = h0 * cn + h1 * cn2;
      for (int off = 32; off; off >>= 1) part += __shfl_xor(part, off, 64);
      if (lane == 0)
        y[(size_t)(b * LSEQ + t0 + tl) * 256 + h * 64 + p] = f2bf(part + Dh * xv);
    }
    __syncthreads();
  }
}

// ---------------- chunk phase A ----------------
__global__ __launch_bounds__(256) void k_chunkA(const unsigned short* __restrict__ bc,
                                                const unsigned short* __restrict__ xsT,
                                                const unsigned short* __restrict__ bT,
                                                const float* __restrict__ dts,
                                                const float* __restrict__ cums,
                                                float* __restrict__ ST,
                                                unsigned short* __restrict__ yb) {
  __shared__ __align__(16) unsigned short Bsm[64 * 128];  // token-major B
  __shared__ __align__(16) unsigned short BTs[128 * 64];  // ch-major scaled B
  __shared__ __align__(16) unsigned short XT[64 * 64];    // ch-major X
  __shared__ __align__(16) unsigned short Ms[64 * 72];    // mask / y-staging
  __shared__ float dtl[64], cuml[64], scl[64];
  int bid = blockIdx.x;
  int bh = bid >> 6, c = bid & 63;
  int b = bh >> 2, h = bh & 3;
  int m0 = b * LSEQ + c * 64;
  int tid = threadIdx.x, w = tid >> 6, lane = tid & 63;

  if (tid < 64) {
    dtl[tid] = dts[bh * LSEQ + c * 64 + tid];
    cuml[tid] = cums[bh * LSEQ + c * 64 + tid];
  }
  __syncthreads();
  float cumQ = cuml[63];

  for (int it = 0; it < 4; it++) {
    int idx = it * 256 + tid, row = idx >> 4, g = idx & 15;
    uint4 v = *(const uint4*)&bc[(size_t)(m0 + row) * 256 + g * 8];
    *(uint4*)((char*)Bsm + row * 256 + ((g ^ (row & 7)) << 4)) = v;
  }
  for (int it = 0; it < 2; it++) {
    int idx = it * 256 + tid, row = idx >> 3, g = idx & 7;
    uint4 v = *(const uint4*)&xsT[((size_t)(b * 256 + h * 64 + row)) * LSEQ + c * 64 + g * 8];
    *(uint4*)((char*)XT + row * 128 + ((g ^ (row & 7)) << 4)) = v;
  }
  if (tid < 64) scl[tid] = dtl[tid] * __expf(cumQ - cuml[tid]);
  __syncthreads();
  for (int it = 0; it < 4; it++) {
    int idx = it * 256 + tid, row = idx >> 3, g = idx & 7;
    uint4 v = *(const uint4*)&bT[((size_t)(b * 128 + row)) * LSEQ + c * 64 + g * 8];
    const unsigned short* pv = (const unsigned short*)&v;
    uint4 o; unsigned short* po = (unsigned short*)&o;
#pragma unroll
    for (int e = 0; e < 8; e++) po[e] = f2bf(bf2f(pv[e]) * scl[g * 8 + e]);
    *(uint4*)((char*)BTs + row * 128 + ((g ^ (row & 7)) << 4)) = o;
  }

  // GEMM1: G = C·B^T, A direct from global
  int rt = w * 16 + (lane & 15);
  const unsigned short* arow = bc + (size_t)(m0 + rt) * 256 + 128;
  f32x4 acc1[4];
#pragma unroll
  for (int i = 0; i < 4; i++) acc1[i] = fz4();
#pragma unroll
  for (int ks = 0; ks < 4; ks++) {
    int g = ks * 4 + (lane >> 4);
    bf16x8 a = *(const bf16x8*)&arow[g * 8];
#pragma unroll
    for (int ni = 0; ni < 4; ni++) {
      int rs = ni * 16 + (lane & 15);
      bf16x8 bfr = *(const bf16x8*)((char*)Bsm + rs * 256 + ((g ^ (rs & 7)) << 4));
      acc1[ni] = __builtin_amdgcn_mfma_f32_16x16x32_bf16(a, bfr, acc1[ni], 0, 0, 0);
    }
  }
#pragma unroll
  for (int ni = 0; ni < 4; ni++)
#pragma unroll
    for (int j = 0; j < 4; j++) {
      int t = w * 16 + (lane >> 4) * 4 + j;
      int s = ni * 16 + (lane & 15);
      float v = 0.f;
      if (t >= s) v = acc1[ni][j] * __expf(cuml[t] - cuml[s]) * dtl[s];
      *(unsigned short*)((char*)Ms + t * 128 + (((s >> 3) ^ (t & 7)) << 4) + ((s & 7) << 1)) = f2bf(v);
    }
  __syncthreads();

  // GEMM2: Y_intra = M·X ; GEMM3: ST = X^T·Bsc
  f32x4 acc2[4], acc3[8];
#pragma unroll
  for (int i = 0; i < 4; i++) acc2[i] = fz4();
#pragma unroll
  for (int i = 0; i < 8; i++) acc3[i] = fz4();
#pragma unroll
  for (int ks = 0; ks < 2; ks++) {
    int g = ks * 4 + (lane >> 4);
    bf16x8 xf[4];
#pragma unroll
    for (int ni = 0; ni < 4; ni++) {
      int rp = ni * 16 + (lane & 15);
      xf[ni] = *(const bf16x8*)((char*)XT + rp * 128 + ((g ^ (rp & 7)) << 4));
    }
    {
      bf16x8 a = *(const bf16x8*)((char*)Ms + rt * 128 + ((g ^ (rt & 7)) << 4));
#pragma unroll
      for (int ni = 0; ni < 4; ni++)
        acc2[ni] = __builtin_amdgcn_mfma_f32_16x16x32_bf16(a, xf[ni], acc2[ni], 0, 0, 0);
    }
    {
      bf16x8 a3 = xf[w];
#pragma unroll
      for (int ni = 0; ni < 8; ni++) {
        int rn = ni * 16 + (lane & 15);
        bf16x8 bfr = *(const bf16x8*)((char*)BTs + rn * 128 + ((g ^ (rn & 7)) << 4));
        acc3[ni] = __builtin_amdgcn_mfma_f32_16x16x32_bf16(a3, bfr, acc3[ni], 0, 0, 0);
      }
    }
  }
  __syncthreads();
#pragma unroll
  for (int ni = 0; ni < 4; ni++)
#pragma unroll
    for (int j = 0; j < 4; j++) {
      int t = w * 16 + (lane >> 4) * 4 + j;
      int p = ni * 16 + (lane & 15);
      Ms[t * 72 + p] = f2bf(acc2[ni][j]);
    }
  float* stp = ST + ((size_t)bid << 13);
#pragma unroll
  for (int ni = 0; ni < 8; ni++)
#pragma unroll
    for (int j = 0; j < 4; j++) {
      int p = w * 16 + (lane >> 4) * 4 + j;
      int n = ni * 16 + (lane & 15);
      stp[p * 128 + n] = acc3[ni][j];
    }
  __syncthreads();
  {
    int rr = tid >> 3, cc = (tid & 7) * 8;
    for (int it = 0; it < 2; it++) {
      int t = it * 32 + rr;
      uint4 v = *(const uint4*)&Ms[t * 72 + cc];
      *(uint4*)&yb[(size_t)(m0 + t) * 256 + h * 64 + cc] = v;
    }
  }
}

// ---------------- chunk phase B: sequential state carry ----------------
__global__ __launch_bounds__(256) void k_chunkB(const float* __restrict__ ST,
                                                const float* __restrict__ cums,
                                                unsigned short* __restrict__ HT) {
  int bid = blockIdx.x;
  int bh = bid >> 3, psl = bid & 7;
  int p = psl * 8 + (threadIdx.x >> 5);
  int n0 = (threadIdx.x & 31) * 4;
  float H[4] = {0.f, 0.f, 0.f, 0.f};
  for (int c = 0; c < 64; c++) {
    size_t base = (size_t)(bh * 64 + c);
    ushort4 hv;
    unsigned short* ha = (unsigned short*)&hv;
#pragma unroll
    for (int e = 0; e < 4; e++) ha[e] = f2bf(H[e]);
    *(ushort4*)&HT[(base * 64 + p) * 128 + n0] = hv;
    float4 s4 = *(const float4*)&ST[(base << 13) + p * 128 + n0];
    float dec = __expf(cums[bh * LSEQ + c * 64 + 63]);
    H[0] = H[0] * dec + s4.x;
    H[1] = H[1] * dec + s4.y;
    H[2] = H[2] * dec + s4.z;
    H[3] = H[3] * dec + s4.w;
  }
}

// ---------------- chunk phase C: Y += exp(cum)·C·Hstart^T + D·x ----------------
__global__ __launch_bounds__(256) void k_chunkC(const unsigned short* __restrict__ bc,
                                                const unsigned short* __restrict__ xs,
                                                const unsigned short* __restrict__ HT,
                                                const float* __restrict__ cums,
                                                const float* __restrict__ Dp,
                                                unsigned short* __restrict__ yb) {
  __shared__ __align__(16) unsigned short Hs[64 * 128];
  __shared__ __align__(16) unsigned short yst[64 * 72];
  int bid = blockIdx.x;
  int bh = bid >> 6, c = bid & 63;
  int b = bh >> 2, h = bh & 3;
  int m0 = b * LSEQ + c * 64;
  int tid = threadIdx.x, w = tid >> 6, lane = tid & 63;
  float Dh = Dp[h];
  for (int it = 0; it < 4; it++) {
    int idx = it * 256 + tid, row = idx >> 4, g = idx & 15;
    uint4 v = *(const uint4*)&HT[((size_t)(bh * 64 + c) * 64 + row) * 128 + g * 8];
    *(uint4*)((char*)Hs + row * 256 + ((g ^ (row & 7)) << 4)) = v;
  }
  float exq[4];
  {
    int tb = w * 16 + (lane >> 4) * 4;
#pragma unroll
    for (int j = 0; j < 4; j++) exq[j] = __expf(cums[bh * LSEQ + c * 64 + tb + j]);
  }
  __syncthreads();
  int rt = w * 16 + (lane & 15);
  const unsigned short* arow = bc + (size_t)(m0 + rt) * 256 + 128;
  f32x4 acc[4];
#pragma unroll
  for (int i = 0; i < 4; i++) acc[i] = fz4();
#pragma unroll
  for (int ks = 0; ks < 4; ks++) {
    int g = ks * 4 + (lane >> 4);
    bf16x8 a = *(const bf16x8*)&arow[g * 8];
#pragma unroll
    for (int ni = 0; ni < 4; ni++) {
      int rp = ni * 16 + (lane & 15);
      bf16x8 bfr = *(const bf16x8*)((char*)Hs + rp * 256 + ((g ^ (rp & 7)) << 4));
      acc[ni] = __builtin_amdgcn_mfma_f32_16x16x32_bf16(a, bfr, acc[ni], 0, 0, 0);
    }
  }
#pragma unroll
  for (int ni = 0; ni < 4; ni++)
#pragma unroll
    for (int j = 0; j < 4; j++) {
      int t = w * 16 + (lane >> 4) * 4 + j;
      int p = ni * 16 + (lane & 15);
      yst[t * 72 + p] = f2bf(acc[ni][j] * exq[j]);
    }
  __syncthreads();
  {
    int rr = tid >> 3, cc = (tid & 7) * 8;
    for (int it = 0; it < 2; it++) {
      int t = it * 32 + rr;
      size_t off = (size_t)(m0 + t) * 256 + h * 64 + cc;
      uint4 yo = *(const uint4*)&yb[off];
      uint4 xv = *(const uint4*)&xs[off];
      const unsigned short* pyo = (const unsigned short*)&yo;
      const unsigned short* pxv = (const unsigned short*)&xv;
      const unsigned short* pys = &yst[t * 72 + cc];
      uint4 vo;
      unsigned short* po = (unsigned short*)&vo;
#pragma unroll
      for (int e = 0; e < 8; e++)
        po[e] = f2bf(bf2f(pyo[e]) + bf2f(pys[e]) + Dh * bf2f(pxv[e]));
      *(uint4*)&yb[off] = vo;
    }
  }
}

// ---------------- gate + RMSNorm ----------------
template <int MODE>
__global__ __launch_bounds__(256) void k_ycat(const unsigned short* __restrict__ y,
                                              const unsigned short* __restrict__ zsrc,
                                              const float* __restrict__ norm_w,
                                              unsigned short* __restrict__ ocat) {
  int bid = blockIdx.x;
  int tid = threadIdx.x, w = tid >> 6, lane = tid & 63;
  size_t m = (size_t)bid * 4 + w;
  int j0 = lane * 4;
  ushort4 yv = *(const ushort4*)&y[m * 256 + j0];
  ushort4 zv;
  if constexpr (MODE == 0) zv = *(const ushort4*)&zsrc[m * 256 + j0];
  else zv = *(const ushort4*)&zsrc[m * 1280 + 512 + j0];
  unsigned short ya[4] = {yv.x, yv.y, yv.z, yv.w};
  unsigned short za[4] = {zv.x, zv.y, zv.z, zv.w};
  float g[4]; float ssum = 0.f;
  for (int i = 0; i < 4; i++) {
    float gg = bf2f(ya[i]) * silu(bf2f(za[i]));
    g[i] = gg; ssum += gg * gg;
  }
  for (int off = 32; off; off >>= 1) ssum += __shfl_xor(ssum, off, 64);
  float inv = rsqrtf(ssum * (1.f / 256.f) + 1e-5f);
  ushort4 o2;
  unsigned short* o2a = (unsigned short*)&o2;
  for (int i = 0; i < 4; i++) o2a[i] = f2bf(g[i] * norm_w[j0 + i] * inv);
  *(ushort4*)&ocat[m * 512 + 256 + j0] = o2;
  if constexpr (MODE == 1) {
    ushort4 p0 = *(const ushort4*)&zsrc[m * 1280 + 2 * j0];
    ushort4 p1 = *(const ushort4*)&zsrc[m * 1280 + 2 * j0 + 4];
    ushort4 o1;
    unsigned short* o1a = (unsigned short*)&o1;
    o1a[0] = f2bf(silu(bf2f(p0.x)) * bf2f(p0.y));
    o1a[1] = f2bf(silu(bf2f(p0.z)) * bf2f(p0.w));
    o1a[2] = f2bf(silu(bf2f(p1.x)) * bf2f(p1.y));
    o1a[3] = f2bf(silu(bf2f(p1.z)) * bf2f(p1.w));
    *(ushort4*)&ocat[m * 512 + j0] = o1;
  }
}

// ---------------- SE ----------------
__global__ void k_zero(float* __restrict__ p) { p[blockIdx.x * 256 + threadIdx.x] = 0.f; }

__global__ __launch_bounds__(256) void k_semean(const float* __restrict__ res, float* __restrict__ smean) {
  int bid = blockIdx.x;
  int b = bid >> 5, ch = bid & 31;
  int c = threadIdx.x;
  float acc = 0.f;
  for (int r = 0; r < 128; r++)
    acc += res[(size_t)(b * LSEQ + ch * 128 + r) * 256 + c];
  atomicAdd(&smean[b * 256 + c], acc);
}

__global__ __launch_bounds__(512) void k_sefc(const float* __restrict__ smean,
                                              const float* __restrict__ w1, const float* __restrict__ b1,
                                              const float* __restrict__ w2, const float* __restrict__ b2,
                                              float* __restrict__ s2) {
  __shared__ float s1[512];
  int tid = threadIdx.x;
  int b = tid >> 6, j = tid & 63;
  float acc = b1[j];
  for (int k = 0; k < 256; k++) acc += smean[b * 256 + k] * (1.f / 4096.f) * w1[j * 256 + k];
  s1[b * 64 + j] = fmaxf(acc, 0.f);
  __syncthreads();
  for (int idx = tid; idx < 2048; idx += 512) {
    int bb = idx >> 8, c = idx & 255;
    float a2 = b2[c];
    for (int k = 0; k < 64; k++) a2 += s1[bb * 64 + k] * w2[c * 64 + k];
    s2[idx] = 1.f / (1.f + expf(-a2));
  }
}

// ---------------- final: transpose + SE scale ----------------
__global__ __launch_bounds__(256) void k_final(const float* __restrict__ res,
                                               const float* __restrict__ s2,
                                               float* __restrict__ out) {
  __shared__ float t[64][65];
  int bid = blockIdx.x;
  int b = bid >> 8;
  int r = bid & 255;
  int ct = r >> 6, lt = r & 63;
  int c0 = ct * 64, l0 = lt * 64;
  int tid = threadIdx.x, j = tid & 63, i0 = tid >> 6;
  for (int rr = 0; rr < 16; rr++) {
    int i = i0 + rr * 4;
    t[i][j] = res[(size_t)(b * LSEQ + l0 + i) * 256 + c0 + j];
  }
  __syncthreads();
  for (int rr = 0; rr < 16; rr++) {
    int ci = i0 + rr * 4;
    float s = s2[b * 256 + c0 + ci];
    out[(size_t)(b * 256 + c0 + ci) * LSEQ + l0 + j] = t[j][ci] * s;
  }
}

// ---------------- launch ----------------
extern "C" void kernel_launch(void* const* d_in, const int* in_sizes, int n_in,
                              void* d_out, int out_size, void* d_ws, size_t ws_size,
                              hipStream_t stream) {
  const float* x         = (const float*)d_in[0];
  const float* in_proj_w = (const float*)d_in[1];
  const float* conv_w    = (const float*)d_in[2];
  const float* conv_b    = (const float*)d_in[3];
  const float* dt_bias   = (const float*)d_in[4];
  const float* A_log     = (const float*)d_in[5];
  const float* Dp        = (const float*)d_in[6];
  const float* norm_w    = (const float*)d_in[7];
  const float* out_projw = (const float*)d_in[8];
  const float* se_w1     = (const float*)d_in[9];
  const float* se_b1     = (const float*)d_in[10];
  const float* se_w2     = (const float*)d_in[11];
  const float* se_b2     = (const float*)d_in[12];
  float* out = (float*)d_out;
  char* ws = (char*)d_ws;

  const size_t NEED_CHUNKED = 220676096;

  if (ws_size >= NEED_CHUNKED) {
    float*          ST    = (float*)(ws + 0);
    unsigned short* ubf   = (unsigned short*)(ws + 0);
    unsigned short* xbc   = (unsigned short*)(ws + 16777216);
    float*          res   = (float*)(ws + 0);
    unsigned short* zcat  = (unsigned short*)(ws + 67108864);
    unsigned short* zbuf  = (unsigned short*)(ws + 100663296);
    unsigned short* xsb   = (unsigned short*)(ws + 117440512);
    unsigned short* bcb   = (unsigned short*)(ws + 134217728);
    unsigned short* HT    = (unsigned short*)(ws + 150994944);
    unsigned short* xsT   = (unsigned short*)(ws + 150994944);
    unsigned short* bT    = (unsigned short*)(ws + 167772160);
    unsigned short* ybuf  = (unsigned short*)(ws + 184549376);
    unsigned short* wpad  = (unsigned short*)(ws + 201326592);
    unsigned short* woutb = (unsigned short*)(ws + 202047488);
    float*          dtraw = (float*)(ws + 202309632);
    float*          dts   = (float*)(ws + 202833920);
    float*          cums  = (float*)(ws + 203358208);
    float*          smean = (float*)(ws + 203882496);
    float*          s2    = (float*)(ws + 203890688);

    k_prep<<<3968, 256, 0, stream>>>(in_proj_w, out_projw, wpad, woutb, x, ubf);
    k_gemm<256, 256, 256, 2><<<256 * 11, 256, 0, stream>>>(ubf, wpad, (float*)xbc, zcat, zbuf, dtraw, 11);
    k_conv<<<1536, 256, 0, stream>>>(xbc, 512, conv_w, conv_b, xsb, bcb, xsT, bT,
                                     dtraw, dt_bias, A_log, dts, cums);
    k_chunkA<<<2048, 256, 0, stream>>>(bcb, xsT, bT, dts, cums, ST, ybuf);
    k_chunkB<<<256, 256, 0, stream>>>(ST, cums, HT);
    k_chunkC<<<2048, 256, 0, stream>>>(bcb, xsb, HT, cums, Dp, ybuf);
    k_ycat<0><<<8192, 256, 0, stream>>>(ybuf, zbuf, norm_w, zcat);
    k_gemm<512, 512, 512, 1><<<256 * 2, 256, 0, stream>>>(zcat, woutb, res, nullptr, nullptr, nullptr, 2);
    k_zero<<<8, 256, 0, stream>>>(smean);
    k_semean<<<256, 256, 0, stream>>>(res, smean);
    k_sefc<<<1, 512, 0, stream>>>(smean, se_w1, se_b1, se_w2, se_b2, s2);
    k_final<<<2048, 256, 0, stream>>>(res, s2, out);
  } else {
    unsigned short* ubf   = (unsigned short*)(ws + 0);
    unsigned short* xsb   = (unsigned short*)(ws + 16777216);
    float*          res   = (float*)(ws + 0);
    unsigned short* bcb   = (unsigned short*)(ws + 33554432);
    unsigned short* zx    = (unsigned short*)(ws + 50331648);
    float*          dtb   = (float*)(ws + 134217728);
    unsigned short* ybuf  = (unsigned short*)(ws + 134742016);
    unsigned short* ycat  = (unsigned short*)(ws + 151519232);
    unsigned short* wpad  = (unsigned short*)(ws + 185073664);
    unsigned short* woutb = (unsigned short*)(ws + 185794560);
    float*          smean = (float*)(ws + 186056704);
    float*          s2    = (float*)(ws + 186064896);

    k_prep<<<3968, 256, 0, stream>>>(in_proj_w, out_projw, wpad, woutb, x, ubf);
    k_gemm<256, 256, 256, 0><<<256 * 11, 256, 0, stream>>>(ubf, wpad, nullptr, zx, nullptr, dtb, 11);
    k_conv<<<1024, 256, 0, stream>>>(zx + 768, 1280, conv_w, conv_b, xsb, bcb, nullptr, nullptr,
                                     nullptr, nullptr, nullptr, nullptr, nullptr);
    k_scan<<<512, 256, 0, stream>>>(xsb, bcb, dtb, dt_bias, A_log, Dp, ybuf);
    k_ycat<1><<<8192, 256, 0, stream>>>(ybuf, zx, norm_w, ycat);
    k_gemm<512, 512, 512, 1><<<256 * 2, 256, 0, stream>>>(ycat, woutb, res, nullptr, nullptr, nullptr, 2);
    k_zero<<<8, 256, 0, stream>>>(smean);
    k_semean<<<256, 256, 0, stream>>>(res, smean);
    k_sefc<<<1, 512, 0, stream>>>(smean, se_w1, se_b1, se_w2, se_b2, s2);
    k_final<<<2048, 256, 0, stream>>>(res, s2, out);
  }
}

// Round 6
// 221.038 us; speedup vs baseline: 6.8896x; 1.0239x over previous
//
#include <hip/hip_runtime.h>
#include <stdint.h>

// ---------------- types / helpers ----------------
typedef __attribute__((ext_vector_type(8))) short bf16x8;
typedef __attribute__((ext_vector_type(4))) float f32x4;

__device__ __forceinline__ float bf2f(unsigned short u) {
  unsigned int x = ((unsigned int)u) << 16;
  return __builtin_bit_cast(float, x);
}
__device__ __forceinline__ unsigned short f2bf(float f) {
  unsigned int x = __builtin_bit_cast(unsigned int, f);
  unsigned int r = x + 0x7FFFu + ((x >> 16) & 1u);
  return (unsigned short)(r >> 16);
}
__device__ __forceinline__ float silu(float v) { return v / (1.f + __expf(-v)); }
__device__ __forceinline__ f32x4 fz4() { f32x4 z; z[0]=0.f; z[1]=0.f; z[2]=0.f; z[3]=0.f; return z; }

#define LSEQ 4096
#define DMODEL 256
#define NIN 1284
#define NINP 1408   // padded to 11*128

// ---------------- prep: weight cast/pad/interleave + x transpose ----------------
__global__ __launch_bounds__(256) void k_prep(const float* __restrict__ w_in,
                                              const float* __restrict__ w_out,
                                              unsigned short* __restrict__ wpad,
                                              unsigned short* __restrict__ woutbf,
                                              const float* __restrict__ x,
                                              unsigned short* __restrict__ ubf) {
  int bid = blockIdx.x;
  int tid = threadIdx.x;
  if (bid < 1920) {
    int idx = bid * 256 + tid;
    const int tot1 = NINP * DMODEL;           // 360448
    if (idx < tot1) {
      int n = idx / DMODEL, k = idx % DMODEL;
      int src = (n < 512) ? ((n & 1) ? 256 + (n >> 1) : (n >> 1)) : n;
      float v = (src < NIN) ? w_in[src * DMODEL + k] : 0.f;
      wpad[idx] = f2bf(v);
    } else {
      int j = idx - tot1;                      // 256*512 = 131072
      woutbf[j] = f2bf(w_out[j]);
    }
    return;
  }
  __shared__ float t[64][65];
  int r = (bid - 1920) & 255;
  int b = (bid - 1920) >> 8;
  int lt = r >> 2, kt = r & 3;
  int l0 = lt * 64, k0 = kt * 64;
  int j = tid & 63, i0 = tid >> 6;
  for (int rr = 0; rr < 16; rr++) {
    int ki = i0 + rr * 4;
    t[ki][j] = x[(size_t)(b * DMODEL + k0 + ki) * LSEQ + l0 + j];
  }
  __syncthreads();
  for (int rr = 0; rr < 16; rr++) {
    int li = i0 + rr * 4;
    ubf[(size_t)(b * LSEQ + l0 + li) * DMODEL + k0 + j] = f2bf(t[j][li]);
  }
}

// ---------------- bf16 MFMA GEMM, 128x128 tile, BK=64, T2-swizzled LDS ----------------
// C[m][n] = sum_k A[m][k] * B[n][k]
// EPI=0 (fallback): combined zx[m][1280] (z0/x0 interleaved in cols 0..511) + dt
// EPI=1: res_t bf16 [b][c][l] via outBF
// EPI=2 (chunked): zc=silu(z0)*x0 -> zcat cols 0..255; z -> zbuf; xBC -> xbc; dt -> dtb
template <int KDIM, int LDA, int LDB, int EPI>
__global__ __launch_bounds__(256) void k_gemm(const unsigned short* __restrict__ A,
                                              const unsigned short* __restrict__ B,
                                              float* __restrict__ outF,
                                              unsigned short* __restrict__ outBF,
                                              unsigned short* __restrict__ outBF2,
                                              float* __restrict__ dtb, int tilesN) {
  __shared__ __align__(16) short lds[17408];     // 34816 B
  short* As = lds;
  short* Bs = lds + 8192;
  int nwg = gridDim.x;
  int orig = blockIdx.x;
  int wgid = (nwg & 7) ? orig : ((orig & 7) * (nwg >> 3) + (orig >> 3));
  int tn = wgid % tilesN, tm = wgid / tilesN;
  int m0 = tm * 128, n0 = tn * 128;
  int tid = threadIdx.x;
  int w = tid >> 6, lane = tid & 63;
  int wr = w >> 1, wc = w & 1;
  f32x4 acc[4][4];
  for (int i = 0; i < 4; i++)
    for (int j = 0; j < 4; j++) acc[i][j] = fz4();

  for (int kt = 0; kt < KDIM / 64; kt++) {
    int k0 = kt * 64;
    for (int i = 0; i < 4; i++) {
      int rowblk = w * 32 + i * 8;
      int row = rowblk + (lane >> 3);
      int kc = ((lane & 7) ^ (row & 7)) * 8;   // pre-swizzled source granule
      const unsigned short* ga = A + (size_t)(m0 + row) * LDA + k0 + kc;
      __builtin_amdgcn_global_load_lds((const __attribute__((address_space(1))) unsigned int*)ga,
                                       (__attribute__((address_space(3))) unsigned int*)&As[rowblk * 64],
                                       16, 0, 0);
      const unsigned short* gb = B + (size_t)(n0 + row) * LDB + k0 + kc;
      __builtin_amdgcn_global_load_lds((const __attribute__((address_space(1))) unsigned int*)gb,
                                       (__attribute__((address_space(3))) unsigned int*)&Bs[rowblk * 64],
                                       16, 0, 0);
    }
    __syncthreads();
    for (int kk = 0; kk < 64; kk += 32) {
      int gq = (kk >> 3) + (lane >> 4);       // logical granule 0..7
      bf16x8 af[4], bfr[4];
      for (int mi = 0; mi < 4; mi++) {
        int rt = wr * 64 + mi * 16 + (lane & 15);
        af[mi] = *(const bf16x8*)((const char*)As + rt * 128 + ((gq ^ (rt & 7)) << 4));
      }
      for (int ni = 0; ni < 4; ni++) {
        int rs = wc * 64 + ni * 16 + (lane & 15);
        bfr[ni] = *(const bf16x8*)((const char*)Bs + rs * 128 + ((gq ^ (rs & 7)) << 4));
      }
      for (int mi = 0; mi < 4; mi++)
        for (int ni = 0; ni < 4; ni++)
          acc[mi][ni] = __builtin_amdgcn_mfma_f32_16x16x32_bf16(af[mi], bfr[ni], acc[mi][ni], 0, 0, 0);
    }
    __syncthreads();
  }

  int fq = lane >> 4, fr = lane & 15;
  if constexpr (EPI == 1) {
    // res_t bf16 [b][c][l]: stage transposed (c-major, stride 136), coalesced row stores
    short* Ct = lds;
    for (int mi = 0; mi < 4; mi++)
      for (int ni = 0; ni < 4; ni++)
        for (int j = 0; j < 4; j++) {
          int r = wr * 64 + mi * 16 + fq * 4 + j;     // l within tile
          int cch = wc * 64 + ni * 16 + fr;           // c within tile
          Ct[cch * 136 + r] = (short)f2bf(acc[mi][ni][j]);
        }
    __syncthreads();
    int b = m0 >> 12, l0 = m0 & 4095;
    for (int it = 0; it < 4; it++) {
      int row = it * 32 + (tid >> 3);
      int cc = (tid & 7) * 16;
      uint4 v0 = *(const uint4*)&Ct[row * 136 + cc];
      uint4 v1 = *(const uint4*)&Ct[row * 136 + cc + 8];
      unsigned short* dst = outBF + ((size_t)(b * 256 + n0 + row)) * 4096 + l0 + cc;
      *(uint4*)dst = v0;
      *(uint4*)&dst[8] = v1;
    }
  } else if constexpr (EPI == 2) {
    unsigned short* xbc = (unsigned short*)outF;
    if (n0 >= 1280) {
      if (wc == 0 && fr < 4) {
        for (int mi = 0; mi < 4; mi++)
          for (int j = 0; j < 4; j++) {
            int m = m0 + wr * 64 + mi * 16 + fq * 4 + j;
            dtb[m * 4 + fr] = acc[mi][0][j];
          }
      }
    } else if (n0 < 512) {
      short* Ct = lds;
      for (int mi = 0; mi < 4; mi++)
        for (int ni = 0; ni < 4; ni++)
          for (int j = 0; j < 4; j++) {
            float v = acc[mi][ni][j];
            float vp = __shfl_xor(v, 1, 64);
            if (!(fr & 1)) {
              float zc = silu(v) * vp;
              Ct[(wr * 64 + mi * 16 + fq * 4 + j) * 72 + wc * 32 + ni * 8 + (fr >> 1)] =
                  (short)f2bf(zc);
            }
          }
      __syncthreads();
      int r = tid >> 1, base = (tid & 1) * 32;
      for (int it = 0; it < 4; it++) {
        int cc = base + it * 8;
        uint4 v = *(const uint4*)&Ct[r * 72 + cc];
        *(uint4*)&outBF[(size_t)(m0 + r) * 512 + (n0 >> 1) + cc] = v;
      }
    } else {
      short* Ct = lds;
      for (int mi = 0; mi < 4; mi++)
        for (int ni = 0; ni < 4; ni++)
          for (int j = 0; j < 4; j++)
            Ct[(wr * 64 + mi * 16 + fq * 4 + j) * 136 + wc * 64 + ni * 16 + fr] =
                (short)f2bf(acc[mi][ni][j]);
      __syncthreads();
      int rr = tid >> 4, cc = (tid & 15) * 8;
      for (int it = 0; it < 8; it++) {
        int r = it * 16 + rr;
        uint4 v = *(const uint4*)&Ct[r * 136 + cc];
        if (n0 < 768) *(uint4*)&outBF2[(size_t)(m0 + r) * 256 + (n0 - 512) + cc] = v;
        else *(uint4*)&xbc[(size_t)(m0 + r) * 512 + (n0 - 768) + cc] = v;
      }
    }
  } else {  // EPI == 0 fallback
    bool dttile = (n0 >= 1280);
    if (dttile) {
      if (wc == 0 && fr < 4) {
        for (int mi = 0; mi < 4; mi++)
          for (int j = 0; j < 4; j++) {
            int m = m0 + wr * 64 + mi * 16 + fq * 4 + j;
            dtb[m * 4 + fr] = acc[mi][0][j];
          }
      }
    } else {
      short* Ct = lds;
      for (int mi = 0; mi < 4; mi++)
        for (int ni = 0; ni < 4; ni++)
          for (int j = 0; j < 4; j++)
            Ct[(wr * 64 + mi * 16 + fq * 4 + j) * 136 + wc * 64 + ni * 16 + fr] =
                (short)f2bf(acc[mi][ni][j]);
      __syncthreads();
      int rr = tid >> 4, cc = (tid & 15) * 8;
      for (int it = 0; it < 8; it++) {
        int r = it * 16 + rr;
        uint4 v = *(const uint4*)&Ct[r * 136 + cc];
        *(uint4*)&outBF[(size_t)(m0 + r) * 1280 + n0 + cc] = v;
      }
    }
  }
}

// ---------------- depthwise causal conv (4 taps) + SiLU; + dtpre tail blocks ----------------
__global__ __launch_bounds__(256) void k_conv(const unsigned short* __restrict__ src, int stride,
                                              const float* __restrict__ conv_w,
                                              const float* __restrict__ conv_b,
                                              unsigned short* __restrict__ xs,
                                              unsigned short* __restrict__ bc,
                                              unsigned short* __restrict__ xsT,
                                              unsigned short* __restrict__ bT,
                                              const float* __restrict__ dtraw,
                                              const float* __restrict__ dt_bias,
                                              const float* __restrict__ A_log,
                                              float* __restrict__ dts,
                                              float* __restrict__ cums) {
  __shared__ __align__(16) unsigned short xt[35 * 512];
  int bid = blockIdx.x;
  int tid = threadIdx.x;
  if (bid >= 1024) {
    int w4 = tid >> 6, lane = tid & 63;
    int gc = (bid - 1024) * 4 + w4;
    int bh = gc >> 6, cc = gc & 63;
    int b2 = bh >> 2, h2 = bh & 3;
    int t = cc * 64 + lane;
    float v = dtraw[(size_t)(b2 * LSEQ + t) * 4 + h2] + dt_bias[h2];
    float dt = (v > 20.f) ? v : log1pf(__expf(v));
    float Ah = -__expf(A_log[h2]);
    float s = dt * Ah;
    for (int off = 1; off < 64; off <<= 1) {
      float o = __shfl_up(s, off, 64);
      if (lane >= off) s += o;
    }
    dts[bh * LSEQ + t] = dt;
    cums[bh * LSEQ + t] = s;
    return;
  }
  int b = bid >> 7;
  int t0 = (bid & 127) * 32;
  for (int id = tid; id < 35 * 64; id += 256) {
    int r = id >> 6, ch = id & 63;
    int t = t0 - 3 + r;
    float4 v;
    if (t < 0) v = make_float4(0.f, 0.f, 0.f, 0.f);
    else v = *(const float4*)&src[(size_t)(b * LSEQ + t) * stride + ch * 8];
    *(float4*)&xt[r * 512 + ch * 8] = v;
  }
  __syncthreads();
  int c0 = tid, c1 = tid + 256;
  float w0[4], w1[4];
  for (int k = 0; k < 4; k++) { w0[k] = conv_w[c0 * 4 + k]; w1[k] = conv_w[c1 * 4 + k]; }
  float bb0 = conv_b[c0], bb1 = conv_b[c1];
  unsigned short xa0[32], xa1[32];
#pragma unroll
  for (int tl = 0; tl < 32; tl++) {
    float a0 = bb0, a1 = bb1;
    for (int k = 0; k < 4; k++) {
      a0 += bf2f(xt[(tl + k) * 512 + c0]) * w0[k];
      a1 += bf2f(xt[(tl + k) * 512 + c1]) * w1[k];
    }
    a0 = silu(a0); a1 = silu(a1);
    unsigned short u0 = f2bf(a0), u1 = f2bf(a1);
    xa0[tl] = u0; xa1[tl] = u1;
    size_t row = (size_t)(b * LSEQ + t0 + tl);
    xs[row * 256 + c0] = u0;
    bc[row * 256 + (c1 - 256)] = u1;
  }
  if (xsT) {
    const uint4* p0 = (const uint4*)xa0;
    for (int k = 0; k < 4; k++)
      *(uint4*)&xsT[((size_t)(b * 256 + c0)) * LSEQ + t0 + k * 8] = p0[k];
    if (c1 < 384) {
      const uint4* p1 = (const uint4*)xa1;
      for (int k = 0; k < 4; k++)
        *(uint4*)&bT[((size_t)(b * 128 + (c1 - 256))) * LSEQ + t0 + k * 8] = p1[k];
    }
  }
}

// ---------------- OLD sequential scan (ws fallback) ----------------
__global__ __launch_bounds__(256) void k_scan(const unsigned short* __restrict__ xs,
                                              const unsigned short* __restrict__ bc,
                                              const float* __restrict__ dtb,
                                              const float* __restrict__ dt_bias,
                                              const float* __restrict__ A_log,
                                              const float* __restrict__ Dp,
                                              unsigned short* __restrict__ y) {
  __shared__ __align__(16) unsigned short bcl[32 * 256];
  __shared__ float xsl[32][4];
  __shared__ float dtl[32], dal[32];
  int bid = blockIdx.x;
  int b = bid >> 6;
  int h = (bid >> 4) & 3;
  int pg = bid & 15;
  int tid = threadIdx.x, w = tid >> 6, lane = tid & 63;
  int p = pg * 4 + w;
  float Ah = -expf(A_log[h]);
  float Dh = Dp[h];
  float bias = dt_bias[h];
  float h0 = 0.f, h1 = 0.f;
  for (int t0 = 0; t0 < LSEQ; t0 += 32) {
    for (int id = tid; id < 32 * 32; id += 256) {
      int r = id >> 5, ch = id & 31;
      *(float4*)&bcl[r * 256 + ch * 8] =
          *(const float4*)&bc[(size_t)(b * LSEQ + t0 + r) * 256 + ch * 8];
    }
    if (tid < 128) {
      int r = tid >> 2, pp = tid & 3;
      xsl[r][pp] = bf2f(xs[(size_t)(b * LSEQ + t0 + r) * 256 + h * 64 + pg * 4 + pp]);
    } else if (tid < 160) {
      int r = tid - 128;
      float v = dtb[(size_t)(b * LSEQ + t0 + r) * 4 + h] + bias;
      float dt = (v > 20.f) ? v : log1pf(expf(v));
      dtl[r] = dt;
      dal[r] = expf(dt * Ah);
    }
    __syncthreads();
    for (int tl = 0; tl < 32; tl++) {
      float dtv = dtl[tl], dav = dal[tl], xv = xsl[tl][w];
      float bn  = bf2f(bcl[tl * 256 + lane]);
      float bn2 = bf2f(bcl[tl * 256 + 64 + lane]);
      float cn  = bf2f(bcl[tl * 256 + 128 + lane]);
      float cn2 = bf2f(bcl[tl * 256 + 192 + lane]);
      float coef = dtv * xv;
      h0 = h0 * dav + coef * bn;
      h1 = h1 * dav + coef * bn2;
      float part = h0 * cn + h1 * cn2;
      for (int off = 32; off; off >>= 1) part += __shfl_xor(part, off, 64);
      if (lane == 0)
        y[(size_t)(b * LSEQ + t0 + tl) * 256 + h * 64 + p] = f2bf(part + Dh * xv);
    }
    __syncthreads();
  }
}

// ---------------- chunk phase A ----------------
// LDS (shorts): Bsm [0,8192) BTs [8192,16384) XT [16384,20480) Ms [20480,25088)
// epilogue: STst overlays [0, 8704)
__global__ __launch_bounds__(256) void k_chunkA(const unsigned short* __restrict__ bc,
                                                const unsigned short* __restrict__ xsT,
                                                const unsigned short* __restrict__ bT,
                                                const float* __restrict__ dts,
                                                const float* __restrict__ cums,
                                                unsigned short* __restrict__ ST,
                                                unsigned short* __restrict__ yb) {
  __shared__ __align__(16) unsigned short sh[25088];
  unsigned short* Bsm = sh;
  unsigned short* BTs = sh + 8192;
  unsigned short* XT  = sh + 16384;
  unsigned short* Ms  = sh + 20480;
  __shared__ float dtl[64], cuml[64], scl[64];
  int bid = blockIdx.x;
  int bh = bid >> 6, c = bid & 63;
  int b = bh >> 2, h = bh & 3;
  int m0 = b * LSEQ + c * 64;
  int tid = threadIdx.x, w = tid >> 6, lane = tid & 63;

  if (tid < 64) {
    dtl[tid] = dts[bh * LSEQ + c * 64 + tid];
    cuml[tid] = cums[bh * LSEQ + c * 64 + tid];
  }
  __syncthreads();
  float cumQ = cuml[63];

  for (int it = 0; it < 4; it++) {
    int idx = it * 256 + tid, row = idx >> 4, g = idx & 15;
    uint4 v = *(const uint4*)&bc[(size_t)(m0 + row) * 256 + g * 8];
    *(uint4*)((char*)Bsm + row * 256 + ((g ^ (row & 7)) << 4)) = v;
  }
  for (int it = 0; it < 2; it++) {
    int idx = it * 256 + tid, row = idx >> 3, g = idx & 7;
    uint4 v = *(const uint4*)&xsT[((size_t)(b * 256 + h * 64 + row)) * LSEQ + c * 64 + g * 8];
    *(uint4*)((char*)XT + row * 128 + ((g ^ (row & 7)) << 4)) = v;
  }
  if (tid < 64) scl[tid] = dtl[tid] * __expf(cumQ - cuml[tid]);
  __syncthreads();
  for (int it = 0; it < 4; it++) {
    int idx = it * 256 + tid, row = idx >> 3, g = idx & 7;
    uint4 v = *(const uint4*)&bT[((size_t)(b * 128 + row)) * LSEQ + c * 64 + g * 8];
    const unsigned short* pv = (const unsigned short*)&v;
    uint4 o; unsigned short* po = (unsigned short*)&o;
#pragma unroll
    for (int e = 0; e < 8; e++) po[e] = f2bf(bf2f(pv[e]) * scl[g * 8 + e]);
    *(uint4*)((char*)BTs + row * 128 + ((g ^ (row & 7)) << 4)) = o;
  }

  // GEMM1: G = C·B^T, A direct from global
  int rt = w * 16 + (lane & 15);
  const unsigned short* arow = bc + (size_t)(m0 + rt) * 256 + 128;
  f32x4 acc1[4];
#pragma unroll
  for (int i = 0; i < 4; i++) acc1[i] = fz4();
#pragma unroll
  for (int ks = 0; ks < 4; ks++) {
    int g = ks * 4 + (lane >> 4);
    bf16x8 a = *(const bf16x8*)&arow[g * 8];
#pragma unroll
    for (int ni = 0; ni < 4; ni++) {
      int rs = ni * 16 + (lane & 15);
      bf16x8 bfr = *(const bf16x8*)((char*)Bsm + rs * 256 + ((g ^ (rs & 7)) << 4));
      acc1[ni] = __builtin_amdgcn_mfma_f32_16x16x32_bf16(a, bfr, acc1[ni], 0, 0, 0);
    }
  }
#pragma unroll
  for (int ni = 0; ni < 4; ni++)
#pragma unroll
    for (int j = 0; j < 4; j++) {
      int t = w * 16 + (lane >> 4) * 4 + j;
      int s = ni * 16 + (lane & 15);
      float v = 0.f;
      if (t >= s) v = acc1[ni][j] * __expf(cuml[t] - cuml[s]) * dtl[s];
      *(unsigned short*)((char*)Ms + t * 128 + (((s >> 3) ^ (t & 7)) << 4) + ((s & 7) << 1)) = f2bf(v);
    }
  __syncthreads();

  // GEMM2: Y_intra = M·X ; GEMM3: ST = X^T·Bsc
  f32x4 acc2[4], acc3[8];
#pragma unroll
  for (int i = 0; i < 4; i++) acc2[i] = fz4();
#pragma unroll
  for (int i = 0; i < 8; i++) acc3[i] = fz4();
#pragma unroll
  for (int ks = 0; ks < 2; ks++) {
    int g = ks * 4 + (lane >> 4);
    bf16x8 xf[4];
#pragma unroll
    for (int ni = 0; ni < 4; ni++) {
      int rp = ni * 16 + (lane & 15);
      xf[ni] = *(const bf16x8*)((char*)XT + rp * 128 + ((g ^ (rp & 7)) << 4));
    }
    {
      bf16x8 a = *(const bf16x8*)((char*)Ms + rt * 128 + ((g ^ (rt & 7)) << 4));
#pragma unroll
      for (int ni = 0; ni < 4; ni++)
        acc2[ni] = __builtin_amdgcn_mfma_f32_16x16x32_bf16(a, xf[ni], acc2[ni], 0, 0, 0);
    }
    {
      bf16x8 a3 = xf[w];
#pragma unroll
      for (int ni = 0; ni < 8; ni++) {
        int rn = ni * 16 + (lane & 15);
        bf16x8 bfr = *(const bf16x8*)((char*)BTs + rn * 128 + ((g ^ (rn & 7)) << 4));
        acc3[ni] = __builtin_amdgcn_mfma_f32_16x16x32_bf16(a3, bfr, acc3[ni], 0, 0, 0);
      }
    }
  }
  __syncthreads();   // all LDS operand reads done; safe to overlay
  // stage y (Ms) and ST (bf16, STst over Bsm/BTs region)
  unsigned short* STst = sh;
#pragma unroll
  for (int ni = 0; ni < 4; ni++)
#pragma unroll
    for (int j = 0; j < 4; j++) {
      int t = w * 16 + (lane >> 4) * 4 + j;
      int p = ni * 16 + (lane & 15);
      Ms[t * 72 + p] = f2bf(acc2[ni][j]);
    }
#pragma unroll
  for (int ni = 0; ni < 8; ni++)
#pragma unroll
    for (int j = 0; j < 4; j++) {
      int p = w * 16 + (lane >> 4) * 4 + j;
      int n = ni * 16 + (lane & 15);
      STst[p * 136 + n] = f2bf(acc3[ni][j]);
    }
  __syncthreads();
  {
    int rr = tid >> 3, cc = (tid & 7) * 8;
    for (int it = 0; it < 2; it++) {
      int t = it * 32 + rr;
      uint4 v = *(const uint4*)&Ms[t * 72 + cc];
      *(uint4*)&yb[(size_t)(m0 + t) * 256 + h * 64 + cc] = v;
    }
  }
  {
    unsigned short* stp = ST + ((size_t)bid << 13);
    int rr = tid >> 2, cc = (tid & 3) * 32;
    for (int q = 0; q < 4; q++) {
      uint4 v = *(const uint4*)&STst[rr * 136 + cc + q * 8];
      *(uint4*)&stp[rr * 128 + cc + q * 8] = v;
    }
  }
}

// ---------------- chunk phase B: sequential state carry (ST bf16) ----------------
__global__ __launch_bounds__(256) void k_chunkB(const unsigned short* __restrict__ ST,
                                                const float* __restrict__ cums,
                                                unsigned short* __restrict__ HT) {
  int bid = blockIdx.x;
  int bh = bid >> 3, psl = bid & 7;
  int p = psl * 8 + (threadIdx.x >> 5);
  int n0 = (threadIdx.x & 31) * 4;
  float H[4] = {0.f, 0.f, 0.f, 0.f};
  for (int c = 0; c < 64; c++) {
    size_t base = (size_t)(bh * 64 + c);
    ushort4 hv;
    unsigned short* ha = (unsigned short*)&hv;
#pragma unroll
    for (int e = 0; e < 4; e++) ha[e] = f2bf(H[e]);
    *(ushort4*)&HT[(base * 64 + p) * 128 + n0] = hv;
    ushort4 s4 = *(const ushort4*)&ST[(base << 13) + p * 128 + n0];
    float dec = __expf(cums[bh * LSEQ + c * 64 + 63]);
    H[0] = H[0] * dec + bf2f(s4.x);
    H[1] = H[1] * dec + bf2f(s4.y);
    H[2] = H[2] * dec + bf2f(s4.z);
    H[3] = H[3] * dec + bf2f(s4.w);
  }
}

// ---------------- chunk phase C: Y += exp(cum)·C·Hstart^T + D·x ----------------
__global__ __launch_bounds__(256) void k_chunkC(const unsigned short* __restrict__ bc,
                                                const unsigned short* __restrict__ xs,
                                                const unsigned short* __restrict__ HT,
                                                const float* __restrict__ cums,
                                                const float* __restrict__ Dp,
                                                unsigned short* __restrict__ yb) {
  __shared__ __align__(16) unsigned short Hs[64 * 128];
  __shared__ __align__(16) unsigned short yst[64 * 72];
  int bid = blockIdx.x;
  int bh = bid >> 6, c = bid & 63;
  int b = bh >> 2, h = bh & 3;
  int m0 = b * LSEQ + c * 64;
  int tid = threadIdx.x, w = tid >> 6, lane = tid & 63;
  float Dh = Dp[h];
  for (int it = 0; it < 4; it++) {
    int idx = it * 256 + tid, row = idx >> 4, g = idx & 15;
    uint4 v = *(const uint4*)&HT[((size_t)(bh * 64 + c) * 64 + row) * 128 + g * 8];
    *(uint4*)((char*)Hs + row * 256 + ((g ^ (row & 7)) << 4)) = v;
  }
  float exq[4];
  {
    int tb = w * 16 + (lane >> 4) * 4;
#pragma unroll
    for (int j = 0; j < 4; j++) exq[j] = __expf(cums[bh * LSEQ + c * 64 + tb + j]);
  }
  __syncthreads();
  int rt = w * 16 + (lane & 15);
  const unsigned short* arow = bc + (size_t)(m0 + rt) * 256 + 128;
  f32x4 acc[4];
#pragma unroll
  for (int i = 0; i < 4; i++) acc[i] = fz4();
#pragma unroll
  for (int ks = 0; ks < 4; ks++) {
    int g = ks * 4 + (lane >> 4);
    bf16x8 a = *(const bf16x8*)&arow[g * 8];
#pragma unroll
    for (int ni = 0; ni < 4; ni++) {
      int rp = ni * 16 + (lane & 15);
      bf16x8 bfr = *(const bf16x8*)((char*)Hs + rp * 256 + ((g ^ (rp & 7)) << 4));
      acc[ni] = __builtin_amdgcn_mfma_f32_16x16x32_bf16(a, bfr, acc[ni], 0, 0, 0);
    }
  }
#pragma unroll
  for (int ni = 0; ni < 4; ni++)
#pragma unroll
    for (int j = 0; j < 4; j++) {
      int t = w * 16 + (lane >> 4) * 4 + j;
      int p = ni * 16 + (lane & 15);
      yst[t * 72 + p] = f2bf(acc[ni][j] * exq[j]);
    }
  __syncthreads();
  {
    int rr = tid >> 3, cc = (tid & 7) * 8;
    for (int it = 0; it < 2; it++) {
      int t = it * 32 + rr;
      size_t off = (size_t)(m0 + t) * 256 + h * 64 + cc;
      uint4 yo = *(const uint4*)&yb[off];
      uint4 xv = *(const uint4*)&xs[off];
      const unsigned short* pyo = (const unsigned short*)&yo;
      const unsigned short* pxv = (const unsigned short*)&xv;
      const unsigned short* pys = &yst[t * 72 + cc];
      uint4 vo;
      unsigned short* po = (unsigned short*)&vo;
#pragma unroll
      for (int e = 0; e < 8; e++)
        po[e] = f2bf(bf2f(pyo[e]) + bf2f(pys[e]) + Dh * bf2f(pxv[e]));
      *(uint4*)&yb[off] = vo;
    }
  }
}

// ---------------- gate + RMSNorm ----------------
template <int MODE>
__global__ __launch_bounds__(256) void k_ycat(const unsigned short* __restrict__ y,
                                              const unsigned short* __restrict__ zsrc,
                                              const float* __restrict__ norm_w,
                                              unsigned short* __restrict__ ocat) {
  int bid = blockIdx.x;
  int tid = threadIdx.x, w = tid >> 6, lane = tid & 63;
  size_t m = (size_t)bid * 4 + w;
  int j0 = lane * 4;
  ushort4 yv = *(const ushort4*)&y[m * 256 + j0];
  ushort4 zv;
  if constexpr (MODE == 0) zv = *(const ushort4*)&zsrc[m * 256 + j0];
  else zv = *(const ushort4*)&zsrc[m * 1280 + 512 + j0];
  unsigned short ya[4] = {yv.x, yv.y, yv.z, yv.w};
  unsigned short za[4] = {zv.x, zv.y, zv.z, zv.w};
  float g[4]; float ssum = 0.f;
  for (int i = 0; i < 4; i++) {
    float gg = bf2f(ya[i]) * silu(bf2f(za[i]));
    g[i] = gg; ssum += gg * gg;
  }
  for (int off = 32; off; off >>= 1) ssum += __shfl_xor(ssum, off, 64);
  float inv = rsqrtf(ssum * (1.f / 256.f) + 1e-5f);
  ushort4 o2;
  unsigned short* o2a = (unsigned short*)&o2;
  for (int i = 0; i < 4; i++) o2a[i] = f2bf(g[i] * norm_w[j0 + i] * inv);
  *(ushort4*)&ocat[m * 512 + 256 + j0] = o2;
  if constexpr (MODE == 1) {
    ushort4 p0 = *(const ushort4*)&zsrc[m * 1280 + 2 * j0];
    ushort4 p1 = *(const ushort4*)&zsrc[m * 1280 + 2 * j0 + 4];
    ushort4 o1;
    unsigned short* o1a = (unsigned short*)&o1;
    o1a[0] = f2bf(silu(bf2f(p0.x)) * bf2f(p0.y));
    o1a[1] = f2bf(silu(bf2f(p0.z)) * bf2f(p0.w));
    o1a[2] = f2bf(silu(bf2f(p1.x)) * bf2f(p1.y));
    o1a[3] = f2bf(silu(bf2f(p1.z)) * bf2f(p1.w));
    *(ushort4*)&ocat[m * 512 + j0] = o1;
  }
}

// ---------------- SE mean: one block per (b,c) row of res_t ----------------
__global__ __launch_bounds__(256) void k_semean(const unsigned short* __restrict__ rest,
                                                float* __restrict__ smean) {
  __shared__ float wsum[4];
  int row = blockIdx.x;                       // b*256 + c
  int tid = threadIdx.x, w = tid >> 6, lane = tid & 63;
  const unsigned short* p = rest + (size_t)row * 4096;
  float acc = 0.f;
  for (int it = 0; it < 2; it++) {
    uint4 v = *(const uint4*)&p[(it * 256 + tid) * 8];
    const unsigned short* pv = (const unsigned short*)&v;
#pragma unroll
    for (int e = 0; e < 8; e++) acc += bf2f(pv[e]);
  }
  for (int off = 32; off; off >>= 1) acc += __shfl_xor(acc, off, 64);
  if (lane == 0) wsum[w] = acc;
  __syncthreads();
  if (tid == 0) smean[row] = wsum[0] + wsum[1] + wsum[2] + wsum[3];
}

__global__ __launch_bounds__(512) void k_sefc(const float* __restrict__ smean,
                                              const float* __restrict__ w1, const float* __restrict__ b1,
                                              const float* __restrict__ w2, const float* __restrict__ b2,
                                              float* __restrict__ s2) {
  __shared__ float s1[512];
  int tid = threadIdx.x;
  int b = tid >> 6, j = tid & 63;
  float acc = b1[j];
  for (int k = 0; k < 256; k++) acc += smean[b * 256 + k] * (1.f / 4096.f) * w1[j * 256 + k];
  s1[b * 64 + j] = fmaxf(acc, 0.f);
  __syncthreads();
  for (int idx = tid; idx < 2048; idx += 512) {
    int bb = idx >> 8, c = idx & 255;
    float a2 = b2[c];
    for (int k = 0; k < 64; k++) a2 += s1[bb * 64 + k] * w2[c * 64 + k];
    s2[idx] = 1.f / (1.f + expf(-a2));
  }
}

// ---------------- final: elementwise SE scale on res_t ----------------
__global__ __launch_bounds__(256) void k_final(const unsigned short* __restrict__ rest,
                                               const float* __restrict__ s2,
                                               float* __restrict__ out) {
  int row = blockIdx.x;                       // b*256 + c
  float s = s2[row];
  int tid = threadIdx.x;
  const unsigned short* p = rest + (size_t)row * 4096;
  float* o = out + (size_t)row * 4096;
  for (int it = 0; it < 2; it++) {
    int base = (it * 256 + tid) * 8;
    uint4 v = *(const uint4*)&p[base];
    const unsigned short* pv = (const unsigned short*)&v;
    float4 f0, f1;
    f0.x = bf2f(pv[0]) * s; f0.y = bf2f(pv[1]) * s;
    f0.z = bf2f(pv[2]) * s; f0.w = bf2f(pv[3]) * s;
    f1.x = bf2f(pv[4]) * s; f1.y = bf2f(pv[5]) * s;
    f1.z = bf2f(pv[6]) * s; f1.w = bf2f(pv[7]) * s;
    *(float4*)&o[base] = f0;
    *(float4*)&o[base + 4] = f1;
  }
}

// ---------------- launch ----------------
extern "C" void kernel_launch(void* const* d_in, const int* in_sizes, int n_in,
                              void* d_out, int out_size, void* d_ws, size_t ws_size,
                              hipStream_t stream) {
  const float* x         = (const float*)d_in[0];
  const float* in_proj_w = (const float*)d_in[1];
  const float* conv_w    = (const float*)d_in[2];
  const float* conv_b    = (const float*)d_in[3];
  const float* dt_bias   = (const float*)d_in[4];
  const float* A_log     = (const float*)d_in[5];
  const float* Dp        = (const float*)d_in[6];
  const float* norm_w    = (const float*)d_in[7];
  const float* out_projw = (const float*)d_in[8];
  const float* se_w1     = (const float*)d_in[9];
  const float* se_b1     = (const float*)d_in[10];
  const float* se_w2     = (const float*)d_in[11];
  const float* se_b2     = (const float*)d_in[12];
  float* out = (float*)d_out;
  char* ws = (char*)d_ws;

  const size_t NEED_CHUNKED = 220676096;

  if (ws_size >= NEED_CHUNKED) {
    unsigned short* ST16  = (unsigned short*)(ws + 0);          // 33.5MB, chunkA->chunkB
    unsigned short* ubf   = (unsigned short*)(ws + 0);          // pre-gemm1 tenant
    unsigned short* xbc   = (unsigned short*)(ws + 16777216);   // gemm1->conv tenant
    unsigned short* res16 = (unsigned short*)(ws + 0);          // post-chunkB tenant (16.7MB)
    unsigned short* zcat  = (unsigned short*)(ws + 67108864);
    unsigned short* zbuf  = (unsigned short*)(ws + 100663296);
    unsigned short* xsb   = (unsigned short*)(ws + 117440512);
    unsigned short* bcb   = (unsigned short*)(ws + 134217728);
    unsigned short* HT    = (unsigned short*)(ws + 150994944);
    unsigned short* xsT   = (unsigned short*)(ws + 150994944);  // pre-chunkB tenant
    unsigned short* bT    = (unsigned short*)(ws + 167772160);  // pre-chunkB tenant
    unsigned short* ybuf  = (unsigned short*)(ws + 184549376);
    unsigned short* wpad  = (unsigned short*)(ws + 201326592);
    unsigned short* woutb = (unsigned short*)(ws + 202047488);
    float*          dtraw = (float*)(ws + 202309632);
    float*          dts   = (float*)(ws + 202833920);
    float*          cums  = (float*)(ws + 203358208);
    float*          smean = (float*)(ws + 203882496);
    float*          s2    = (float*)(ws + 203890688);

    k_prep<<<3968, 256, 0, stream>>>(in_proj_w, out_projw, wpad, woutb, x, ubf);
    k_gemm<256, 256, 256, 2><<<256 * 11, 256, 0, stream>>>(ubf, wpad, (float*)xbc, zcat, zbuf, dtraw, 11);
    k_conv<<<1536, 256, 0, stream>>>(xbc, 512, conv_w, conv_b, xsb, bcb, xsT, bT,
                                     dtraw, dt_bias, A_log, dts, cums);
    k_chunkA<<<2048, 256, 0, stream>>>(bcb, xsT, bT, dts, cums, ST16, ybuf);
    k_chunkB<<<256, 256, 0, stream>>>(ST16, cums, HT);
    k_chunkC<<<2048, 256, 0, stream>>>(bcb, xsb, HT, cums, Dp, ybuf);
    k_ycat<0><<<8192, 256, 0, stream>>>(ybuf, zbuf, norm_w, zcat);
    k_gemm<512, 512, 512, 1><<<256 * 2, 256, 0, stream>>>(zcat, woutb, nullptr, res16, nullptr, nullptr, 2);
    k_semean<<<2048, 256, 0, stream>>>(res16, smean);
    k_sefc<<<1, 512, 0, stream>>>(smean, se_w1, se_b1, se_w2, se_b2, s2);
    k_final<<<2048, 256, 0, stream>>>(res16, s2, out);
  } else {
    unsigned short* ubf   = (unsigned short*)(ws + 0);
    unsigned short* res16 = (unsigned short*)(ws + 0);
    unsigned short* xsb   = (unsigned short*)(ws + 16777216);
    unsigned short* bcb   = (unsigned short*)(ws + 33554432);
    unsigned short* zx    = (unsigned short*)(ws + 50331648);
    float*          dtb   = (float*)(ws + 134217728);
    unsigned short* ybuf  = (unsigned short*)(ws + 134742016);
    unsigned short* ycat  = (unsigned short*)(ws + 151519232);
    unsigned short* wpad  = (unsigned short*)(ws + 185073664);
    unsigned short* woutb = (unsigned short*)(ws + 185794560);
    float*          smean = (float*)(ws + 186056704);
    float*          s2    = (float*)(ws + 186064896);

    k_prep<<<3968, 256, 0, stream>>>(in_proj_w, out_projw, wpad, woutb, x, ubf);
    k_gemm<256, 256, 256, 0><<<256 * 11, 256, 0, stream>>>(ubf, wpad, nullptr, zx, nullptr, dtb, 11);
    k_conv<<<1024, 256, 0, stream>>>(zx + 768, 1280, conv_w, conv_b, xsb, bcb, nullptr, nullptr,
                                     nullptr, nullptr, nullptr, nullptr, nullptr);
    k_scan<<<512, 256, 0, stream>>>(xsb, bcb, dtb, dt_bias, A_log, Dp, ybuf);
    k_ycat<1><<<8192, 256, 0, stream>>>(ybuf, zx, norm_w, ycat);
    k_gemm<512, 512, 512, 1><<<256 * 2, 256, 0, stream>>>(ycat, woutb, nullptr, res16, nullptr, nullptr, 2);
    k_semean<<<2048, 256, 0, stream>>>(res16, smean);
    k_sefc<<<1, 512, 0, stream>>>(smean, se_w1, se_b1, se_w2, se_b2, s2);
    k_final<<<2048, 256, 0, stream>>>(res16, s2, out);
  }
}